// Round 4
// baseline (399.250 us; speedup 1.0000x reference)
//
#include <hip/hip_runtime.h>
#include <hip/hip_bf16.h>

#define BATCH 2
#define SEQ 2048
#define DM 512
#define NH 8
#define DHD 64
#define QP 256
#define KVP 341
#define KVPAD 352
#define DQKPAD 96
#define MROWS 4096   // BATCH*SEQ

// bf16 arena element offsets (cumulative over setup_inputs order)
#define OFF_X     0
#define OFF_WDQ   2097152
#define OFF_WUQ   2228224
#define OFF_WQR   2359296
#define OFF_WDKV  2375680
#define OFF_WUKV  2550272
#define OFF_WKR   2899456
#define OFF_WO    2932224
#define OFF_QG    3194368
#define OFF_QB    3194624
#define OFF_KG    3194880
#define OFF_KB    3195221
#define N_ELEMS   3195562

typedef __bf16 bf16x8 __attribute__((ext_vector_type(8)));
typedef float f32x4 __attribute__((ext_vector_type(4)));
typedef __hip_bfloat16 bf16;
typedef unsigned short u16;

static __device__ __forceinline__ bf16x8 ld_bf8(const bf16* p) {
    return __builtin_bit_cast(bf16x8, *(const uint4*)p);
}

// ---------------- dtype detect: bf16 vs fp32 device buffers ----------------
__global__ void detect_k(const u16* __restrict__ x, int* __restrict__ flagp) {
    __shared__ int cnt;
    if (threadIdx.x == 0) cnt = 0;
    __syncthreads();
    int bad = 0;
    for (int i = threadIdx.x; i < 2048; i += 256) {
        u16 u = x[i];
        int e = (u >> 7) & 0xFF;
        if (u != 0 && (e < 90 || e > 164)) bad++;
    }
    atomicAdd(&cnt, bad);
    __syncthreads();
    if (threadIdx.x == 0) *flagp = (cnt > 256) ? 1 : 0;  // 1 => inputs are fp32
}

// ---------------- convert/copy all inputs into bf16 arena ----------------
__global__ __launch_bounds__(256) void cvt_all(
    const void* s0, const void* s1, const void* s2, const void* s3,
    const void* s4, const void* s5, const void* s6, const void* s7,
    const void* s8, const void* s9, const void* s10, const void* s11,
    u16* __restrict__ arena, const int* __restrict__ flagp)
{
    int gid = blockIdx.x * 256 + threadIdx.x;
    if (gid >= N_ELEMS) return;
    const int f = *flagp;
    const void* src; int base;
    if      (gid < OFF_WDQ)  { src = s0;  base = OFF_X; }
    else if (gid < OFF_WUQ)  { src = s1;  base = OFF_WDQ; }
    else if (gid < OFF_WQR)  { src = s2;  base = OFF_WUQ; }
    else if (gid < OFF_WDKV) { src = s3;  base = OFF_WQR; }
    else if (gid < OFF_WUKV) { src = s4;  base = OFF_WDKV; }
    else if (gid < OFF_WKR)  { src = s5;  base = OFF_WUKV; }
    else if (gid < OFF_WO)   { src = s6;  base = OFF_WKR; }
    else if (gid < OFF_QG)   { src = s7;  base = OFF_WO; }
    else if (gid < OFF_QB)   { src = s8;  base = OFF_QG; }
    else if (gid < OFF_KG)   { src = s9;  base = OFF_QB; }
    else if (gid < OFF_KB)   { src = s10; base = OFF_KG; }
    else                     { src = s11; base = OFF_KB; }
    int local = gid - base;
    u16 v;
    if (f) {
        float xv = ((const float*)src)[local];
        v = __builtin_bit_cast(u16, __float2bfloat16(xv));
    } else {
        v = ((const u16*)src)[local];
    }
    arena[gid] = v;
}

// ---------------- generic 64x64 bf16 MFMA GEMM ----------------
// modes: 0 fp32->C0(ldc); 1 out-dtype->C0/C0f(ldc); 2 Q-scatter; 3 KV-scatter.
__global__ __launch_bounds__(256) void gemm64(
    const bf16* __restrict__ A, int lda,
    const bf16* __restrict__ Bm, int ldb,
    int N, int Kpad, int KbValid, int bt, int mode,
    void* __restrict__ C0, int ldc,
    bf16* __restrict__ kv_k, bf16* __restrict__ kv_v,
    const int* __restrict__ flagp, float* __restrict__ C0f)
{
    __shared__ __align__(16) bf16 Al[64][40];
    __shared__ __align__(16) bf16 Bl[64][40];
    const int tid = threadIdx.x;
    const int m0 = blockIdx.y * 64, n0 = blockIdx.x * 64;
    const int lane = tid & 63, w = tid >> 6;
    const int wm = w >> 1, wn = w & 1;
    const int g = lane >> 4, lr = lane & 15;
    f32x4 acc[2][2] = {};
    const int arow = tid >> 2, acol = (tid & 3) * 8;

    for (int k0 = 0; k0 < Kpad; k0 += 32) {
        *(uint4*)&Al[arow][acol] =
            *(const uint4*)&A[(size_t)(m0 + arow) * lda + k0 + acol];
        if (bt) {
            *(uint4*)&Bl[arow][acol] =
                *(const uint4*)&Bm[(size_t)(n0 + arow) * ldb + k0 + acol];
        } else {
            int n = tid & 63;
            #pragma unroll
            for (int p = 0; p < 8; ++p) {
                int kk = p * 4 + (tid >> 6);
                bf16 v = __float2bfloat16(0.f);
                if ((k0 + kk) < KbValid && (n0 + n) < N)
                    v = Bm[(size_t)(k0 + kk) * ldb + n0 + n];
                Bl[n][kk] = v;
            }
        }
        __syncthreads();
        #pragma unroll
        for (int mt = 0; mt < 2; ++mt) {
            bf16x8 a = ld_bf8(&Al[wm * 32 + mt * 16 + lr][g * 8]);
            #pragma unroll
            for (int nt = 0; nt < 2; ++nt) {
                bf16x8 b = ld_bf8(&Bl[wn * 32 + nt * 16 + lr][g * 8]);
                acc[mt][nt] = __builtin_amdgcn_mfma_f32_16x16x32_bf16(a, b, acc[mt][nt], 0, 0, 0);
            }
        }
        __syncthreads();
    }

    const int f32o = flagp ? *flagp : 0;
    #pragma unroll
    for (int mt = 0; mt < 2; ++mt)
    #pragma unroll
    for (int nt = 0; nt < 2; ++nt)
    #pragma unroll
    for (int r = 0; r < 4; ++r) {
        int gm = m0 + wm * 32 + mt * 16 + g * 4 + r;
        int gn = n0 + wn * 32 + nt * 16 + lr;
        if (gn >= N) continue;
        float v = acc[mt][nt][r];
        if (mode == 0) {
            ((float*)C0)[(size_t)gm * ldc + gn] = v;
        } else if (mode == 1) {
            if (f32o) C0f[(size_t)gm * ldc + gn] = v;
            else ((bf16*)C0)[(size_t)gm * ldc + gn] = __float2bfloat16(v);
        } else if (mode == 2) {
            int h = gn >> 6, dh = gn & 63;
            int b = gm >> 11, s = gm & 2047;
            ((bf16*)C0)[((size_t)(b * NH + h) * SEQ + s) * DQKPAD + dh] = __float2bfloat16(v);
        } else { // mode 3: KV scatter
            int b = gm >> 11, s = gm & 2047;
            if (gn < DM) {
                int h = gn >> 6, dh = gn & 63;
                kv_k[((size_t)(b * NH + h) * SEQ + s) * DQKPAD + dh] = __float2bfloat16(v);
            } else {
                int c = gn - DM;
                int h = c >> 6, dv = c & 63;
                kv_v[((size_t)(b * NH + h) * SEQ + s) * DHD + dv] = __float2bfloat16(v);
            }
        }
    }
}

// ---------------- row layernorm (fp32 in; O1 dual-dtype, O2 bf16) ----------------
__global__ __launch_bounds__(256) void ln_row(
    const float* __restrict__ Y, int N,
    const bf16* __restrict__ gam, const bf16* __restrict__ bet,
    bf16* __restrict__ O1, float* __restrict__ O1f, const int* __restrict__ flagp, int ld1,
    bf16* __restrict__ O2, int ld2, int padN)
{
    int row = blockIdx.x;
    const float* y = Y + (size_t)row * N;
    int tid = threadIdx.x;
    const int f32o = flagp ? *flagp : 0;
    float s = 0.f, ss = 0.f;
    for (int i = tid; i < N; i += 256) { float v = y[i]; s += v; ss += v * v; }
    #pragma unroll
    for (int m = 1; m < 64; m <<= 1) { s += __shfl_xor(s, m); ss += __shfl_xor(ss, m); }
    __shared__ float red[2][4];
    int w = tid >> 6;
    if ((tid & 63) == 0) { red[0][w] = s; red[1][w] = ss; }
    __syncthreads();
    s = red[0][0] + red[0][1] + red[0][2] + red[0][3];
    ss = red[1][0] + red[1][1] + red[1][2] + red[1][3];
    float mean = s / N;
    float var = ss / N - mean * mean;
    float rstd = rsqrtf(var + 1e-5f);
    for (int i = tid; i < N; i += 256) {
        float v = (y[i] - mean) * rstd * __bfloat162float(gam[i]) + __bfloat162float(bet[i]);
        if (f32o) O1f[(size_t)row * ld1 + i] = v;
        else O1[(size_t)row * ld1 + i] = __float2bfloat16(v);
        if (O2) O2[(size_t)row * ld2 + i] = __float2bfloat16(v);
    }
    if (O2) for (int i = N + tid; i < padN; i += 256) O2[(size_t)row * ld2 + i] = __float2bfloat16(0.f);
}

// ---------------- rope + pad fill for q/k rope tails ----------------
__global__ __launch_bounds__(256) void rope_fill(
    const float* __restrict__ yqr, const float* __restrict__ ykr,
    bf16* __restrict__ qa, bf16* __restrict__ ka)
{
    int idx = blockIdx.x * 256 + threadIdx.x;
    if (idx >= MROWS * NH) return;
    int m = idx >> 3, h = idx & 7;
    int b = m >> 11, s = m & 2047;
    float q[8], k[8], qo[8], ko[8];
    #pragma unroll
    for (int j = 0; j < 8; ++j) {
        q[j] = yqr[(size_t)m * 64 + h * 8 + j];
        k[j] = ykr[(size_t)m * 64 + h * 8 + j];
    }
    #pragma unroll
    for (int i = 0; i < 4; ++i) {
        float inv = exp2f(-(float)i * 3.3219280948873623f);  // 10000^(-i/4)
        float ang = (float)s * inv;
        float sn, cs;
        sincosf(ang, &sn, &cs);
        qo[i] = q[i] * cs - q[i + 4] * sn;
        qo[i + 4] = q[i + 4] * cs + q[i] * sn;
        ko[i] = k[i] * cs - k[i + 4] * sn;
        ko[i + 4] = k[i + 4] * cs + k[i] * sn;
    }
    bf16* qp = qa + ((size_t)(b * NH + h) * SEQ + s) * DQKPAD;
    bf16* kp = ka + ((size_t)(b * NH + h) * SEQ + s) * DQKPAD;
    #pragma unroll
    for (int j = 0; j < 8; ++j) {
        qp[64 + j] = __float2bfloat16(qo[j]);
        kp[64 + j] = __float2bfloat16(ko[j]);
    }
    #pragma unroll
    for (int j = 72; j < 96; ++j) {
        qp[j] = __float2bfloat16(0.f);
        kp[j] = __float2bfloat16(0.f);
    }
}

// ---------------- causal flash attention ----------------
__global__ __launch_bounds__(256) void attn_fwd(
    const bf16* __restrict__ qa, const bf16* __restrict__ ka, const bf16* __restrict__ va,
    bf16* __restrict__ ao)
{
    __shared__ __align__(16) bf16 Kl[32][104];
    __shared__ __align__(16) bf16 Vt[64][40];
    __shared__ __align__(16) bf16 Pl[4][16][40];
    const int qb = blockIdx.x, bh = blockIdx.y;
    const int tid = threadIdx.x, w = tid >> 6, lane = tid & 63;
    const int g = lane >> 4, lr = lane & 15;
    const size_t base = (size_t)bh * SEQ;
    const int qrow = qb * 64 + w * 16 + lr;

    bf16x8 qf[3];
    #pragma unroll
    for (int kc = 0; kc < 3; ++kc)
        qf[kc] = ld_bf8(&qa[(base + qrow) * DQKPAD + kc * 32 + g * 8]);

    float m_r[4], l_r[4];
    f32x4 acc_o[4] = {};
    #pragma unroll
    for (int r = 0; r < 4; ++r) { m_r[r] = -__builtin_inff(); l_r[r] = 0.f; }

    const int jend = qb * 64 + 64;
    const float SC = 0.11785113019775793f;   // 1/sqrt(72)
    const float L2E = 1.4426950408889634f;

    for (int j0 = 0; j0 < jend; j0 += 32) {
        __syncthreads();
        for (int u = tid; u < 384; u += 256) {
            int row = u / 12, cc = (u % 12) * 8;
            *(uint4*)&Kl[row][cc] = *(const uint4*)&ka[(base + j0 + row) * DQKPAD + cc];
        }
        {
            int row = tid >> 3, cc = (tid & 7) * 8;
            uint4 vv = *(const uint4*)&va[(base + j0 + row) * DHD + cc];
            const bf16* pv = (const bf16*)&vv;
            #pragma unroll
            for (int j = 0; j < 8; ++j) Vt[cc + j][row] = pv[j];
        }
        __syncthreads();

        f32x4 accs[2] = {};
        #pragma unroll
        for (int kc = 0; kc < 3; ++kc) {
            #pragma unroll
            for (int nt = 0; nt < 2; ++nt) {
                bf16x8 kf = ld_bf8(&Kl[nt * 16 + lr][kc * 32 + g * 8]);
                accs[nt] = __builtin_amdgcn_mfma_f32_16x16x32_bf16(qf[kc], kf, accs[nt], 0, 0, 0);
            }
        }
        float pv2[2][4];
        #pragma unroll
        for (int nt = 0; nt < 2; ++nt)
        #pragma unroll
        for (int r = 0; r < 4; ++r) {
            int jj = j0 + nt * 16 + lr;
            int qr = qb * 64 + w * 16 + g * 4 + r;
            float sv = accs[nt][r] * SC;
            pv2[nt][r] = (jj <= qr) ? sv : -__builtin_inff();
        }
        #pragma unroll
        for (int r = 0; r < 4; ++r) {
            float rm = fmaxf(pv2[0][r], pv2[1][r]);
            rm = fmaxf(rm, __shfl_xor(rm, 1));
            rm = fmaxf(rm, __shfl_xor(rm, 2));
            rm = fmaxf(rm, __shfl_xor(rm, 4));
            rm = fmaxf(rm, __shfl_xor(rm, 8));
            float mn = fmaxf(m_r[r], rm);
            float alpha = exp2f((m_r[r] - mn) * L2E);
            m_r[r] = mn;
            float p0 = exp2f((pv2[0][r] - mn) * L2E);
            float p1 = exp2f((pv2[1][r] - mn) * L2E);
            pv2[0][r] = p0; pv2[1][r] = p1;
            float rs = p0 + p1;
            rs += __shfl_xor(rs, 1); rs += __shfl_xor(rs, 2);
            rs += __shfl_xor(rs, 4); rs += __shfl_xor(rs, 8);
            l_r[r] = l_r[r] * alpha + rs;
            #pragma unroll
            for (int nv = 0; nv < 4; ++nv) acc_o[nv][r] *= alpha;
        }
        #pragma unroll
        for (int nt = 0; nt < 2; ++nt)
        #pragma unroll
        for (int r = 0; r < 4; ++r)
            Pl[w][g * 4 + r][nt * 16 + lr] = __float2bfloat16(pv2[nt][r]);
        bf16x8 pf = ld_bf8(&Pl[w][lr][g * 8]);
        #pragma unroll
        for (int nv = 0; nv < 4; ++nv) {
            bf16x8 vf = ld_bf8(&Vt[nv * 16 + lr][g * 8]);
            acc_o[nv] = __builtin_amdgcn_mfma_f32_16x16x32_bf16(pf, vf, acc_o[nv], 0, 0, 0);
        }
    }

    int b = bh >> 3, h = bh & 7;
    #pragma unroll
    for (int r = 0; r < 4; ++r) {
        float inv = 1.0f / l_r[r];
        int qr = qb * 64 + w * 16 + g * 4 + r;
        #pragma unroll
        for (int nv = 0; nv < 4; ++nv)
            ao[((size_t)(b * SEQ) + qr) * DM + h * DHD + nv * 16 + lr] =
                __float2bfloat16(acc_o[nv][r] * inv);
    }
}

extern "C" void kernel_launch(void* const* d_in, const int* in_sizes, int n_in,
                              void* d_out, int out_size, void* d_ws, size_t ws_size,
                              hipStream_t stream) {
    char* ws = (char*)d_ws;
    bf16* AR      = (bf16*)(ws + 0);            // bf16 arena (6,391,124 B)
    int*  flagp   = (int*)(ws + 6391168);
    float* y_dq   = (float*)(ws + 6391296);
    float* y_dkv  = (float*)(ws + 10585600);
    float* y_kr   = (float*)(ws + 16172544);
    float* y_qr   = (float*)(ws + 17221120);
    bf16* cq      = (bf16*)(ws + 18269696);
    bf16* ckvp    = (bf16*)(ws + 20366848);
    bf16* q_attn  = (bf16*)(ws + 23250432);
    bf16* k_attn  = (bf16*)(ws + 29541888);
    bf16* v_attn  = (bf16*)(ws + 35833344);
    bf16* attn_o  = (bf16*)(ws + 40027648);

    const bf16* xb    = AR + OFF_X;
    const bf16* W_dq  = AR + OFF_WDQ;
    const bf16* W_uq  = AR + OFF_WUQ;
    const bf16* W_qr  = AR + OFF_WQR;
    const bf16* W_dkv = AR + OFF_WDKV;
    const bf16* W_ukv = AR + OFF_WUKV;
    const bf16* W_kr  = AR + OFF_WKR;
    const bf16* W_o   = AR + OFF_WO;
    const bf16* qg    = AR + OFF_QG;
    const bf16* qb_   = AR + OFF_QB;
    const bf16* kg    = AR + OFF_KG;
    const bf16* kb    = AR + OFF_KB;

    bf16*  out_b = (bf16*)d_out;
    float* out_f = (float*)d_out;
    bf16*  ckv_b = out_b + (size_t)MROWS * DM;
    float* ckv_f = out_f + (size_t)MROWS * DM;

    dim3 blk(256);
    detect_k<<<1, blk, 0, stream>>>((const u16*)d_in[0], flagp);
    cvt_all<<<dim3((N_ELEMS + 255) / 256), blk, 0, stream>>>(
        d_in[0], d_in[1], d_in[2], d_in[3], d_in[4], d_in[5],
        d_in[6], d_in[7], d_in[8], d_in[9], d_in[10], d_in[11],
        (u16*)AR, flagp);

    // low-rank projections from x
    gemm64<<<dim3(4, 64), blk, 0, stream>>>(xb, DM, W_dq, QP, QP, DM, DM, 0, 0, y_dq, QP, nullptr, nullptr, nullptr, nullptr);
    gemm64<<<dim3(6, 64), blk, 0, stream>>>(xb, DM, W_dkv, KVP, KVP, DM, DM, 0, 0, y_dkv, KVP, nullptr, nullptr, nullptr, nullptr);
    gemm64<<<dim3(1, 64), blk, 0, stream>>>(xb, DM, W_kr, 64, 64, DM, DM, 0, 0, y_kr, 64, nullptr, nullptr, nullptr, nullptr);
    // layernorms
    ln_row<<<MROWS, blk, 0, stream>>>(y_dq, QP, qg, qb_, cq, nullptr, nullptr, QP, nullptr, 0, 0);
    ln_row<<<MROWS, blk, 0, stream>>>(y_dkv, KVP, kg, kb, ckv_b, ckv_f, flagp, KVP, ckvp, KVPAD, KVPAD);
    // up-projections
    gemm64<<<dim3(8, 64), blk, 0, stream>>>(cq, QP, W_uq, DM, DM, QP, QP, 0, 2, q_attn, 0, nullptr, nullptr, nullptr, nullptr);
    gemm64<<<dim3(1, 64), blk, 0, stream>>>(cq, QP, W_qr, 64, 64, QP, QP, 0, 0, y_qr, 64, nullptr, nullptr, nullptr, nullptr);
    gemm64<<<dim3(16, 64), blk, 0, stream>>>(ckvp, KVPAD, W_ukv, 1024, 1024, KVPAD, KVP, 0, 3, nullptr, 0, k_attn, v_attn, nullptr, nullptr);
    // rope tails + pad zeros
    rope_fill<<<dim3(MROWS * NH / 256), blk, 0, stream>>>(y_qr, y_kr, q_attn, k_attn);
    // attention
    attn_fwd<<<dim3(SEQ / 64, 16), blk, 0, stream>>>(q_attn, k_attn, v_attn, attn_o);
    // output projection (B^T) -> d_out (dual dtype)
    gemm64<<<dim3(8, 64), blk, 0, stream>>>(attn_o, DM, W_o, DM, DM, DM, DM, 1, 1, out_b, DM, nullptr, nullptr, flagp, out_f);
}

// Round 5
// 180.179 us; speedup vs baseline: 2.2159x; 2.2159x over previous
//
#include <hip/hip_runtime.h>
#include <hip/hip_bf16.h>

#define BATCH 2
#define SEQ 2048
#define DM 512
#define NH 8
#define DHD 64
#define QP 256
#define KVP 341
#define KVPAD 352
#define DQKPAD 96
#define MROWS 4096   // BATCH*SEQ

// bf16 arena element offsets (cumulative over setup_inputs order)
#define OFF_X     0
#define OFF_WDQ   2097152
#define OFF_WUQ   2228224
#define OFF_WQR   2359296
#define OFF_WDKV  2375680
#define OFF_WUKV  2550272
#define OFF_WKR   2899456
#define OFF_WO    2932224
#define OFF_QG    3194368
#define OFF_QB    3194624
#define OFF_KG    3194880
#define OFF_KB    3195221
#define N_ELEMS   3195562

// transposed-weight arena element offsets
#define T_DQ   0        // [256][512]
#define T_DKV  131072   // [384][512] (n>=341 zero)
#define T_KR   327680   // [64][512]
#define T_UQ   360448   // [512][256]
#define T_QR   491520   // [64][256]
#define T_UKV  507904   // [1024][352] (k>=341 zero)
#define T_TOT  868352

typedef __bf16 bf16x8 __attribute__((ext_vector_type(8)));
typedef float f32x4 __attribute__((ext_vector_type(4)));
typedef __hip_bfloat16 bf16;
typedef unsigned short u16;

static __device__ __forceinline__ bf16x8 ld_bf8(const bf16* p) {
    return __builtin_bit_cast(bf16x8, *(const uint4*)p);
}

// ---------------- dtype detect: bf16 vs fp32 device buffers ----------------
__global__ void detect_k(const u16* __restrict__ x, int* __restrict__ flagp) {
    __shared__ int cnt;
    if (threadIdx.x == 0) cnt = 0;
    __syncthreads();
    int bad = 0;
    for (int i = threadIdx.x; i < 2048; i += 256) {
        u16 u = x[i];
        int e = (u >> 7) & 0xFF;
        if (u != 0 && (e < 90 || e > 164)) bad++;
    }
    atomicAdd(&cnt, bad);
    __syncthreads();
    if (threadIdx.x == 0) *flagp = (cnt > 256) ? 1 : 0;  // 1 => inputs are fp32
}

// ---------------- convert/copy all inputs into bf16 arena ----------------
__global__ __launch_bounds__(256) void cvt_all(
    const void* s0, const void* s1, const void* s2, const void* s3,
    const void* s4, const void* s5, const void* s6, const void* s7,
    const void* s8, const void* s9, const void* s10, const void* s11,
    u16* __restrict__ arena, const int* __restrict__ flagp)
{
    int gid = blockIdx.x * 256 + threadIdx.x;
    if (gid >= N_ELEMS) return;
    const int f = *flagp;
    const void* src; int base;
    if      (gid < OFF_WDQ)  { src = s0;  base = OFF_X; }
    else if (gid < OFF_WUQ)  { src = s1;  base = OFF_WDQ; }
    else if (gid < OFF_WQR)  { src = s2;  base = OFF_WUQ; }
    else if (gid < OFF_WDKV) { src = s3;  base = OFF_WQR; }
    else if (gid < OFF_WUKV) { src = s4;  base = OFF_WDKV; }
    else if (gid < OFF_WKR)  { src = s5;  base = OFF_WUKV; }
    else if (gid < OFF_WO)   { src = s6;  base = OFF_WKR; }
    else if (gid < OFF_QG)   { src = s7;  base = OFF_WO; }
    else if (gid < OFF_QB)   { src = s8;  base = OFF_QG; }
    else if (gid < OFF_KG)   { src = s9;  base = OFF_QB; }
    else if (gid < OFF_KB)   { src = s10; base = OFF_KG; }
    else                     { src = s11; base = OFF_KB; }
    int local = gid - base;
    u16 v;
    if (f) {
        float xv = ((const float*)src)[local];
        v = __builtin_bit_cast(u16, __float2bfloat16(xv));
    } else {
        v = ((const u16*)src)[local];
    }
    arena[gid] = v;
}

// ---------------- transpose + zero-pad all weights into WT arena ----------------
__global__ __launch_bounds__(256) void wt_all(const bf16* __restrict__ AR, bf16* __restrict__ WT) {
    int gid = blockIdx.x * 256 + threadIdx.x;
    if (gid >= T_TOT) return;
    const bf16* src; int base, Kp, Nv, Kv;
    if      (gid < T_DKV) { base = T_DQ;  Kp = 512; src = AR + OFF_WDQ;  Nv = 256;  Kv = 512; }
    else if (gid < T_KR)  { base = T_DKV; Kp = 512; src = AR + OFF_WDKV; Nv = 341;  Kv = 512; }
    else if (gid < T_UQ)  { base = T_KR;  Kp = 512; src = AR + OFF_WKR;  Nv = 64;   Kv = 512; }
    else if (gid < T_QR)  { base = T_UQ;  Kp = 256; src = AR + OFF_WUQ;  Nv = 512;  Kv = 256; }
    else if (gid < T_UKV) { base = T_QR;  Kp = 256; src = AR + OFF_WQR;  Nv = 64;   Kv = 256; }
    else                  { base = T_UKV; Kp = 352; src = AR + OFF_WUKV; Nv = 1024; Kv = 341; }
    int loc = gid - base;
    int n = loc / Kp, k = loc % Kp;
    bf16 v = __float2bfloat16(0.f);
    if (n < Nv && k < Kv) v = src[(size_t)k * Nv + n];
    WT[gid] = v;
}

// ---------------- generic 64x64 bf16 MFMA GEMM (B pre-transposed [N][K]) -----
// modes: 0 fp32->C0(ldc); 1 out-dtype->C0/C0f(ldc); 2 Q-scatter; 3 KV-scatter.
__global__ __launch_bounds__(256) void gemm64(
    const bf16* __restrict__ A, int lda,
    const bf16* __restrict__ BT, int ldb,
    int N, int Kpad, int mode,
    void* __restrict__ C0, int ldc,
    bf16* __restrict__ kv_k, bf16* __restrict__ kv_v,
    const int* __restrict__ flagp, float* __restrict__ C0f)
{
    __shared__ __align__(16) bf16 Al[64][40];
    __shared__ __align__(16) bf16 Bl[64][40];
    const int tid = threadIdx.x;
    const int m0 = blockIdx.y * 64, n0 = blockIdx.x * 64;
    const int lane = tid & 63, w = tid >> 6;
    const int wm = w >> 1, wn = w & 1;
    const int g = lane >> 4, lr = lane & 15;
    f32x4 acc[2][2] = {};
    const int arow = tid >> 2, acol = (tid & 3) * 8;

    for (int k0 = 0; k0 < Kpad; k0 += 32) {
        *(uint4*)&Al[arow][acol] =
            *(const uint4*)&A[(size_t)(m0 + arow) * lda + k0 + acol];
        *(uint4*)&Bl[arow][acol] =
            *(const uint4*)&BT[(size_t)(n0 + arow) * ldb + k0 + acol];
        __syncthreads();
        #pragma unroll
        for (int mt = 0; mt < 2; ++mt) {
            bf16x8 a = ld_bf8(&Al[wm * 32 + mt * 16 + lr][g * 8]);
            #pragma unroll
            for (int nt = 0; nt < 2; ++nt) {
                bf16x8 b = ld_bf8(&Bl[wn * 32 + nt * 16 + lr][g * 8]);
                acc[mt][nt] = __builtin_amdgcn_mfma_f32_16x16x32_bf16(a, b, acc[mt][nt], 0, 0, 0);
            }
        }
        __syncthreads();
    }

    const int f32o = flagp ? *flagp : 0;
    #pragma unroll
    for (int mt = 0; mt < 2; ++mt)
    #pragma unroll
    for (int nt = 0; nt < 2; ++nt)
    #pragma unroll
    for (int r = 0; r < 4; ++r) {
        int gm = m0 + wm * 32 + mt * 16 + g * 4 + r;
        int gn = n0 + wn * 32 + nt * 16 + lr;
        if (gn >= N) continue;
        float v = acc[mt][nt][r];
        if (mode == 0) {
            ((float*)C0)[(size_t)gm * ldc + gn] = v;
        } else if (mode == 1) {
            if (f32o) C0f[(size_t)gm * ldc + gn] = v;
            else ((bf16*)C0)[(size_t)gm * ldc + gn] = __float2bfloat16(v);
        } else if (mode == 2) {
            int h = gn >> 6, dh = gn & 63;
            int b = gm >> 11, s = gm & 2047;
            ((bf16*)C0)[((size_t)(b * NH + h) * SEQ + s) * DQKPAD + dh] = __float2bfloat16(v);
        } else { // mode 3: K scatter [bh][s][96]; V scatter TRANSPOSED [bh][64][2048]
            int b = gm >> 11, s = gm & 2047;
            if (gn < DM) {
                int h = gn >> 6, dh = gn & 63;
                kv_k[((size_t)(b * NH + h) * SEQ + s) * DQKPAD + dh] = __float2bfloat16(v);
            } else {
                int c = gn - DM;
                int h = c >> 6, dv = c & 63;
                kv_v[((size_t)(b * NH + h) * DHD + dv) * SEQ + s] = __float2bfloat16(v);
            }
        }
    }
}

// ---------------- row layernorm (fp32 in; O1 dual-dtype, O2 bf16) ----------------
__global__ __launch_bounds__(256) void ln_row(
    const float* __restrict__ Y, int N,
    const bf16* __restrict__ gam, const bf16* __restrict__ bet,
    bf16* __restrict__ O1, float* __restrict__ O1f, const int* __restrict__ flagp, int ld1,
    bf16* __restrict__ O2, int ld2, int padN)
{
    int row = blockIdx.x;
    const float* y = Y + (size_t)row * N;
    int tid = threadIdx.x;
    const int f32o = flagp ? *flagp : 0;
    float s = 0.f, ss = 0.f;
    for (int i = tid; i < N; i += 256) { float v = y[i]; s += v; ss += v * v; }
    #pragma unroll
    for (int m = 1; m < 64; m <<= 1) { s += __shfl_xor(s, m); ss += __shfl_xor(ss, m); }
    __shared__ float red[2][4];
    int w = tid >> 6;
    if ((tid & 63) == 0) { red[0][w] = s; red[1][w] = ss; }
    __syncthreads();
    s = red[0][0] + red[0][1] + red[0][2] + red[0][3];
    ss = red[1][0] + red[1][1] + red[1][2] + red[1][3];
    float mean = s / N;
    float var = ss / N - mean * mean;
    float rstd = rsqrtf(var + 1e-5f);
    for (int i = tid; i < N; i += 256) {
        float v = (y[i] - mean) * rstd * __bfloat162float(gam[i]) + __bfloat162float(bet[i]);
        if (f32o) O1f[(size_t)row * ld1 + i] = v;
        else O1[(size_t)row * ld1 + i] = __float2bfloat16(v);
        if (O2) O2[(size_t)row * ld2 + i] = __float2bfloat16(v);
    }
    if (O2) for (int i = N + tid; i < padN; i += 256) O2[(size_t)row * ld2 + i] = __float2bfloat16(0.f);
}

// ---------------- rope + pad fill for q/k rope tails ----------------
__global__ __launch_bounds__(256) void rope_fill(
    const float* __restrict__ yqr, const float* __restrict__ ykr,
    bf16* __restrict__ qa, bf16* __restrict__ ka)
{
    int idx = blockIdx.x * 256 + threadIdx.x;
    if (idx >= MROWS * NH) return;
    int m = idx >> 3, h = idx & 7;
    int b = m >> 11, s = m & 2047;
    float q[8], k[8], qo[8], ko[8];
    #pragma unroll
    for (int j = 0; j < 8; ++j) {
        q[j] = yqr[(size_t)m * 64 + h * 8 + j];
        k[j] = ykr[(size_t)m * 64 + h * 8 + j];
    }
    #pragma unroll
    for (int i = 0; i < 4; ++i) {
        float inv = exp2f(-(float)i * 3.3219280948873623f);  // 10000^(-i/4)
        float ang = (float)s * inv;
        float sn, cs;
        sincosf(ang, &sn, &cs);
        qo[i] = q[i] * cs - q[i + 4] * sn;
        qo[i + 4] = q[i + 4] * cs + q[i] * sn;
        ko[i] = k[i] * cs - k[i + 4] * sn;
        ko[i + 4] = k[i + 4] * cs + k[i] * sn;
    }
    bf16* qp = qa + ((size_t)(b * NH + h) * SEQ + s) * DQKPAD;
    bf16* kp = ka + ((size_t)(b * NH + h) * SEQ + s) * DQKPAD;
    #pragma unroll
    for (int j = 0; j < 8; ++j) {
        qp[64 + j] = __float2bfloat16(qo[j]);
        kp[64 + j] = __float2bfloat16(ko[j]);
    }
    #pragma unroll
    for (int j = 72; j < 96; ++j) {
        qp[j] = __float2bfloat16(0.f);
        kp[j] = __float2bfloat16(0.f);
    }
}

// ---------------- causal flash attention, split-KV (4 splits) ----------------
// grid (4 splits, 32 q-tiles, 16 bh); block 256 (4 waves x 16 q-rows).
// Partials: po (bf16, un-normalized O), mlm/mll (fp32 running max / sum).
__global__ __launch_bounds__(256) void attn_split(
    const bf16* __restrict__ qa, const bf16* __restrict__ ka, const bf16* __restrict__ vat,
    bf16* __restrict__ po, float* __restrict__ mlm, float* __restrict__ mll)
{
    __shared__ __align__(16) bf16 Kl[64][104];
    __shared__ __align__(16) bf16 Vt[64][72];
    __shared__ __align__(16) bf16 Pl[4][16][72];
    const int sp = blockIdx.x, qb = blockIdx.y, bh = blockIdx.z;
    const int tid = threadIdx.x, w = tid >> 6, lane = tid & 63;
    const int g = lane >> 4, lr = lane & 15;
    const size_t base = (size_t)bh * SEQ;
    const int qrow0 = qb * 64 + w * 16;

    bf16x8 qf[3];
    #pragma unroll
    for (int kc = 0; kc < 3; ++kc)
        qf[kc] = ld_bf8(&qa[(base + qrow0 + lr) * DQKPAD + kc * 32 + g * 8]);

    float m_r[4], l_r[4];
    f32x4 acc_o[4] = {};
    #pragma unroll
    for (int r = 0; r < 4; ++r) { m_r[r] = -1e30f; l_r[r] = 0.f; }

    const int ng = qb + 1;                       // 64-key granules in this q-tile's range
    const int bs = (ng * sp) >> 2, be = (ng * (sp + 1)) >> 2;
    const float SC = 0.11785113019775793f;       // 1/sqrt(72)
    const float L2E = 1.4426950408889634f;

    for (int gi = bs; gi < be; ++gi) {
        const int j0 = gi * 64;
        __syncthreads();
        for (int u = tid; u < 768; u += 256) {   // K tile: 64 rows x 96
            int row = u / 12, cc = (u % 12) * 8;
            *(uint4*)&Kl[row][cc] = *(const uint4*)&ka[(base + j0 + row) * DQKPAD + cc];
        }
        {                                        // V^T tile: 64 d x 64 keys
            int d = tid >> 2, ko = (tid & 3) * 16;
            const bf16* vsrc = &vat[((size_t)bh * DHD + d) * SEQ + j0 + ko];
            *(uint4*)&Vt[d][ko]     = *(const uint4*)vsrc;
            *(uint4*)&Vt[d][ko + 8] = *(const uint4*)(vsrc + 8);
        }
        __syncthreads();

        f32x4 accs[4] = {};
        #pragma unroll
        for (int kc = 0; kc < 3; ++kc) {
            #pragma unroll
            for (int nt = 0; nt < 4; ++nt) {
                bf16x8 kf = ld_bf8(&Kl[nt * 16 + lr][kc * 32 + g * 8]);
                accs[nt] = __builtin_amdgcn_mfma_f32_16x16x32_bf16(qf[kc], kf, accs[nt], 0, 0, 0);
            }
        }
        float pv2[4][4];
        #pragma unroll
        for (int nt = 0; nt < 4; ++nt)
        #pragma unroll
        for (int r = 0; r < 4; ++r) {
            int jj = j0 + nt * 16 + lr;
            int qr = qrow0 + g * 4 + r;
            float sv = accs[nt][r] * SC;
            pv2[nt][r] = (jj <= qr) ? sv : -1e30f;
        }
        #pragma unroll
        for (int r = 0; r < 4; ++r) {
            float rm = fmaxf(fmaxf(pv2[0][r], pv2[1][r]), fmaxf(pv2[2][r], pv2[3][r]));
            rm = fmaxf(rm, __shfl_xor(rm, 1));
            rm = fmaxf(rm, __shfl_xor(rm, 2));
            rm = fmaxf(rm, __shfl_xor(rm, 4));
            rm = fmaxf(rm, __shfl_xor(rm, 8));
            float mn = fmaxf(m_r[r], rm);
            float alpha = exp2f((m_r[r] - mn) * L2E);
            m_r[r] = mn;
            float rs = 0.f;
            #pragma unroll
            for (int nt = 0; nt < 4; ++nt) {
                float p = exp2f((pv2[nt][r] - mn) * L2E);
                pv2[nt][r] = p; rs += p;
            }
            rs += __shfl_xor(rs, 1); rs += __shfl_xor(rs, 2);
            rs += __shfl_xor(rs, 4); rs += __shfl_xor(rs, 8);
            l_r[r] = l_r[r] * alpha + rs;
            #pragma unroll
            for (int nv = 0; nv < 4; ++nv) acc_o[nv][r] *= alpha;
        }
        #pragma unroll
        for (int nt = 0; nt < 4; ++nt)
        #pragma unroll
        for (int r = 0; r < 4; ++r)
            Pl[w][g * 4 + r][nt * 16 + lr] = __float2bfloat16(pv2[nt][r]);
        bf16x8 pf0 = ld_bf8(&Pl[w][lr][g * 8]);
        bf16x8 pf1 = ld_bf8(&Pl[w][lr][32 + g * 8]);
        #pragma unroll
        for (int nv = 0; nv < 4; ++nv) {
            bf16x8 vf0 = ld_bf8(&Vt[nv * 16 + lr][g * 8]);
            acc_o[nv] = __builtin_amdgcn_mfma_f32_16x16x32_bf16(pf0, vf0, acc_o[nv], 0, 0, 0);
            bf16x8 vf1 = ld_bf8(&Vt[nv * 16 + lr][32 + g * 8]);
            acc_o[nv] = __builtin_amdgcn_mfma_f32_16x16x32_bf16(pf1, vf1, acc_o[nv], 0, 0, 0);
        }
    }

    const size_t pb = (size_t)(bh * 4 + sp) * SEQ;
    #pragma unroll
    for (int r = 0; r < 4; ++r) {
        int qrow = qrow0 + g * 4 + r;
        #pragma unroll
        for (int nv = 0; nv < 4; ++nv)
            po[(pb + qrow) * DHD + nv * 16 + lr] = __float2bfloat16(acc_o[nv][r]);
        if (lr == 0) { mlm[pb + qrow] = m_r[r]; mll[pb + qrow] = l_r[r]; }
    }
}

// ---------------- combine split partials -> attn_o [b][s][h*64+d] ----------------
__global__ __launch_bounds__(256) void attn_combine(
    const bf16* __restrict__ po, const float* __restrict__ mlm, const float* __restrict__ mll,
    bf16* __restrict__ ao)
{
    int id = blockIdx.x * 256 + threadIdx.x;   // 16*2048*8 = 262144
    int bh = id >> 14;
    int rem = id & 16383;
    int q = rem >> 3, dc = (rem & 7) * 8;
    const float L2E = 1.4426950408889634f;
    size_t mlb = (size_t)bh * 4 * SEQ + q;
    float ms[4], ls[4];
    #pragma unroll
    for (int s = 0; s < 4; ++s) { ms[s] = mlm[mlb + (size_t)s * SEQ]; ls[s] = mll[mlb + (size_t)s * SEQ]; }
    float M = fmaxf(fmaxf(ms[0], ms[1]), fmaxf(ms[2], ms[3]));
    float wsc[4]; float L = 0.f;
    #pragma unroll
    for (int s = 0; s < 4; ++s) { wsc[s] = exp2f((ms[s] - M) * L2E); L += wsc[s] * ls[s]; }
    float o[8] = {};
    #pragma unroll
    for (int s = 0; s < 4; ++s) {
        bf16x8 pv = ld_bf8(&po[((size_t)(bh * 4 + s) * SEQ + q) * DHD + dc]);
        #pragma unroll
        for (int j = 0; j < 8; ++j) o[j] += wsc[s] * (float)pv[j];
    }
    float invL = 1.f / L;
    int b = bh >> 3, h = bh & 7;
    __bf16 tmp[8];
    #pragma unroll
    for (int j = 0; j < 8; ++j) tmp[j] = (__bf16)(o[j] * invL);
    *(uint4*)&ao[((size_t)(b * SEQ) + q) * DM + h * DHD + dc] = *(uint4*)tmp;
}

extern "C" void kernel_launch(void* const* d_in, const int* in_sizes, int n_in,
                              void* d_out, int out_size, void* d_ws, size_t ws_size,
                              hipStream_t stream) {
    char* ws = (char*)d_ws;
    bf16* AR      = (bf16*)(ws + 0);              // bf16 arena (x dead after gemms 1-3)
    float* ml_m   = (float*)(ws + 0);             // alias x region (written by attn)
    float* ml_l   = (float*)(ws + 524288);
    bf16* WT      = (bf16*)(ws + 6391296);        // transposed weights (1,736,704 B)
    int*  flagp   = (int*)(ws + 8128000);
    float* y_dq   = (float*)(ws + 8128512);
    float* y_dkv  = (float*)(ws + 12322816);
    float* y_kr   = (float*)(ws + 17909760);
    float* y_qr   = (float*)(ws + 18958336);
    bf16* cq      = (bf16*)(ws + 20006912);
    bf16* ckvp    = (bf16*)(ws + 22104064);
    bf16* po      = (bf16*)(ws + 8128512);        // alias dead y/cq/ckvp region (16.78MB)
    bf16* q_attn  = (bf16*)(ws + 24987648);
    bf16* k_attn  = (bf16*)(ws + 31279104);
    bf16* v_attnT = (bf16*)(ws + 37570560);
    bf16* attn_o  = (bf16*)(ws + 41764864);

    const bf16* xb  = AR + OFF_X;
    const bf16* W_o = AR + OFF_WO;
    const bf16* qg  = AR + OFF_QG;
    const bf16* qb_ = AR + OFF_QB;
    const bf16* kg  = AR + OFF_KG;
    const bf16* kb  = AR + OFF_KB;

    bf16*  out_b = (bf16*)d_out;
    float* out_f = (float*)d_out;
    bf16*  ckv_b = out_b + (size_t)MROWS * DM;
    float* ckv_f = out_f + (size_t)MROWS * DM;

    dim3 blk(256);
    detect_k<<<1, blk, 0, stream>>>((const u16*)d_in[0], flagp);
    cvt_all<<<dim3((N_ELEMS + 255) / 256), blk, 0, stream>>>(
        d_in[0], d_in[1], d_in[2], d_in[3], d_in[4], d_in[5],
        d_in[6], d_in[7], d_in[8], d_in[9], d_in[10], d_in[11],
        (u16*)AR, flagp);
    wt_all<<<dim3((T_TOT + 255) / 256), blk, 0, stream>>>(AR, WT);

    // low-rank projections from x
    gemm64<<<dim3(4, 64), blk, 0, stream>>>(xb, DM, WT + T_DQ, DM, QP, DM, 0, y_dq, QP, nullptr, nullptr, nullptr, nullptr);
    gemm64<<<dim3(6, 64), blk, 0, stream>>>(xb, DM, WT + T_DKV, DM, KVP, DM, 0, y_dkv, KVP, nullptr, nullptr, nullptr, nullptr);
    gemm64<<<dim3(1, 64), blk, 0, stream>>>(xb, DM, WT + T_KR, DM, 64, DM, 0, y_kr, 64, nullptr, nullptr, nullptr, nullptr);
    // layernorms
    ln_row<<<MROWS, blk, 0, stream>>>(y_dq, QP, qg, qb_, cq, nullptr, nullptr, QP, nullptr, 0, 0);
    ln_row<<<MROWS, blk, 0, stream>>>(y_dkv, KVP, kg, kb, ckv_b, ckv_f, flagp, KVP, ckvp, KVPAD, KVPAD);
    // up-projections
    gemm64<<<dim3(8, 64), blk, 0, stream>>>(cq, QP, WT + T_UQ, QP, DM, QP, 2, q_attn, 0, nullptr, nullptr, nullptr, nullptr);
    gemm64<<<dim3(1, 64), blk, 0, stream>>>(cq, QP, WT + T_QR, QP, 64, QP, 0, y_qr, 64, nullptr, nullptr, nullptr, nullptr);
    gemm64<<<dim3(16, 64), blk, 0, stream>>>(ckvp, KVPAD, WT + T_UKV, KVPAD, 1024, KVPAD, 3, nullptr, 0, k_attn, v_attnT, nullptr, nullptr);
    // rope tails + pad zeros
    rope_fill<<<dim3(MROWS * NH / 256), blk, 0, stream>>>(y_qr, y_kr, q_attn, k_attn);
    // attention (split-KV) + combine
    attn_split<<<dim3(4, SEQ / 64, 16), blk, 0, stream>>>(q_attn, k_attn, v_attnT, po, ml_m, ml_l);
    attn_combine<<<dim3(16 * SEQ * 8 / 256), blk, 0, stream>>>(po, ml_m, ml_l, attn_o);
    // output projection (W_o rows are already [N][K]) -> d_out (dual dtype)
    gemm64<<<dim3(8, 64), blk, 0, stream>>>(attn_o, DM, W_o, DM, DM, DM, 1, out_b, DM, nullptr, nullptr, flagp, out_f);
}

// Round 6
// 172.193 us; speedup vs baseline: 2.3186x; 1.0464x over previous
//
#include <hip/hip_runtime.h>
#include <hip/hip_bf16.h>

#define BATCH 2
#define SEQ 2048
#define DM 512
#define NH 8
#define DHD 64
#define QP 256
#define KVP 341
#define DQKPAD 96
#define MROWS 4096   // BATCH*SEQ

// bf16 arena element offsets (cumulative over setup_inputs order)
#define OFF_X     0
#define OFF_WDQ   2097152
#define OFF_WUQ   2228224
#define OFF_WQR   2359296
#define OFF_WDKV  2375680
#define OFF_WUKV  2550272
#define OFF_WKR   2899456
#define OFF_WO    2932224
#define OFF_QG    3194368
#define OFF_QB    3194624
#define OFF_KG    3194880
#define OFF_KB    3195221
#define N_ELEMS   3195562

// transposed-weight arena element offsets ([N][K], K padded)
#define T_DQ   0        // [256][512]
#define T_DKV  131072   // [384][512] (n>=341 zero)
#define T_KR   327680   // [64][512]
#define T_UQ   360448   // [512][256]
#define T_QR   491520   // [64][256]
#define T_UKV  507904   // [1024][384] (k>=341 zero)
#define T_TOT  901120

typedef __bf16 bf16x8 __attribute__((ext_vector_type(8)));
typedef float f32x4 __attribute__((ext_vector_type(4)));
typedef __hip_bfloat16 bf16;
typedef unsigned short u16;

static __device__ __forceinline__ bf16x8 ld_bf8(const bf16* p) {
    return __builtin_bit_cast(bf16x8, *(const uint4*)p);
}

// ---------------- dtype detect: bf16 vs fp32 device buffers ----------------
__global__ void detect_k(const u16* __restrict__ x, int* __restrict__ flagp) {
    __shared__ int cnt;
    if (threadIdx.x == 0) cnt = 0;
    __syncthreads();
    int bad = 0;
    for (int i = threadIdx.x; i < 2048; i += 256) {
        u16 u = x[i];
        int e = (u >> 7) & 0xFF;
        if (u != 0 && (e < 90 || e > 164)) bad++;
    }
    atomicAdd(&cnt, bad);
    __syncthreads();
    if (threadIdx.x == 0) *flagp = (cnt > 256) ? 1 : 0;  // 1 => inputs are fp32
}

// ---------------- convert/copy all inputs into bf16 arena ----------------
__global__ __launch_bounds__(256) void cvt_all(
    const void* s0, const void* s1, const void* s2, const void* s3,
    const void* s4, const void* s5, const void* s6, const void* s7,
    const void* s8, const void* s9, const void* s10, const void* s11,
    u16* __restrict__ arena, const int* __restrict__ flagp)
{
    int gid = blockIdx.x * 256 + threadIdx.x;
    if (gid >= N_ELEMS) return;
    const int f = *flagp;
    const void* src; int base;
    if      (gid < OFF_WDQ)  { src = s0;  base = OFF_X; }
    else if (gid < OFF_WUQ)  { src = s1;  base = OFF_WDQ; }
    else if (gid < OFF_WQR)  { src = s2;  base = OFF_WUQ; }
    else if (gid < OFF_WDKV) { src = s3;  base = OFF_WQR; }
    else if (gid < OFF_WUKV) { src = s4;  base = OFF_WDKV; }
    else if (gid < OFF_WKR)  { src = s5;  base = OFF_WUKV; }
    else if (gid < OFF_WO)   { src = s6;  base = OFF_WKR; }
    else if (gid < OFF_QG)   { src = s7;  base = OFF_WO; }
    else if (gid < OFF_QB)   { src = s8;  base = OFF_QG; }
    else if (gid < OFF_KG)   { src = s9;  base = OFF_QB; }
    else if (gid < OFF_KB)   { src = s10; base = OFF_KG; }
    else                     { src = s11; base = OFF_KB; }
    int local = gid - base;
    u16 v;
    if (f) {
        float xv = ((const float*)src)[local];
        v = __builtin_bit_cast(u16, __float2bfloat16(xv));
    } else {
        v = ((const u16*)src)[local];
    }
    arena[gid] = v;
}

// ---------------- transpose + zero-pad all weights into WT arena ----------------
__global__ __launch_bounds__(256) void wt_all(const bf16* __restrict__ AR, bf16* __restrict__ WT) {
    int gid = blockIdx.x * 256 + threadIdx.x;
    if (gid >= T_TOT) return;
    const bf16* src; int base, Kp, Nv, Kv;
    if      (gid < T_DKV) { base = T_DQ;  Kp = 512; src = AR + OFF_WDQ;  Nv = 256;  Kv = 512; }
    else if (gid < T_KR)  { base = T_DKV; Kp = 512; src = AR + OFF_WDKV; Nv = 341;  Kv = 512; }
    else if (gid < T_UQ)  { base = T_KR;  Kp = 512; src = AR + OFF_WKR;  Nv = 64;   Kv = 512; }
    else if (gid < T_QR)  { base = T_UQ;  Kp = 256; src = AR + OFF_WUQ;  Nv = 512;  Kv = 256; }
    else if (gid < T_UKV) { base = T_QR;  Kp = 256; src = AR + OFF_WQR;  Nv = 64;   Kv = 256; }
    else                  { base = T_UKV; Kp = 384; src = AR + OFF_WUKV; Nv = 1024; Kv = 341; }
    int loc = gid - base;
    int n = loc / Kp, k = loc % Kp;
    bf16 v = __float2bfloat16(0.f);
    if (n < Nv && k < Kv) v = src[(size_t)k * Nv + n];
    WT[gid] = v;
}

// ------- 128x64 bf16 MFMA GEMM, BK=64, B pre-transposed [N][K] -------
// 4 waves, each 32(M)x64(N). modes: 0 fp32->C0(ldc); 1 dual->C0/C0f;
// 3 KV-scatter (K rows + V^T); 4 Q-scatter (gn<512) + y_qr fp32 tail.
__global__ __launch_bounds__(256) void gemm128(
    const bf16* __restrict__ A, int lda,
    const bf16* __restrict__ BT, int ldb,
    int N, int Kpad, int mode,
    void* __restrict__ C0, int ldc,
    bf16* __restrict__ kv_k, bf16* __restrict__ kv_v,
    const int* __restrict__ flagp, float* __restrict__ C0f)
{
    __shared__ __align__(16) bf16 Al[128][72];
    __shared__ __align__(16) bf16 Bl[64][72];
    const int tid = threadIdx.x;
    const int m0 = blockIdx.y * 128, n0 = blockIdx.x * 64;
    const int lane = tid & 63, w = tid >> 6;
    const int g = lane >> 4, lr = lane & 15;
    f32x4 acc[2][4] = {};
    const int srow = tid >> 3, scol = (tid & 7) * 8;

    for (int k0 = 0; k0 < Kpad; k0 += 64) {
        #pragma unroll
        for (int p = 0; p < 4; ++p)
            *(uint4*)&Al[p * 32 + srow][scol] =
                *(const uint4*)&A[(size_t)(m0 + p * 32 + srow) * lda + k0 + scol];
        #pragma unroll
        for (int p = 0; p < 2; ++p)
            *(uint4*)&Bl[p * 32 + srow][scol] =
                *(const uint4*)&BT[(size_t)(n0 + p * 32 + srow) * ldb + k0 + scol];
        __syncthreads();
        #pragma unroll
        for (int ks = 0; ks < 2; ++ks) {
            bf16x8 a0 = ld_bf8(&Al[w * 32 + lr][ks * 32 + g * 8]);
            bf16x8 a1 = ld_bf8(&Al[w * 32 + 16 + lr][ks * 32 + g * 8]);
            #pragma unroll
            for (int nt = 0; nt < 4; ++nt) {
                bf16x8 b = ld_bf8(&Bl[nt * 16 + lr][ks * 32 + g * 8]);
                acc[0][nt] = __builtin_amdgcn_mfma_f32_16x16x32_bf16(a0, b, acc[0][nt], 0, 0, 0);
                acc[1][nt] = __builtin_amdgcn_mfma_f32_16x16x32_bf16(a1, b, acc[1][nt], 0, 0, 0);
            }
        }
        __syncthreads();
    }

    const int f32o = (mode == 1 && flagp) ? *flagp : 0;
    #pragma unroll
    for (int mt = 0; mt < 2; ++mt)
    #pragma unroll
    for (int nt = 0; nt < 4; ++nt)
    #pragma unroll
    for (int r = 0; r < 4; ++r) {
        int gm = m0 + w * 32 + mt * 16 + g * 4 + r;
        int gn = n0 + nt * 16 + lr;
        float v = acc[mt][nt][r];
        if (mode == 0) {
            ((float*)C0)[(size_t)gm * ldc + gn] = v;
        } else if (mode == 1) {
            if (f32o) C0f[(size_t)gm * ldc + gn] = v;
            else ((bf16*)C0)[(size_t)gm * ldc + gn] = __float2bfloat16(v);
        } else if (mode == 4) {
            int b = gm >> 11, s = gm & 2047;
            if (gn < DM) {
                int h = gn >> 6, dh = gn & 63;
                ((bf16*)C0)[((size_t)(b * NH + h) * SEQ + s) * DQKPAD + dh] = __float2bfloat16(v);
            } else {
                C0f[(size_t)gm * 64 + (gn - DM)] = v;
            }
        } else { // mode 3: K scatter [bh][s][96]; V scatter TRANSPOSED [bh][64][2048]
            int b = gm >> 11, s = gm & 2047;
            if (gn < DM) {
                int h = gn >> 6, dh = gn & 63;
                kv_k[((size_t)(b * NH + h) * SEQ + s) * DQKPAD + dh] = __float2bfloat16(v);
            } else {
                int c = gn - DM;
                int h = c >> 6, dv = c & 63;
                kv_v[((size_t)(b * NH + h) * DHD + dv) * SEQ + s] = __float2bfloat16(v);
            }
        }
    }
}

// ---------------- row layernorm (fp32 in, strided; O1 dual-dtype, O2 bf16) ----
__global__ __launch_bounds__(256) void ln_row(
    const float* __restrict__ Y, int ldy, int N,
    const bf16* __restrict__ gam, const bf16* __restrict__ bet,
    bf16* __restrict__ O1, float* __restrict__ O1f, const int* __restrict__ flagp, int ld1,
    bf16* __restrict__ O2, int ld2, int padN)
{
    int row = blockIdx.x;
    const float* y = Y + (size_t)row * ldy;
    int tid = threadIdx.x;
    const int f32o = flagp ? *flagp : 0;
    float s = 0.f, ss = 0.f;
    for (int i = tid; i < N; i += 256) { float v = y[i]; s += v; ss += v * v; }
    #pragma unroll
    for (int m = 1; m < 64; m <<= 1) { s += __shfl_xor(s, m); ss += __shfl_xor(ss, m); }
    __shared__ float red[2][4];
    int w = tid >> 6;
    if ((tid & 63) == 0) { red[0][w] = s; red[1][w] = ss; }
    __syncthreads();
    s = red[0][0] + red[0][1] + red[0][2] + red[0][3];
    ss = red[1][0] + red[1][1] + red[1][2] + red[1][3];
    float mean = s / N;
    float var = ss / N - mean * mean;
    float rstd = rsqrtf(var + 1e-5f);
    for (int i = tid; i < N; i += 256) {
        float v = (y[i] - mean) * rstd * __bfloat162float(gam[i]) + __bfloat162float(bet[i]);
        if (f32o) O1f[(size_t)row * ld1 + i] = v;
        else O1[(size_t)row * ld1 + i] = __float2bfloat16(v);
        if (O2) O2[(size_t)row * ld2 + i] = __float2bfloat16(v);
    }
    if (O2) for (int i = N + tid; i < padN; i += 256) O2[(size_t)row * ld2 + i] = __float2bfloat16(0.f);
}

// ---------------- rope + pad fill for q/k rope tails ----------------
__global__ __launch_bounds__(256) void rope_fill(
    const float* __restrict__ yqr, int ldq,
    const float* __restrict__ ykr, int ldk,
    bf16* __restrict__ qa, bf16* __restrict__ ka)
{
    int idx = blockIdx.x * 256 + threadIdx.x;
    if (idx >= MROWS * NH) return;
    int m = idx >> 3, h = idx & 7;
    int b = m >> 11, s = m & 2047;
    float q[8], k[8], qo[8], ko[8];
    #pragma unroll
    for (int j = 0; j < 8; ++j) {
        q[j] = yqr[(size_t)m * ldq + h * 8 + j];
        k[j] = ykr[(size_t)m * ldk + h * 8 + j];
    }
    #pragma unroll
    for (int i = 0; i < 4; ++i) {
        float inv = exp2f(-(float)i * 3.3219280948873623f);  // 10000^(-i/4)
        float ang = (float)s * inv;
        float sn, cs;
        sincosf(ang, &sn, &cs);
        qo[i] = q[i] * cs - q[i + 4] * sn;
        qo[i + 4] = q[i + 4] * cs + q[i] * sn;
        ko[i] = k[i] * cs - k[i + 4] * sn;
        ko[i + 4] = k[i + 4] * cs + k[i] * sn;
    }
    bf16* qp = qa + ((size_t)(b * NH + h) * SEQ + s) * DQKPAD;
    bf16* kp = ka + ((size_t)(b * NH + h) * SEQ + s) * DQKPAD;
    #pragma unroll
    for (int j = 0; j < 8; ++j) {
        qp[64 + j] = __float2bfloat16(qo[j]);
        kp[64 + j] = __float2bfloat16(ko[j]);
    }
    #pragma unroll
    for (int j = 72; j < 96; ++j) {
        qp[j] = __float2bfloat16(0.f);
        kp[j] = __float2bfloat16(0.f);
    }
}

// ------- barrier-free causal flash attention, split-KV, swapped QK^T -------
// grid 2048 1D: xcd=id&7 -> 2 bh per XCD (L2 residency); 4 waves x 16 q-rows.
// K,V^T fragments read direct from global (L1/L2); only P goes through LDS.
__global__ __launch_bounds__(256) void attn_split2(
    const bf16* __restrict__ qa, const bf16* __restrict__ ka, const bf16* __restrict__ vat,
    bf16* __restrict__ po, float* __restrict__ mlm, float* __restrict__ mll)
{
    __shared__ __align__(16) bf16 Pl[4][16][72];
    const int id = blockIdx.x;
    const int xcd = id & 7, idx = id >> 3;
    const int bh = xcd * 2 + (idx >> 7);
    const int rest = idx & 127;
    const int sp = rest & 3, qb = rest >> 2;
    const int tid = threadIdx.x, w = tid >> 6, lane = tid & 63;
    const int g = lane >> 4, lr = lane & 15;
    const size_t base = (size_t)bh * SEQ;
    const int qrow0 = qb * 64 + w * 16;
    const int myq = qrow0 + lr;

    bf16x8 qf[3];
    #pragma unroll
    for (int kc = 0; kc < 3; ++kc)
        qf[kc] = ld_bf8(&qa[(base + myq) * DQKPAD + kc * 32 + g * 8]);

    float m_p = -1e30f, l_p = 0.f;     // per-lane state for q-row = myq
    f32x4 acc_o[4] = {};
    const int ng = qb + 1;
    const int bs = (ng * sp) >> 2, be = (ng * (sp + 1)) >> 2;
    const float SC = 0.11785113019775793f;   // 1/sqrt(72)
    const float L2E = 1.4426950408889634f;
    const bf16* vb = vat + (size_t)bh * DHD * SEQ;

    for (int gi = bs; gi < be; ++gi) {
        const int j0 = gi * 64;
        const bf16* kb = ka + (base + j0) * DQKPAD;
        f32x4 accs[4] = {};
        #pragma unroll
        for (int kc = 0; kc < 3; ++kc) {
            #pragma unroll
            for (int nt = 0; nt < 4; ++nt) {
                bf16x8 kf = ld_bf8(&kb[(size_t)(nt * 16 + lr) * DQKPAD + kc * 32 + g * 8]);
                accs[nt] = __builtin_amdgcn_mfma_f32_16x16x32_bf16(kf, qf[kc], accs[nt], 0, 0, 0);
            }
        }
        // lane owns q=myq; its keys are j0 + nt*16 + g*4 + r
        float s[4][4];
        float mloc = -1e30f;
        #pragma unroll
        for (int nt = 0; nt < 4; ++nt)
        #pragma unroll
        for (int r = 0; r < 4; ++r) {
            int key = j0 + nt * 16 + g * 4 + r;
            float sv = accs[nt][r] * SC;
            sv = (key <= myq) ? sv : -1e30f;
            s[nt][r] = sv;
            mloc = fmaxf(mloc, sv);
        }
        mloc = fmaxf(mloc, __shfl_xor(mloc, 16));
        mloc = fmaxf(mloc, __shfl_xor(mloc, 32));
        float mn = fmaxf(m_p, mloc);
        float alpha = exp2f((m_p - mn) * L2E);
        m_p = mn;
        float rs = 0.f;
        #pragma unroll
        for (int nt = 0; nt < 4; ++nt)
        #pragma unroll
        for (int r = 0; r < 4; ++r) {
            float p = exp2f((s[nt][r] - mn) * L2E);
            s[nt][r] = p; rs += p;
        }
        rs += __shfl_xor(rs, 16);
        rs += __shfl_xor(rs, 32);
        l_p = l_p * alpha + rs;
        float ar[4];
        #pragma unroll
        for (int r = 0; r < 4; ++r) ar[r] = __shfl(alpha, g * 4 + r);
        #pragma unroll
        for (int nv = 0; nv < 4; ++nv)
        #pragma unroll
        for (int r = 0; r < 4; ++r) acc_o[nv][r] *= ar[r];
        // P -> wave-private LDS in [q][k] layout (packed 8B writes)
        #pragma unroll
        for (int nt = 0; nt < 4; ++nt) {
            ushort4 pk;
            pk.x = __builtin_bit_cast(u16, __float2bfloat16(s[nt][0]));
            pk.y = __builtin_bit_cast(u16, __float2bfloat16(s[nt][1]));
            pk.z = __builtin_bit_cast(u16, __float2bfloat16(s[nt][2]));
            pk.w = __builtin_bit_cast(u16, __float2bfloat16(s[nt][3]));
            *(ushort4*)&Pl[w][lr][nt * 16 + g * 4] = pk;
        }
        #pragma unroll
        for (int ks = 0; ks < 2; ++ks) {
            bf16x8 pf = ld_bf8(&Pl[w][lr][ks * 32 + g * 8]);
            #pragma unroll
            for (int nv = 0; nv < 4; ++nv) {
                bf16x8 vf = ld_bf8(&vb[(size_t)(nv * 16 + lr) * SEQ + j0 + ks * 32 + g * 8]);
                acc_o[nv] = __builtin_amdgcn_mfma_f32_16x16x32_bf16(pf, vf, acc_o[nv], 0, 0, 0);
            }
        }
    }

    const size_t pb = (size_t)(bh * 4 + sp) * SEQ;
    #pragma unroll
    for (int r = 0; r < 4; ++r) {
        int qrow = qrow0 + g * 4 + r;
        #pragma unroll
        for (int nv = 0; nv < 4; ++nv)
            po[(pb + qrow) * DHD + nv * 16 + lr] = __float2bfloat16(acc_o[nv][r]);
    }
    if (lane < 16) {
        mlm[pb + qrow0 + lane] = m_p;
        mll[pb + qrow0 + lane] = l_p;
    }
}

// ---------------- combine split partials -> attn_o [b][s][h*64+d] ----------------
__global__ __launch_bounds__(256) void attn_combine(
    const bf16* __restrict__ po, const float* __restrict__ mlm, const float* __restrict__ mll,
    bf16* __restrict__ ao)
{
    int id = blockIdx.x * 256 + threadIdx.x;   // 16*2048*8 = 262144
    int bh = id >> 14;
    int rem = id & 16383;
    int q = rem >> 3, dc = (rem & 7) * 8;
    const float L2E = 1.4426950408889634f;
    size_t mlb = (size_t)bh * 4 * SEQ + q;
    float ms[4], ls[4];
    #pragma unroll
    for (int s = 0; s < 4; ++s) { ms[s] = mlm[mlb + (size_t)s * SEQ]; ls[s] = mll[mlb + (size_t)s * SEQ]; }
    float M = fmaxf(fmaxf(ms[0], ms[1]), fmaxf(ms[2], ms[3]));
    float wsc[4]; float L = 0.f;
    #pragma unroll
    for (int s = 0; s < 4; ++s) { wsc[s] = exp2f((ms[s] - M) * L2E); L += wsc[s] * ls[s]; }
    float o[8] = {};
    #pragma unroll
    for (int s = 0; s < 4; ++s) {
        bf16x8 pv = ld_bf8(&po[((size_t)(bh * 4 + s) * SEQ + q) * DHD + dc]);
        #pragma unroll
        for (int j = 0; j < 8; ++j) o[j] += wsc[s] * (float)pv[j];
    }
    float invL = 1.f / L;
    int b = bh >> 3, h = bh & 7;
    __bf16 tmp[8];
    #pragma unroll
    for (int j = 0; j < 8; ++j) tmp[j] = (__bf16)(o[j] * invL);
    *(uint4*)&ao[((size_t)(b * SEQ) + q) * DM + h * DHD + dc] = *(uint4*)tmp;
}

extern "C" void kernel_launch(void* const* d_in, const int* in_sizes, int n_in,
                              void* d_out, int out_size, void* d_ws, size_t ws_size,
                              hipStream_t stream) {
    char* ws = (char*)d_ws;
    bf16* AR      = (bf16*)(ws + 0);              // bf16 arena (x dead after x-gemm)
    float* ml_m   = (float*)(ws + 0);             // alias x region
    float* ml_l   = (float*)(ws + 524288);
    bf16* WT      = (bf16*)(ws + 6391296);        // transposed weights (1,802,240 B)
    int*  flagp   = (int*)(ws + 8193536);
    float* y      = (float*)(ws + 8194048);       // fused x-proj out [4096][704] fp32
    float* y_qr   = (float*)(ws + 19728384);      // [4096][64] fp32
    bf16* cq      = (bf16*)(ws + 20776960);       // [4096][256]
    bf16* ckvp    = (bf16*)(ws + 22874112);       // [4096][384]
    bf16* po      = (bf16*)(ws + 8194048);        // alias dead y/y_qr/cq/ckvp (16.78MB)
    bf16* q_attn  = (bf16*)(ws + 26019840);
    bf16* k_attn  = (bf16*)(ws + 32311296);
    bf16* v_attnT = (bf16*)(ws + 38602752);
    bf16* attn_o  = (bf16*)(ws + 42797056);

    const bf16* xb  = AR + OFF_X;
    const bf16* W_o = AR + OFF_WO;
    const bf16* qg  = AR + OFF_QG;
    const bf16* qb_ = AR + OFF_QB;
    const bf16* kg  = AR + OFF_KG;
    const bf16* kb  = AR + OFF_KB;

    bf16*  out_b = (bf16*)d_out;
    float* out_f = (float*)d_out;
    bf16*  ckv_b = out_b + (size_t)MROWS * DM;
    float* ckv_f = out_f + (size_t)MROWS * DM;

    dim3 blk(256);
    detect_k<<<1, blk, 0, stream>>>((const u16*)d_in[0], flagp);
    cvt_all<<<dim3((N_ELEMS + 255) / 256), blk, 0, stream>>>(
        d_in[0], d_in[1], d_in[2], d_in[3], d_in[4], d_in[5],
        d_in[6], d_in[7], d_in[8], d_in[9], d_in[10], d_in[11],
        (u16*)AR, flagp);
    wt_all<<<dim3((T_TOT + 255) / 256), blk, 0, stream>>>(AR, WT);

    // fused low-rank projections from x: [dq(256) | dkv(384) | kr(64)] = N=704
    gemm128<<<dim3(11, 32), blk, 0, stream>>>(xb, DM, WT + T_DQ, DM, 704, DM, 0, y, 704, nullptr, nullptr, nullptr, nullptr);
    // layernorms (strided reads from fused y)
    ln_row<<<MROWS, blk, 0, stream>>>(y, 704, QP, qg, qb_, cq, nullptr, nullptr, QP, nullptr, 0, 0);
    ln_row<<<MROWS, blk, 0, stream>>>(y + 256, 704, KVP, kg, kb, ckv_b, ckv_f, flagp, KVP, ckvp, 384, 384);
    // fused cq up-projection: [uq(512) scatter | qr(64) fp32] = N=576
    gemm128<<<dim3(9, 32), blk, 0, stream>>>(cq, QP, WT + T_UQ, QP, 576, QP, 4, q_attn, 0, nullptr, nullptr, nullptr, y_qr);
    // kv up-projection (K scatter + V^T scatter)
    gemm128<<<dim3(16, 32), blk, 0, stream>>>(ckvp, 384, WT + T_UKV, 384, 1024, 384, 3, nullptr, 0, k_attn, v_attnT, nullptr, nullptr);
    // rope tails + pad zeros
    rope_fill<<<dim3(MROWS * NH / 256), blk, 0, stream>>>(y_qr, 64, y + 640, 704, q_attn, k_attn);
    // attention (barrier-free split-KV) + combine
    attn_split2<<<dim3(2048), blk, 0, stream>>>(q_attn, k_attn, v_attnT, po, ml_m, ml_l);
    attn_combine<<<dim3(16 * SEQ * 8 / 256), blk, 0, stream>>>(po, ml_m, ml_l, attn_o);
    // output projection (W_o rows are already [N][K]) -> d_out (dual dtype)
    gemm128<<<dim3(8, 32), blk, 0, stream>>>(attn_o, DM, W_o, DM, DM, DM, 1, out_b, DM, nullptr, nullptr, flagp, out_f);
}

// Round 7
// 167.344 us; speedup vs baseline: 2.3858x; 1.0290x over previous
//
#include <hip/hip_runtime.h>
#include <hip/hip_bf16.h>

#define BATCH 2
#define SEQ 2048
#define DM 512
#define NH 8
#define DHD 64
#define QP 256
#define KVP 341
#define DQKPAD 96
#define MROWS 4096   // BATCH*SEQ

// bf16 arena element offsets (cumulative over setup_inputs order)
#define OFF_X     0
#define OFF_WDQ   2097152
#define OFF_WUQ   2228224
#define OFF_WQR   2359296
#define OFF_WDKV  2375680
#define OFF_WUKV  2550272
#define OFF_WKR   2899456
#define OFF_WO    2932224
#define OFF_QG    3194368
#define OFF_QB    3194624
#define OFF_KG    3194880
#define OFF_KB    3195221
#define N_ELEMS   3195562

// transposed-weight arena ([N][K] rows, N padded to x128)
#define T_DQ   0        // fused x-proj [768][512]: dq(0-255) dkv(256-596) 0(597-639) kr(640-703) 0(704-767)
#define T_UQ   393216   // fused [640][256]: uq(0-511) qr(512-575) 0(576-639)
#define T_UKV  557056   // [1024][384] (k>=341 zero)
#define T_TOT  950272

typedef __bf16 bf16x8 __attribute__((ext_vector_type(8)));
typedef float f32x4 __attribute__((ext_vector_type(4)));
typedef __hip_bfloat16 bf16;
typedef unsigned short u16;

static __device__ __forceinline__ bf16x8 ld_bf8(const bf16* p) {
    return __builtin_bit_cast(bf16x8, *(const uint4*)p);
}

// ---------------- dtype detect: bf16 vs fp32 device buffers ----------------
__global__ void detect_k(const u16* __restrict__ x, int* __restrict__ flagp) {
    __shared__ int cnt;
    if (threadIdx.x == 0) cnt = 0;
    __syncthreads();
    int bad = 0;
    for (int i = threadIdx.x; i < 2048; i += 256) {
        u16 u = x[i];
        int e = (u >> 7) & 0xFF;
        if (u != 0 && (e < 90 || e > 164)) bad++;
    }
    atomicAdd(&cnt, bad);
    __syncthreads();
    if (threadIdx.x == 0) *flagp = (cnt > 256) ? 1 : 0;  // 1 => inputs are fp32
}

// ---------------- convert/copy all inputs into bf16 arena ----------------
__global__ __launch_bounds__(256) void cvt_all(
    const void* s0, const void* s1, const void* s2, const void* s3,
    const void* s4, const void* s5, const void* s6, const void* s7,
    const void* s8, const void* s9, const void* s10, const void* s11,
    u16* __restrict__ arena, const int* __restrict__ flagp)
{
    int gid = blockIdx.x * 256 + threadIdx.x;
    if (gid >= N_ELEMS) return;
    const int f = *flagp;
    const void* src; int base;
    if      (gid < OFF_WDQ)  { src = s0;  base = OFF_X; }
    else if (gid < OFF_WUQ)  { src = s1;  base = OFF_WDQ; }
    else if (gid < OFF_WQR)  { src = s2;  base = OFF_WUQ; }
    else if (gid < OFF_WDKV) { src = s3;  base = OFF_WQR; }
    else if (gid < OFF_WUKV) { src = s4;  base = OFF_WDKV; }
    else if (gid < OFF_WKR)  { src = s5;  base = OFF_WUKV; }
    else if (gid < OFF_WO)   { src = s6;  base = OFF_WKR; }
    else if (gid < OFF_QG)   { src = s7;  base = OFF_WO; }
    else if (gid < OFF_QB)   { src = s8;  base = OFF_QG; }
    else if (gid < OFF_KG)   { src = s9;  base = OFF_QB; }
    else if (gid < OFF_KB)   { src = s10; base = OFF_KG; }
    else                     { src = s11; base = OFF_KB; }
    int local = gid - base;
    u16 v;
    if (f) {
        float xv = ((const float*)src)[local];
        v = __builtin_bit_cast(u16, __float2bfloat16(xv));
    } else {
        v = ((const u16*)src)[local];
    }
    arena[gid] = v;
}

// ---------------- transpose + zero-pad all weights into WT arena ----------------
__global__ __launch_bounds__(256) void wt_all(const bf16* __restrict__ AR, bf16* __restrict__ WT) {
    int gid = blockIdx.x * 256 + threadIdx.x;
    if (gid >= T_TOT) return;
    bf16 v = __float2bfloat16(0.f);
    if (gid < T_UQ) {
        int loc = gid, n = loc >> 9, k = loc & 511;
        if      (n < 256) v = AR[OFF_WDQ  + (size_t)k * 256 + n];
        else if (n < 597) v = AR[OFF_WDKV + (size_t)k * 341 + (n - 256)];
        else if (n >= 640 && n < 704) v = AR[OFF_WKR + (size_t)k * 64 + (n - 640)];
    } else if (gid < T_UKV) {
        int loc = gid - T_UQ, n = loc >> 8, k = loc & 255;
        if      (n < 512) v = AR[OFF_WUQ + (size_t)k * 512 + n];
        else if (n < 576) v = AR[OFF_WQR + (size_t)k * 64 + (n - 512)];
    } else {
        int loc = gid - T_UKV, n = loc / 384, k = loc % 384;
        if (k < 341) v = AR[OFF_WUKV + (size_t)k * 1024 + n];
    }
    WT[gid] = v;
}

// ------- 128x128 bf16 MFMA GEMM (m93 structure), BK=32, B pre-transposed [N][K] -------
// 4 waves (2x2), each 64x64 of C (4x4 fragments). N must be multiple of 128.
// modes: 0 fp32->C0(ldc); 1 dual->C0/C0f; 3 KV-scatter (K + V^T); 4 Q-scatter + y_qr.
__global__ __launch_bounds__(256) void gemmT(
    const bf16* __restrict__ A, int lda,
    const bf16* __restrict__ BT, int ldb,
    int Kpad, int mode,
    void* __restrict__ C0, int ldc,
    bf16* __restrict__ kv_k, bf16* __restrict__ kv_v,
    const int* __restrict__ flagp, float* __restrict__ C0f)
{
    __shared__ __align__(16) bf16 Al[128][40];
    __shared__ __align__(16) bf16 Bl[128][40];
    const int tid = threadIdx.x;
    const int m0 = blockIdx.y * 128, n0 = blockIdx.x * 128;
    const int lane = tid & 63, w = tid >> 6;
    const int wm = w & 1, wn = w >> 1;
    const int g = lane >> 4, lr = lane & 15;
    f32x4 acc[4][4] = {};
    const int srow = tid >> 1, scol = (tid & 1) * 16;

    for (int k0 = 0; k0 < Kpad; k0 += 32) {
        const bf16* ap = &A[(size_t)(m0 + srow) * lda + k0 + scol];
        const bf16* bp = &BT[(size_t)(n0 + srow) * ldb + k0 + scol];
        *(uint4*)&Al[srow][scol]     = *(const uint4*)ap;
        *(uint4*)&Al[srow][scol + 8] = *(const uint4*)(ap + 8);
        *(uint4*)&Bl[srow][scol]     = *(const uint4*)bp;
        *(uint4*)&Bl[srow][scol + 8] = *(const uint4*)(bp + 8);
        __syncthreads();
        bf16x8 af[4], bfr[4];
        #pragma unroll
        for (int i = 0; i < 4; ++i) af[i]  = ld_bf8(&Al[wm * 64 + i * 16 + lr][g * 8]);
        #pragma unroll
        for (int i = 0; i < 4; ++i) bfr[i] = ld_bf8(&Bl[wn * 64 + i * 16 + lr][g * 8]);
        #pragma unroll
        for (int mt = 0; mt < 4; ++mt)
        #pragma unroll
        for (int nt = 0; nt < 4; ++nt)
            acc[mt][nt] = __builtin_amdgcn_mfma_f32_16x16x32_bf16(af[mt], bfr[nt], acc[mt][nt], 0, 0, 0);
        __syncthreads();
    }

    const int f32o = (mode == 1 && flagp) ? *flagp : 0;
    #pragma unroll
    for (int mt = 0; mt < 4; ++mt)
    #pragma unroll
    for (int nt = 0; nt < 4; ++nt)
    #pragma unroll
    for (int r = 0; r < 4; ++r) {
        int gm = m0 + wm * 64 + mt * 16 + g * 4 + r;
        int gn = n0 + wn * 64 + nt * 16 + lr;
        float v = acc[mt][nt][r];
        if (mode == 0) {
            ((float*)C0)[(size_t)gm * ldc + gn] = v;
        } else if (mode == 1) {
            if (f32o) C0f[(size_t)gm * ldc + gn] = v;
            else ((bf16*)C0)[(size_t)gm * ldc + gn] = __float2bfloat16(v);
        } else if (mode == 4) {
            int b = gm >> 11, s = gm & 2047;
            if (gn < DM) {
                int h = gn >> 6, dh = gn & 63;
                ((bf16*)C0)[((size_t)(b * NH + h) * SEQ + s) * DQKPAD + dh] = __float2bfloat16(v);
            } else if (gn < 576) {
                C0f[(size_t)gm * 64 + (gn - DM)] = v;
            }
        } else { // mode 3: K scatter [bh][s][96]; V scatter TRANSPOSED [bh][64][2048]
            int b = gm >> 11, s = gm & 2047;
            if (gn < DM) {
                int h = gn >> 6, dh = gn & 63;
                kv_k[((size_t)(b * NH + h) * SEQ + s) * DQKPAD + dh] = __float2bfloat16(v);
            } else {
                int c = gn - DM;
                int h = c >> 6, dv = c & 63;
                kv_v[((size_t)(b * NH + h) * DHD + dv) * SEQ + s] = __float2bfloat16(v);
            }
        }
    }
}

// ---------------- row layernorm (fp32 in, strided; O1 dual-dtype, O2 bf16) ----
__global__ __launch_bounds__(256) void ln_row(
    const float* __restrict__ Y, int ldy, int N,
    const bf16* __restrict__ gam, const bf16* __restrict__ bet,
    bf16* __restrict__ O1, float* __restrict__ O1f, const int* __restrict__ flagp, int ld1,
    bf16* __restrict__ O2, int ld2, int padN)
{
    int row = blockIdx.x;
    const float* y = Y + (size_t)row * ldy;
    int tid = threadIdx.x;
    const int f32o = flagp ? *flagp : 0;
    float s = 0.f, ss = 0.f;
    for (int i = tid; i < N; i += 256) { float v = y[i]; s += v; ss += v * v; }
    #pragma unroll
    for (int m = 1; m < 64; m <<= 1) { s += __shfl_xor(s, m); ss += __shfl_xor(ss, m); }
    __shared__ float red[2][4];
    int w = tid >> 6;
    if ((tid & 63) == 0) { red[0][w] = s; red[1][w] = ss; }
    __syncthreads();
    s = red[0][0] + red[0][1] + red[0][2] + red[0][3];
    ss = red[1][0] + red[1][1] + red[1][2] + red[1][3];
    float mean = s / N;
    float var = ss / N - mean * mean;
    float rstd = rsqrtf(var + 1e-5f);
    for (int i = tid; i < N; i += 256) {
        float v = (y[i] - mean) * rstd * __bfloat162float(gam[i]) + __bfloat162float(bet[i]);
        if (f32o) O1f[(size_t)row * ld1 + i] = v;
        else O1[(size_t)row * ld1 + i] = __float2bfloat16(v);
        if (O2) O2[(size_t)row * ld2 + i] = __float2bfloat16(v);
    }
    if (O2) for (int i = N + tid; i < padN; i += 256) O2[(size_t)row * ld2 + i] = __float2bfloat16(0.f);
}

// ---------------- rope + pad fill for q/k rope tails ----------------
__global__ __launch_bounds__(256) void rope_fill(
    const float* __restrict__ yqr, int ldq,
    const float* __restrict__ ykr, int ldk,
    bf16* __restrict__ qa, bf16* __restrict__ ka)
{
    int idx = blockIdx.x * 256 + threadIdx.x;
    if (idx >= MROWS * NH) return;
    int m = idx >> 3, h = idx & 7;
    int b = m >> 11, s = m & 2047;
    float q[8], k[8], qo[8], ko[8];
    #pragma unroll
    for (int j = 0; j < 8; ++j) {
        q[j] = yqr[(size_t)m * ldq + h * 8 + j];
        k[j] = ykr[(size_t)m * ldk + h * 8 + j];
    }
    #pragma unroll
    for (int i = 0; i < 4; ++i) {
        float inv = exp2f(-(float)i * 3.3219280948873623f);  // 10000^(-i/4)
        float ang = (float)s * inv;
        float sn, cs;
        sincosf(ang, &sn, &cs);
        qo[i] = q[i] * cs - q[i + 4] * sn;
        qo[i + 4] = q[i + 4] * cs + q[i] * sn;
        ko[i] = k[i] * cs - k[i + 4] * sn;
        ko[i + 4] = k[i + 4] * cs + k[i] * sn;
    }
    bf16* qp = qa + ((size_t)(b * NH + h) * SEQ + s) * DQKPAD;
    bf16* kp = ka + ((size_t)(b * NH + h) * SEQ + s) * DQKPAD;
    #pragma unroll
    for (int j = 0; j < 8; ++j) {
        qp[64 + j] = __float2bfloat16(qo[j]);
        kp[64 + j] = __float2bfloat16(ko[j]);
    }
    #pragma unroll
    for (int j = 72; j < 96; ++j) {
        qp[j] = __float2bfloat16(0.f);
        kp[j] = __float2bfloat16(0.f);
    }
}

// ---- causal flash attention, split-KV + qb-PAIRING for uniform block work ----
// grid (4 splits, 16 pairs, 16 bh); block 256. Each block runs q-tiles p and 31-p
// sequentially -> every block ~8.25 granules (no tail imbalance).
__global__ __launch_bounds__(256) void attn_split(
    const bf16* __restrict__ qa, const bf16* __restrict__ ka, const bf16* __restrict__ vat,
    bf16* __restrict__ po, float* __restrict__ mlm, float* __restrict__ mll)
{
    __shared__ __align__(16) bf16 Kl[64][104];
    __shared__ __align__(16) bf16 Vt[64][72];
    __shared__ __align__(16) bf16 Pl[4][16][72];
    const int sp = blockIdx.x, pr = blockIdx.y, bh = blockIdx.z;
    const int tid = threadIdx.x, w = tid >> 6, lane = tid & 63;
    const int g = lane >> 4, lr = lane & 15;
    const size_t base = (size_t)bh * SEQ;
    const float SC = 0.11785113019775793f;   // 1/sqrt(72)
    const float L2E = 1.4426950408889634f;

    for (int half = 0; half < 2; ++half) {
        const int qb = half ? (31 - pr) : pr;
        const int qrow0 = qb * 64 + w * 16;

        bf16x8 qf[3];
        #pragma unroll
        for (int kc = 0; kc < 3; ++kc)
            qf[kc] = ld_bf8(&qa[(base + qrow0 + lr) * DQKPAD + kc * 32 + g * 8]);

        float m_r[4], l_r[4];
        f32x4 acc_o[4] = {};
        #pragma unroll
        for (int r = 0; r < 4; ++r) { m_r[r] = -1e30f; l_r[r] = 0.f; }

        const int ng = qb + 1;
        const int bs = (ng * sp) >> 2, be = (ng * (sp + 1)) >> 2;

        for (int gi = bs; gi < be; ++gi) {
            const int j0 = gi * 64;
            __syncthreads();
            for (int u = tid; u < 768; u += 256) {   // K tile: 64 rows x 96
                int row = u / 12, cc = (u % 12) * 8;
                *(uint4*)&Kl[row][cc] = *(const uint4*)&ka[(base + j0 + row) * DQKPAD + cc];
            }
            {                                        // V^T tile: 64 d x 64 keys
                int d = tid >> 2, ko = (tid & 3) * 16;
                const bf16* vsrc = &vat[((size_t)bh * DHD + d) * SEQ + j0 + ko];
                *(uint4*)&Vt[d][ko]     = *(const uint4*)vsrc;
                *(uint4*)&Vt[d][ko + 8] = *(const uint4*)(vsrc + 8);
            }
            __syncthreads();

            f32x4 accs[4] = {};
            #pragma unroll
            for (int kc = 0; kc < 3; ++kc) {
                #pragma unroll
                for (int nt = 0; nt < 4; ++nt) {
                    bf16x8 kf = ld_bf8(&Kl[nt * 16 + lr][kc * 32 + g * 8]);
                    accs[nt] = __builtin_amdgcn_mfma_f32_16x16x32_bf16(qf[kc], kf, accs[nt], 0, 0, 0);
                }
            }
            float pv2[4][4];
            #pragma unroll
            for (int nt = 0; nt < 4; ++nt)
            #pragma unroll
            for (int r = 0; r < 4; ++r) {
                int jj = j0 + nt * 16 + lr;
                int qr = qrow0 + g * 4 + r;
                float sv = accs[nt][r] * SC;
                pv2[nt][r] = (jj <= qr) ? sv : -1e30f;
            }
            #pragma unroll
            for (int r = 0; r < 4; ++r) {
                float rm = fmaxf(fmaxf(pv2[0][r], pv2[1][r]), fmaxf(pv2[2][r], pv2[3][r]));
                rm = fmaxf(rm, __shfl_xor(rm, 1));
                rm = fmaxf(rm, __shfl_xor(rm, 2));
                rm = fmaxf(rm, __shfl_xor(rm, 4));
                rm = fmaxf(rm, __shfl_xor(rm, 8));
                float mn = fmaxf(m_r[r], rm);
                float alpha = exp2f((m_r[r] - mn) * L2E);
                m_r[r] = mn;
                float rs = 0.f;
                #pragma unroll
                for (int nt = 0; nt < 4; ++nt) {
                    float p = exp2f((pv2[nt][r] - mn) * L2E);
                    pv2[nt][r] = p; rs += p;
                }
                rs += __shfl_xor(rs, 1); rs += __shfl_xor(rs, 2);
                rs += __shfl_xor(rs, 4); rs += __shfl_xor(rs, 8);
                l_r[r] = l_r[r] * alpha + rs;
                #pragma unroll
                for (int nv = 0; nv < 4; ++nv) acc_o[nv][r] *= alpha;
            }
            #pragma unroll
            for (int nt = 0; nt < 4; ++nt)
            #pragma unroll
            for (int r = 0; r < 4; ++r)
                Pl[w][g * 4 + r][nt * 16 + lr] = __float2bfloat16(pv2[nt][r]);
            bf16x8 pf0 = ld_bf8(&Pl[w][lr][g * 8]);
            bf16x8 pf1 = ld_bf8(&Pl[w][lr][32 + g * 8]);
            #pragma unroll
            for (int nv = 0; nv < 4; ++nv) {
                bf16x8 vf0 = ld_bf8(&Vt[nv * 16 + lr][g * 8]);
                acc_o[nv] = __builtin_amdgcn_mfma_f32_16x16x32_bf16(pf0, vf0, acc_o[nv], 0, 0, 0);
                bf16x8 vf1 = ld_bf8(&Vt[nv * 16 + lr][32 + g * 8]);
                acc_o[nv] = __builtin_amdgcn_mfma_f32_16x16x32_bf16(pf1, vf1, acc_o[nv], 0, 0, 0);
            }
        }

        const size_t pb = (size_t)(bh * 4 + sp) * SEQ;
        #pragma unroll
        for (int r = 0; r < 4; ++r) {
            int qrow = qrow0 + g * 4 + r;
            #pragma unroll
            for (int nv = 0; nv < 4; ++nv)
                po[(pb + qrow) * DHD + nv * 16 + lr] = __float2bfloat16(acc_o[nv][r]);
        }
        if (lane < 16) {
            mlm[pb + qrow0 + lane] = m_r[0] >= -1e29f || true ? m_r[0] : m_r[0];  // placeholder avoided below
        }
        // per-lane (lr) rows hold m_r/l_r for q = qrow0 + g*4 + r; lane with g==0 owns r-block via shuffle-free store:
        if (g == 0 && lr < 4) {}
        // store m/l: lane pattern — row qrow0 + g*4 + r maps to (g,r); use lanes g*4+r of each 16-group once (w covers 16 rows)
        if (lr == 0) {
            #pragma unroll
            for (int r = 0; r < 4; ++r) {
                mlm[pb + qrow0 + g * 4 + r] = m_r[r];
                mll[pb + qrow0 + g * 4 + r] = l_r[r];
            }
        }
    }
}

// ---------------- combine split partials -> attn_o [b][s][h*64+d] ----------------
__global__ __launch_bounds__(256) void attn_combine(
    const bf16* __restrict__ po, const float* __restrict__ mlm, const float* __restrict__ mll,
    bf16* __restrict__ ao)
{
    int id = blockIdx.x * 256 + threadIdx.x;   // 16*2048*8 = 262144
    int bh = id >> 14;
    int rem = id & 16383;
    int q = rem >> 3, dc = (rem & 7) * 8;
    const float L2E = 1.4426950408889634f;
    size_t mlb = (size_t)bh * 4 * SEQ + q;
    float ms[4], ls[4];
    #pragma unroll
    for (int s = 0; s < 4; ++s) { ms[s] = mlm[mlb + (size_t)s * SEQ]; ls[s] = mll[mlb + (size_t)s * SEQ]; }
    float M = fmaxf(fmaxf(ms[0], ms[1]), fmaxf(ms[2], ms[3]));
    float wsc[4]; float L = 0.f;
    #pragma unroll
    for (int s = 0; s < 4; ++s) { wsc[s] = exp2f((ms[s] - M) * L2E); L += wsc[s] * ls[s]; }
    float o[8] = {};
    #pragma unroll
    for (int s = 0; s < 4; ++s) {
        if (ls[s] <= 0.f) continue;
        bf16x8 pv = ld_bf8(&po[((size_t)(bh * 4 + s) * SEQ + q) * DHD + dc]);
        #pragma unroll
        for (int j = 0; j < 8; ++j) o[j] += wsc[s] * (float)pv[j];
    }
    float invL = 1.f / L;
    int b = bh >> 3, h = bh & 7;
    __bf16 tmp[8];
    #pragma unroll
    for (int j = 0; j < 8; ++j) tmp[j] = (__bf16)(o[j] * invL);
    *(uint4*)&ao[((size_t)(b * SEQ) + q) * DM + h * DHD + dc] = *(uint4*)tmp;
}

extern "C" void kernel_launch(void* const* d_in, const int* in_sizes, int n_in,
                              void* d_out, int out_size, void* d_ws, size_t ws_size,
                              hipStream_t stream) {
    char* ws = (char*)d_ws;
    bf16* AR      = (bf16*)(ws + 0);              // bf16 arena (x region dead after x-gemm)
    float* ml_m   = (float*)(ws + 0);             // alias x region (written by attn)
    float* ml_l   = (float*)(ws + 524288);
    bf16* WT      = (bf16*)(ws + 6391296);        // transposed weights (1,900,544 B)
    int*  flagp   = (int*)(ws + 8291840);
    float* y      = (float*)(ws + 8292352);       // fused x-proj out [4096][768] fp32
    float* y_qr   = (float*)(ws + 20875264);      // [4096][64] fp32
    bf16* cq      = (bf16*)(ws + 21923840);       // [4096][256]
    bf16* ckvp    = (bf16*)(ws + 24020992);       // [4096][384]
    bf16* po      = (bf16*)(ws + 8292352);        // alias dead y..ckvp region (16.78MB)
    bf16* q_attn  = (bf16*)(ws + 27166720);
    bf16* k_attn  = (bf16*)(ws + 33458176);
    bf16* v_attnT = (bf16*)(ws + 39749632);
    bf16* attn_o  = (bf16*)(ws + 43943936);

    const bf16* xb  = AR + OFF_X;
    const bf16* W_o = AR + OFF_WO;
    const bf16* qg  = AR + OFF_QG;
    const bf16* qb_ = AR + OFF_QB;
    const bf16* kg  = AR + OFF_KG;
    const bf16* kb  = AR + OFF_KB;

    bf16*  out_b = (bf16*)d_out;
    float* out_f = (float*)d_out;
    bf16*  ckv_b = out_b + (size_t)MROWS * DM;
    float* ckv_f = out_f + (size_t)MROWS * DM;

    dim3 blk(256);
    detect_k<<<1, blk, 0, stream>>>((const u16*)d_in[0], flagp);
    cvt_all<<<dim3((N_ELEMS + 255) / 256), blk, 0, stream>>>(
        d_in[0], d_in[1], d_in[2], d_in[3], d_in[4], d_in[5],
        d_in[6], d_in[7], d_in[8], d_in[9], d_in[10], d_in[11],
        (u16*)AR, flagp);
    wt_all<<<dim3((T_TOT + 255) / 256), blk, 0, stream>>>(AR, WT);

    // fused low-rank projections from x: [dq(256)|dkv(341+pad)|kr(64)|pad] N=768
    gemmT<<<dim3(6, 32), blk, 0, stream>>>(xb, DM, WT + T_DQ, DM, DM, 0, y, 768, nullptr, nullptr, nullptr, nullptr);
    // layernorms (strided reads from fused y)
    ln_row<<<MROWS, blk, 0, stream>>>(y, 768, QP, qg, qb_, cq, nullptr, nullptr, QP, nullptr, 0, 0);
    ln_row<<<MROWS, blk, 0, stream>>>(y + 256, 768, KVP, kg, kb, ckv_b, ckv_f, flagp, KVP, ckvp, 384, 384);
    // fused cq up-projection: [uq(512) scatter | qr(64) fp32 | pad] N=640
    gemmT<<<dim3(5, 32), blk, 0, stream>>>(cq, QP, WT + T_UQ, QP, QP, 4, q_attn, 0, nullptr, nullptr, nullptr, y_qr);
    // kv up-projection (K scatter + V^T scatter), N=1024, K=384
    gemmT<<<dim3(8, 32), blk, 0, stream>>>(ckvp, 384, WT + T_UKV, 384, 384, 3, nullptr, 0, k_attn, v_attnT, nullptr, nullptr);
    // rope tails + pad zeros
    rope_fill<<<dim3(MROWS * NH / 256), blk, 0, stream>>>(y_qr, 64, y + 640, 768, q_attn, k_attn);
    // attention (split-KV, qb-paired uniform blocks) + combine
    attn_split<<<dim3(4, 16, 16), blk, 0, stream>>>(q_attn, k_attn, v_attnT, po, ml_m, ml_l);
    attn_combine<<<dim3(16 * SEQ * 8 / 256), blk, 0, stream>>>(po, ml_m, ml_l, attn_o);
    // output projection (W_o natural [N][K]) -> d_out (dual dtype), N=512
    gemmT<<<dim3(4, 32), blk, 0, stream>>>(attn_o, DM, W_o, DM, DM, 1, out_b, DM, nullptr, nullptr, flagp, out_f);
}

// Round 8
// 137.937 us; speedup vs baseline: 2.8945x; 1.2132x over previous
//
#include <hip/hip_runtime.h>
#include <hip/hip_bf16.h>

#define BATCH 2
#define SEQ 2048
#define DM 512
#define NH 8
#define DHD 64
#define QP 256
#define KVP 341
#define DQKPAD 96
#define MROWS 4096   // BATCH*SEQ

// bf16 arena element offsets (cumulative over setup_inputs order)
#define OFF_X     0
#define OFF_WDQ   2097152
#define OFF_WUQ   2228224
#define OFF_WQR   2359296
#define OFF_WDKV  2375680
#define OFF_WUKV  2550272
#define OFF_WKR   2899456
#define OFF_WO    2932224
#define OFF_QG    3194368
#define OFF_QB    3194624
#define OFF_KG    3194880
#define OFF_KB    3195221
#define N_ELEMS   3195562

// transposed-weight arena element offsets ([N][K], contiguous dq|dkv|kr for fusion)
#define T_DQ   0        // [256][512]
#define T_DKV  131072   // [384][512] (n>=341 zero)  rows 256..639 of fused x-proj
#define T_KR   327680   // [64][512]                 rows 640..703
#define T_UQ   360448   // [512][256]
#define T_QR   491520   // [64][256]                 fused uq|qr N=576
#define T_UKV  507904   // [1024][384] (k>=341 zero)
#define T_TOT  901120

typedef __bf16 bf16x8 __attribute__((ext_vector_type(8)));
typedef float f32x4 __attribute__((ext_vector_type(4)));
typedef __hip_bfloat16 bf16;
typedef unsigned short u16;

static __device__ __forceinline__ bf16x8 ld_bf8(const bf16* p) {
    return __builtin_bit_cast(bf16x8, *(const uint4*)p);
}

// ---------------- dtype detect: bf16 vs fp32 device buffers ----------------
__global__ void detect_k(const u16* __restrict__ x, int* __restrict__ flagp) {
    __shared__ int cnt;
    if (threadIdx.x == 0) cnt = 0;
    __syncthreads();
    int bad = 0;
    for (int i = threadIdx.x; i < 2048; i += 256) {
        u16 u = x[i];
        int e = (u >> 7) & 0xFF;
        if (u != 0 && (e < 90 || e > 164)) bad++;
    }
    atomicAdd(&cnt, bad);
    __syncthreads();
    if (threadIdx.x == 0) *flagp = (cnt > 256) ? 1 : 0;  // 1 => inputs are fp32
}

// ---------------- convert/copy all inputs into bf16 arena ----------------
__global__ __launch_bounds__(256) void cvt_all(
    const void* s0, const void* s1, const void* s2, const void* s3,
    const void* s4, const void* s5, const void* s6, const void* s7,
    const void* s8, const void* s9, const void* s10, const void* s11,
    u16* __restrict__ arena, const int* __restrict__ flagp)
{
    int gid = blockIdx.x * 256 + threadIdx.x;
    if (gid >= N_ELEMS) return;
    const int f = *flagp;
    const void* src; int base;
    if      (gid < OFF_WDQ)  { src = s0;  base = OFF_X; }
    else if (gid < OFF_WUQ)  { src = s1;  base = OFF_WDQ; }
    else if (gid < OFF_WQR)  { src = s2;  base = OFF_WUQ; }
    else if (gid < OFF_WDKV) { src = s3;  base = OFF_WQR; }
    else if (gid < OFF_WUKV) { src = s4;  base = OFF_WDKV; }
    else if (gid < OFF_WKR)  { src = s5;  base = OFF_WUKV; }
    else if (gid < OFF_WO)   { src = s6;  base = OFF_WKR; }
    else if (gid < OFF_QG)   { src = s7;  base = OFF_WO; }
    else if (gid < OFF_QB)   { src = s8;  base = OFF_QG; }
    else if (gid < OFF_KG)   { src = s9;  base = OFF_QB; }
    else if (gid < OFF_KB)   { src = s10; base = OFF_KG; }
    else                     { src = s11; base = OFF_KB; }
    int local = gid - base;
    u16 v;
    if (f) {
        float xv = ((const float*)src)[local];
        v = __builtin_bit_cast(u16, __float2bfloat16(xv));
    } else {
        v = ((const u16*)src)[local];
    }
    arena[gid] = v;
}

// ---------------- transpose + zero-pad all weights into WT arena ----------------
__global__ __launch_bounds__(256) void wt_all(const bf16* __restrict__ AR, bf16* __restrict__ WT) {
    int gid = blockIdx.x * 256 + threadIdx.x;
    if (gid >= T_TOT) return;
    const bf16* src; int base, Kp, Nv, Kv;
    if      (gid < T_DKV) { base = T_DQ;  Kp = 512; src = AR + OFF_WDQ;  Nv = 256;  Kv = 512; }
    else if (gid < T_KR)  { base = T_DKV; Kp = 512; src = AR + OFF_WDKV; Nv = 341;  Kv = 512; }
    else if (gid < T_UQ)  { base = T_KR;  Kp = 512; src = AR + OFF_WKR;  Nv = 64;   Kv = 512; }
    else if (gid < T_QR)  { base = T_UQ;  Kp = 256; src = AR + OFF_WUQ;  Nv = 512;  Kv = 256; }
    else if (gid < T_UKV) { base = T_QR;  Kp = 256; src = AR + OFF_WQR;  Nv = 64;   Kv = 256; }
    else                  { base = T_UKV; Kp = 384; src = AR + OFF_WUKV; Nv = 1024; Kv = 341; }
    int loc = gid - base;
    int n = loc / Kp, k = loc % Kp;
    bf16 v = __float2bfloat16(0.f);
    if (n < Nv && k < Kv) v = src[(size_t)k * Nv + n];
    WT[gid] = v;
}

// ------- 128x64 bf16 MFMA GEMM, BK=64, B pre-transposed [N][K] -------
// 4 waves, each 32(M)x64(N). modes: 0 fp32->C0(ldc); 1 dual->C0/C0f;
// 3 KV-scatter (K rows + V^T); 4 Q-scatter (gn<512) + y_qr fp32 tail.
__global__ __launch_bounds__(256) void gemm128(
    const bf16* __restrict__ A, int lda,
    const bf16* __restrict__ BT, int ldb,
    int N, int Kpad, int mode,
    void* __restrict__ C0, int ldc,
    bf16* __restrict__ kv_k, bf16* __restrict__ kv_v,
    const int* __restrict__ flagp, float* __restrict__ C0f)
{
    __shared__ __align__(16) bf16 Al[128][72];
    __shared__ __align__(16) bf16 Bl[64][72];
    const int tid = threadIdx.x;
    const int m0 = blockIdx.y * 128, n0 = blockIdx.x * 64;
    const int lane = tid & 63, w = tid >> 6;
    const int g = lane >> 4, lr = lane & 15;
    f32x4 acc[2][4] = {};
    const int srow = tid >> 3, scol = (tid & 7) * 8;

    for (int k0 = 0; k0 < Kpad; k0 += 64) {
        #pragma unroll
        for (int p = 0; p < 4; ++p)
            *(uint4*)&Al[p * 32 + srow][scol] =
                *(const uint4*)&A[(size_t)(m0 + p * 32 + srow) * lda + k0 + scol];
        #pragma unroll
        for (int p = 0; p < 2; ++p)
            *(uint4*)&Bl[p * 32 + srow][scol] =
                *(const uint4*)&BT[(size_t)(n0 + p * 32 + srow) * ldb + k0 + scol];
        __syncthreads();
        #pragma unroll
        for (int ks = 0; ks < 2; ++ks) {
            bf16x8 a0 = ld_bf8(&Al[w * 32 + lr][ks * 32 + g * 8]);
            bf16x8 a1 = ld_bf8(&Al[w * 32 + 16 + lr][ks * 32 + g * 8]);
            #pragma unroll
            for (int nt = 0; nt < 4; ++nt) {
                bf16x8 b = ld_bf8(&Bl[nt * 16 + lr][ks * 32 + g * 8]);
                acc[0][nt] = __builtin_amdgcn_mfma_f32_16x16x32_bf16(a0, b, acc[0][nt], 0, 0, 0);
                acc[1][nt] = __builtin_amdgcn_mfma_f32_16x16x32_bf16(a1, b, acc[1][nt], 0, 0, 0);
            }
        }
        __syncthreads();
    }

    const int f32o = (mode == 1 && flagp) ? *flagp : 0;
    #pragma unroll
    for (int mt = 0; mt < 2; ++mt)
    #pragma unroll
    for (int nt = 0; nt < 4; ++nt)
    #pragma unroll
    for (int r = 0; r < 4; ++r) {
        int gm = m0 + w * 32 + mt * 16 + g * 4 + r;
        int gn = n0 + nt * 16 + lr;
        float v = acc[mt][nt][r];
        if (mode == 0) {
            ((float*)C0)[(size_t)gm * ldc + gn] = v;
        } else if (mode == 1) {
            if (f32o) C0f[(size_t)gm * ldc + gn] = v;
            else ((bf16*)C0)[(size_t)gm * ldc + gn] = __float2bfloat16(v);
        } else if (mode == 4) {
            int b = gm >> 11, s = gm & 2047;
            if (gn < DM) {
                int h = gn >> 6, dh = gn & 63;
                ((bf16*)C0)[((size_t)(b * NH + h) * SEQ + s) * DQKPAD + dh] = __float2bfloat16(v);
            } else {
                C0f[(size_t)gm * 64 + (gn - DM)] = v;
            }
        } else { // mode 3: K scatter [bh][s][96]; V scatter TRANSPOSED [bh][64][2048]
            int b = gm >> 11, s = gm & 2047;
            if (gn < DM) {
                int h = gn >> 6, dh = gn & 63;
                kv_k[((size_t)(b * NH + h) * SEQ + s) * DQKPAD + dh] = __float2bfloat16(v);
            } else {
                int c = gn - DM;
                int h = c >> 6, dv = c & 63;
                kv_v[((size_t)(b * NH + h) * DHD + dv) * SEQ + s] = __float2bfloat16(v);
            }
        }
    }
}

// ---------------- row layernorm (fp32 in, strided; O1 dual-dtype, O2 bf16) ----
__global__ __launch_bounds__(256) void ln_row(
    const float* __restrict__ Y, int ldy, int N,
    const bf16* __restrict__ gam, const bf16* __restrict__ bet,
    bf16* __restrict__ O1, float* __restrict__ O1f, const int* __restrict__ flagp, int ld1,
    bf16* __restrict__ O2, int ld2, int padN)
{
    int row = blockIdx.x;
    const float* y = Y + (size_t)row * ldy;
    int tid = threadIdx.x;
    const int f32o = flagp ? *flagp : 0;
    float s = 0.f, ss = 0.f;
    for (int i = tid; i < N; i += 256) { float v = y[i]; s += v; ss += v * v; }
    #pragma unroll
    for (int m = 1; m < 64; m <<= 1) { s += __shfl_xor(s, m); ss += __shfl_xor(ss, m); }
    __shared__ float red[2][4];
    int w = tid >> 6;
    if ((tid & 63) == 0) { red[0][w] = s; red[1][w] = ss; }
    __syncthreads();
    s = red[0][0] + red[0][1] + red[0][2] + red[0][3];
    ss = red[1][0] + red[1][1] + red[1][2] + red[1][3];
    float mean = s / N;
    float var = ss / N - mean * mean;
    float rstd = rsqrtf(var + 1e-5f);
    for (int i = tid; i < N; i += 256) {
        float v = (y[i] - mean) * rstd * __bfloat162float(gam[i]) + __bfloat162float(bet[i]);
        if (f32o) O1f[(size_t)row * ld1 + i] = v;
        else O1[(size_t)row * ld1 + i] = __float2bfloat16(v);
        if (O2) O2[(size_t)row * ld2 + i] = __float2bfloat16(v);
    }
    if (O2) for (int i = N + tid; i < padN; i += 256) O2[(size_t)row * ld2 + i] = __float2bfloat16(0.f);
}

// ---------------- rope + pad fill for q/k rope tails ----------------
__global__ __launch_bounds__(256) void rope_fill(
    const float* __restrict__ yqr, int ldq,
    const float* __restrict__ ykr, int ldk,
    bf16* __restrict__ qa, bf16* __restrict__ ka)
{
    int idx = blockIdx.x * 256 + threadIdx.x;
    if (idx >= MROWS * NH) return;
    int m = idx >> 3, h = idx & 7;
    int b = m >> 11, s = m & 2047;
    float q[8], k[8], qo[8], ko[8];
    #pragma unroll
    for (int j = 0; j < 8; ++j) {
        q[j] = yqr[(size_t)m * ldq + h * 8 + j];
        k[j] = ykr[(size_t)m * ldk + h * 8 + j];
    }
    #pragma unroll
    for (int i = 0; i < 4; ++i) {
        float inv = exp2f(-(float)i * 3.3219280948873623f);  // 10000^(-i/4)
        float ang = (float)s * inv;
        float sn, cs;
        sincosf(ang, &sn, &cs);
        qo[i] = q[i] * cs - q[i + 4] * sn;
        qo[i + 4] = q[i + 4] * cs + q[i] * sn;
        ko[i] = k[i] * cs - k[i + 4] * sn;
        ko[i + 4] = k[i + 4] * cs + k[i] * sn;
    }
    bf16* qp = qa + ((size_t)(b * NH + h) * SEQ + s) * DQKPAD;
    bf16* kp = ka + ((size_t)(b * NH + h) * SEQ + s) * DQKPAD;
    #pragma unroll
    for (int j = 0; j < 8; ++j) {
        qp[64 + j] = __float2bfloat16(qo[j]);
        kp[64 + j] = __float2bfloat16(ko[j]);
    }
    #pragma unroll
    for (int j = 72; j < 96; ++j) {
        qp[j] = __float2bfloat16(0.f);
        kp[j] = __float2bfloat16(0.f);
    }
}

// ---- causal flash attention: split-KV + qb-pairing + swapped QK^T softmax ----
// grid (4 splits, 16 pairs, 16 bh); block 256 (4 waves x 16 q-rows each).
// Swapped mfma(K,Q): lane owns one q-row's 16 scores -> lane-local softmax
// (15 fmax + 16 exp2 + 2 shuffles for max + 2 for sum + 4 alpha broadcast).
__global__ __launch_bounds__(256) void attn_split3(
    const bf16* __restrict__ qa, const bf16* __restrict__ ka, const bf16* __restrict__ vat,
    bf16* __restrict__ po, float* __restrict__ mlm, float* __restrict__ mll)
{
    __shared__ __align__(16) bf16 Kl[64][104];
    __shared__ __align__(16) bf16 Vt[64][72];
    __shared__ __align__(16) bf16 Pl[4][16][72];
    const int sp = blockIdx.x, pr = blockIdx.y, bh = blockIdx.z;
    const int tid = threadIdx.x, w = tid >> 6, lane = tid & 63;
    const int g = lane >> 4, lr = lane & 15;
    const size_t base = (size_t)bh * SEQ;
    const float SC = 0.11785113019775793f;   // 1/sqrt(72)
    const float L2E = 1.4426950408889634f;
    const bf16* vb = vat + (size_t)bh * DHD * SEQ;

    for (int half = 0; half < 2; ++half) {
        const int qb = half ? (31 - pr) : pr;
        const int qrow0 = qb * 64 + w * 16;
        const int myq = qrow0 + lr;

        bf16x8 qf[3];
        #pragma unroll
        for (int kc = 0; kc < 3; ++kc)
            qf[kc] = ld_bf8(&qa[(base + myq) * DQKPAD + kc * 32 + g * 8]);

        float m_p = -1e30f, l_p = 0.f;   // per-lane state for q-row = myq
        f32x4 acc_o[4] = {};
        const int ng = qb + 1;
        const int bs = (ng * sp) >> 2, be = (ng * (sp + 1)) >> 2;

        for (int gi = bs; gi < be; ++gi) {
            const int j0 = gi * 64;
            __syncthreads();
            for (int u = tid; u < 768; u += 256) {   // K tile: 64 rows x 96
                int row = u / 12, cc = (u % 12) * 8;
                *(uint4*)&Kl[row][cc] = *(const uint4*)&ka[(base + j0 + row) * DQKPAD + cc];
            }
            {                                        // V^T tile: 64 d x 64 keys
                int d = tid >> 2, ko = (tid & 3) * 16;
                const bf16* vsrc = &vb[(size_t)d * SEQ + j0 + ko];
                *(uint4*)&Vt[d][ko]     = *(const uint4*)vsrc;
                *(uint4*)&Vt[d][ko + 8] = *(const uint4*)(vsrc + 8);
            }
            __syncthreads();

            // QK^T swapped: A=K rows (keys), B=Q cols (q). D[row=key][col=q]
            f32x4 accs[4] = {};
            #pragma unroll
            for (int kc = 0; kc < 3; ++kc) {
                #pragma unroll
                for (int nt = 0; nt < 4; ++nt) {
                    bf16x8 kf = ld_bf8(&Kl[nt * 16 + lr][kc * 32 + g * 8]);
                    accs[nt] = __builtin_amdgcn_mfma_f32_16x16x32_bf16(kf, qf[kc], accs[nt], 0, 0, 0);
                }
            }
            // lane owns q=myq; its 16 keys are j0 + nt*16 + g*4 + r
            float s[4][4];
            float mloc = -1e30f;
            #pragma unroll
            for (int nt = 0; nt < 4; ++nt)
            #pragma unroll
            for (int r = 0; r < 4; ++r) {
                int key = j0 + nt * 16 + g * 4 + r;
                float sv = accs[nt][r] * SC;
                sv = (key <= myq) ? sv : -1e30f;
                s[nt][r] = sv;
                mloc = fmaxf(mloc, sv);
            }
            mloc = fmaxf(mloc, __shfl_xor(mloc, 16));
            mloc = fmaxf(mloc, __shfl_xor(mloc, 32));
            float mn = fmaxf(m_p, mloc);
            float alpha = exp2f((m_p - mn) * L2E);
            m_p = mn;
            float rs = 0.f;
            #pragma unroll
            for (int nt = 0; nt < 4; ++nt)
            #pragma unroll
            for (int r = 0; r < 4; ++r) {
                float p = exp2f((s[nt][r] - mn) * L2E);
                s[nt][r] = p; rs += p;
            }
            rs += __shfl_xor(rs, 16);
            rs += __shfl_xor(rs, 32);
            l_p = l_p * alpha + rs;
            // acc_o rows are q=qrow0+g*4+r -> alpha held by lane (g=0, lr=g*4+r)
            float ar[4];
            #pragma unroll
            for (int r = 0; r < 4; ++r) ar[r] = __shfl(alpha, g * 4 + r);
            #pragma unroll
            for (int nv = 0; nv < 4; ++nv)
            #pragma unroll
            for (int r = 0; r < 4; ++r) acc_o[nv][r] *= ar[r];
            // P -> wave-private LDS [q][key] (packed 8B writes)
            #pragma unroll
            for (int nt = 0; nt < 4; ++nt) {
                ushort4 pk;
                pk.x = __builtin_bit_cast(u16, __float2bfloat16(s[nt][0]));
                pk.y = __builtin_bit_cast(u16, __float2bfloat16(s[nt][1]));
                pk.z = __builtin_bit_cast(u16, __float2bfloat16(s[nt][2]));
                pk.w = __builtin_bit_cast(u16, __float2bfloat16(s[nt][3]));
                *(ushort4*)&Pl[w][lr][nt * 16 + g * 4] = pk;
            }
            bf16x8 pf0 = ld_bf8(&Pl[w][lr][g * 8]);
            bf16x8 pf1 = ld_bf8(&Pl[w][lr][32 + g * 8]);
            #pragma unroll
            for (int nv = 0; nv < 4; ++nv) {
                bf16x8 vf0 = ld_bf8(&Vt[nv * 16 + lr][g * 8]);
                acc_o[nv] = __builtin_amdgcn_mfma_f32_16x16x32_bf16(pf0, vf0, acc_o[nv], 0, 0, 0);
                bf16x8 vf1 = ld_bf8(&Vt[nv * 16 + lr][32 + g * 8]);
                acc_o[nv] = __builtin_amdgcn_mfma_f32_16x16x32_bf16(pf1, vf1, acc_o[nv], 0, 0, 0);
            }
        }

        const size_t pb = (size_t)(bh * 4 + sp) * SEQ;
        #pragma unroll
        for (int r = 0; r < 4; ++r) {
            int qrow = qrow0 + g * 4 + r;
            #pragma unroll
            for (int nv = 0; nv < 4; ++nv)
                po[(pb + qrow) * DHD + nv * 16 + lr] = __float2bfloat16(acc_o[nv][r]);
        }
        if (lane < 16) {
            mlm[pb + qrow0 + lane] = m_p;
            mll[pb + qrow0 + lane] = l_p;
        }
    }
}

// ---------------- combine split partials -> attn_o [b][s][h*64+d] ----------------
__global__ __launch_bounds__(256) void attn_combine(
    const bf16* __restrict__ po, const float* __restrict__ mlm, const float* __restrict__ mll,
    bf16* __restrict__ ao)
{
    int id = blockIdx.x * 256 + threadIdx.x;   // 16*2048*8 = 262144
    int bh = id >> 14;
    int rem = id & 16383;
    int q = rem >> 3, dc = (rem & 7) * 8;
    const float L2E = 1.4426950408889634f;
    size_t mlb = (size_t)bh * 4 * SEQ + q;
    float ms[4], ls[4];
    #pragma unroll
    for (int s = 0; s < 4; ++s) { ms[s] = mlm[mlb + (size_t)s * SEQ]; ls[s] = mll[mlb + (size_t)s * SEQ]; }
    float M = fmaxf(fmaxf(ms[0], ms[1]), fmaxf(ms[2], ms[3]));
    float wsc[4]; float L = 0.f;
    #pragma unroll
    for (int s = 0; s < 4; ++s) { wsc[s] = exp2f((ms[s] - M) * L2E); L += wsc[s] * ls[s]; }
    float o[8] = {};
    #pragma unroll
    for (int s = 0; s < 4; ++s) {
        if (ls[s] <= 0.f) continue;
        bf16x8 pv = ld_bf8(&po[((size_t)(bh * 4 + s) * SEQ + q) * DHD + dc]);
        #pragma unroll
        for (int j = 0; j < 8; ++j) o[j] += wsc[s] * (float)pv[j];
    }
    float invL = 1.f / L;
    int b = bh >> 3, h = bh & 7;
    __bf16 tmp[8];
    #pragma unroll
    for (int j = 0; j < 8; ++j) tmp[j] = (__bf16)(o[j] * invL);
    *(uint4*)&ao[((size_t)(b * SEQ) + q) * DM + h * DHD + dc] = *(uint4*)tmp;
}

extern "C" void kernel_launch(void* const* d_in, const int* in_sizes, int n_in,
                              void* d_out, int out_size, void* d_ws, size_t ws_size,
                              hipStream_t stream) {
    char* ws = (char*)d_ws;
    bf16* AR      = (bf16*)(ws + 0);              // bf16 arena (x region dead after x-gemm)
    float* ml_m   = (float*)(ws + 0);             // alias x region (written by attn)
    float* ml_l   = (float*)(ws + 524288);
    bf16* WT      = (bf16*)(ws + 6391296);        // transposed weights (1,802,240 B)
    int*  flagp   = (int*)(ws + 8193536);
    float* y      = (float*)(ws + 8194048);       // fused x-proj out [4096][704] fp32
    float* y_qr   = (float*)(ws + 19728384);      // [4096][64] fp32
    bf16* cq      = (bf16*)(ws + 20776960);       // [4096][256]
    bf16* ckvp    = (bf16*)(ws + 22874112);       // [4096][384]
    bf16* po      = (bf16*)(ws + 8194048);        // alias dead y..ckvp region (16.78MB)
    bf16* q_attn  = (bf16*)(ws + 26019840);
    bf16* k_attn  = (bf16*)(ws + 32311296);
    bf16* v_attnT = (bf16*)(ws + 38602752);
    bf16* attn_o  = (bf16*)(ws + 42797056);

    const bf16* xb  = AR + OFF_X;
    const bf16* W_o = AR + OFF_WO;
    const bf16* qg  = AR + OFF_QG;
    const bf16* qb_ = AR + OFF_QB;
    const bf16* kg  = AR + OFF_KG;
    const bf16* kb  = AR + OFF_KB;

    bf16*  out_b = (bf16*)d_out;
    float* out_f = (float*)d_out;
    bf16*  ckv_b = out_b + (size_t)MROWS * DM;
    float* ckv_f = out_f + (size_t)MROWS * DM;

    dim3 blk(256);
    detect_k<<<1, blk, 0, stream>>>((const u16*)d_in[0], flagp);
    cvt_all<<<dim3((N_ELEMS + 255) / 256), blk, 0, stream>>>(
        d_in[0], d_in[1], d_in[2], d_in[3], d_in[4], d_in[5],
        d_in[6], d_in[7], d_in[8], d_in[9], d_in[10], d_in[11],
        (u16*)AR, flagp);
    wt_all<<<dim3((T_TOT + 255) / 256), blk, 0, stream>>>(AR, WT);

    // fused low-rank projections from x: [dq(256) | dkv(384) | kr(64)] N=704
    gemm128<<<dim3(11, 32), blk, 0, stream>>>(xb, DM, WT + T_DQ, DM, 704, DM, 0, y, 704, nullptr, nullptr, nullptr, nullptr);
    // layernorms (strided reads from fused y)
    ln_row<<<MROWS, blk, 0, stream>>>(y, 704, QP, qg, qb_, cq, nullptr, nullptr, QP, nullptr, 0, 0);
    ln_row<<<MROWS, blk, 0, stream>>>(y + 256, 704, KVP, kg, kb, ckv_b, ckv_f, flagp, KVP, ckvp, 384, 384);
    // fused cq up-projection: [uq(512) scatter | qr(64) fp32] N=576
    gemm128<<<dim3(9, 32), blk, 0, stream>>>(cq, QP, WT + T_UQ, QP, 576, QP, 4, q_attn, 0, nullptr, nullptr, nullptr, y_qr);
    // kv up-projection (K scatter + V^T scatter), N=1024, K=384
    gemm128<<<dim3(16, 32), blk, 0, stream>>>(ckvp, 384, WT + T_UKV, 384, 1024, 384, 3, nullptr, 0, k_attn, v_attnT, nullptr, nullptr);
    // rope tails + pad zeros
    rope_fill<<<dim3(MROWS * NH / 256), blk, 0, stream>>>(y_qr, 64, y + 640, 704, q_attn, k_attn);
    // attention (split-KV, qb-paired, swapped-softmax) + combine
    attn_split3<<<dim3(4, 16, 16), blk, 0, stream>>>(q_attn, k_attn, v_attnT, po, ml_m, ml_l);
    attn_combine<<<dim3(16 * SEQ * 8 / 256), blk, 0, stream>>>(po, ml_m, ml_l, attn_o);
    // output projection (W_o natural [N][K]) -> d_out (dual dtype), N=512
    gemm128<<<dim3(8, 32), blk, 0, stream>>>(attn_o, DM, W_o, DM, DM, DM, 1, out_b, DM, nullptr, nullptr, flagp, out_f);
}

// Round 9
// 132.093 us; speedup vs baseline: 3.0225x; 1.0442x over previous
//
#include <hip/hip_runtime.h>
#include <hip/hip_bf16.h>

#define BATCH 2
#define SEQ 2048
#define DM 512
#define NH 8
#define DHD 64
#define QP 256
#define KVP 341
#define DQKPAD 96
#define MROWS 4096   // BATCH*SEQ

// bf16 arena element offsets (cumulative over setup_inputs order)
#define OFF_X     0
#define OFF_WDQ   2097152
#define OFF_WUQ   2228224
#define OFF_WQR   2359296
#define OFF_WDKV  2375680
#define OFF_WUKV  2550272
#define OFF_WKR   2899456
#define OFF_WO    2932224
#define OFF_QG    3194368
#define OFF_QB    3194624
#define OFF_KG    3194880
#define OFF_KB    3195221
#define N_ELEMS   3195562

// transposed-weight arena element offsets ([N][K], contiguous dq|dkv|kr for fusion)
#define T_DQ   0        // [256][512]
#define T_DKV  131072   // [384][512] (n>=341 zero)  rows 256..639 of fused x-proj
#define T_KR   327680   // [64][512]                 rows 640..703
#define T_UQ   360448   // [512][256]
#define T_QR   491520   // [64][256]                 fused uq|qr N=576
#define T_UKV  507904   // [1024][384] (k>=341 zero)
#define T_TOT  901120

typedef __bf16 bf16x8 __attribute__((ext_vector_type(8)));
typedef float f32x4 __attribute__((ext_vector_type(4)));
typedef __hip_bfloat16 bf16;
typedef unsigned short u16;

static __device__ __forceinline__ bf16x8 ld_bf8(const bf16* p) {
    return __builtin_bit_cast(bf16x8, *(const uint4*)p);
}

// async global->LDS, 16B per lane; LDS dest = wave-uniform base + lane*16
#define GL16(gp, lp) __builtin_amdgcn_global_load_lds( \
    (const __attribute__((address_space(1))) void*)(gp), \
    (__attribute__((address_space(3))) void*)(lp), 16, 0, 0)

// ---------------- dtype detect: bf16 vs fp32 device buffers ----------------
__global__ void detect_k(const u16* __restrict__ x, int* __restrict__ flagp) {
    __shared__ int cnt;
    if (threadIdx.x == 0) cnt = 0;
    __syncthreads();
    int bad = 0;
    for (int i = threadIdx.x; i < 2048; i += 256) {
        u16 u = x[i];
        int e = (u >> 7) & 0xFF;
        if (u != 0 && (e < 90 || e > 164)) bad++;
    }
    atomicAdd(&cnt, bad);
    __syncthreads();
    if (threadIdx.x == 0) *flagp = (cnt > 256) ? 1 : 0;  // 1 => inputs are fp32
}

// ---------------- convert/copy all inputs into bf16 arena ----------------
__global__ __launch_bounds__(256) void cvt_all(
    const void* s0, const void* s1, const void* s2, const void* s3,
    const void* s4, const void* s5, const void* s6, const void* s7,
    const void* s8, const void* s9, const void* s10, const void* s11,
    u16* __restrict__ arena, const int* __restrict__ flagp)
{
    int gid = blockIdx.x * 256 + threadIdx.x;
    if (gid >= N_ELEMS) return;
    const int f = *flagp;
    const void* src; int base;
    if      (gid < OFF_WDQ)  { src = s0;  base = OFF_X; }
    else if (gid < OFF_WUQ)  { src = s1;  base = OFF_WDQ; }
    else if (gid < OFF_WQR)  { src = s2;  base = OFF_WUQ; }
    else if (gid < OFF_WDKV) { src = s3;  base = OFF_WQR; }
    else if (gid < OFF_WUKV) { src = s4;  base = OFF_WDKV; }
    else if (gid < OFF_WKR)  { src = s5;  base = OFF_WUKV; }
    else if (gid < OFF_WO)   { src = s6;  base = OFF_WKR; }
    else if (gid < OFF_QG)   { src = s7;  base = OFF_WO; }
    else if (gid < OFF_QB)   { src = s8;  base = OFF_QG; }
    else if (gid < OFF_KG)   { src = s9;  base = OFF_QB; }
    else if (gid < OFF_KB)   { src = s10; base = OFF_KG; }
    else                     { src = s11; base = OFF_KB; }
    int local = gid - base;
    u16 v;
    if (f) {
        float xv = ((const float*)src)[local];
        v = __builtin_bit_cast(u16, __float2bfloat16(xv));
    } else {
        v = ((const u16*)src)[local];
    }
    arena[gid] = v;
}

// ---------------- transpose + zero-pad all weights into WT arena ----------------
__global__ __launch_bounds__(256) void wt_all(const bf16* __restrict__ AR, bf16* __restrict__ WT) {
    int gid = blockIdx.x * 256 + threadIdx.x;
    if (gid >= T_TOT) return;
    const bf16* src; int base, Kp, Nv, Kv;
    if      (gid < T_DKV) { base = T_DQ;  Kp = 512; src = AR + OFF_WDQ;  Nv = 256;  Kv = 512; }
    else if (gid < T_KR)  { base = T_DKV; Kp = 512; src = AR + OFF_WDKV; Nv = 341;  Kv = 512; }
    else if (gid < T_UQ)  { base = T_KR;  Kp = 512; src = AR + OFF_WKR;  Nv = 64;   Kv = 512; }
    else if (gid < T_QR)  { base = T_UQ;  Kp = 256; src = AR + OFF_WUQ;  Nv = 512;  Kv = 256; }
    else if (gid < T_UKV) { base = T_QR;  Kp = 256; src = AR + OFF_WQR;  Nv = 64;   Kv = 256; }
    else                  { base = T_UKV; Kp = 384; src = AR + OFF_WUKV; Nv = 1024; Kv = 341; }
    int loc = gid - base;
    int n = loc / Kp, k = loc % Kp;
    bf16 v = __float2bfloat16(0.f);
    if (n < Nv && k < Kv) v = src[(size_t)k * Nv + n];
    WT[gid] = v;
}

// ------- 128x64 bf16 MFMA GEMM, BK=64, global_load_lds staging + XOR swizzle -------
// Linear LDS tiles (row=128B), source col pre-swizzled ((l&7)^(l>>3))*8, reads
// swizzled byte ^((row&7)<<4). 4 waves x 32(M)x64(N).
// modes: 0 fp32->C0(ldc); 1 dual->C0/C0f; 3 KV-scatter (K direct, V via LDS
// transpose -> coalesced V^T); 4 Q-scatter (gn<512) + y_qr fp32 tail.
__global__ __launch_bounds__(256) void gemm128(
    const bf16* __restrict__ A, int lda,
    const bf16* __restrict__ BT, int ldb,
    int N, int Kpad, int mode,
    void* __restrict__ C0, int ldc,
    bf16* __restrict__ kv_k, bf16* __restrict__ kv_v,
    const int* __restrict__ flagp, float* __restrict__ C0f)
{
    __shared__ __align__(16) bf16 LB[128 * 64 + 64 * 64];   // Al 16KB | Bl 8KB
    bf16* Al = LB;
    bf16* Bl = LB + 128 * 64;
    const int tid = threadIdx.x;
    const int m0 = blockIdx.y * 128, n0 = blockIdx.x * 64;
    const int lane = tid & 63, w = tid >> 6;
    const int g = lane >> 4, lr = lane & 15;
    f32x4 acc[2][4] = {};
    const int r8 = lane >> 3;
    const int xr8 = ((lane & 7) ^ r8) * 8;     // pre-swizzled source column (elems)
    const int swx = (lr & 7) << 4;             // read-side XOR (bytes)

    for (int k0 = 0; k0 < Kpad; k0 += 64) {
        #pragma unroll
        for (int i = 0; i < 4; ++i)
            GL16(&A[(size_t)(m0 + w * 32 + i * 8 + r8) * lda + k0 + xr8],
                 (char*)Al + w * 4096 + i * 1024);
        #pragma unroll
        for (int i = 0; i < 2; ++i)
            GL16(&BT[(size_t)(n0 + w * 16 + i * 8 + r8) * ldb + k0 + xr8],
                 (char*)Bl + w * 2048 + i * 1024);
        __syncthreads();   // drains vmcnt -> LDS writes complete
        #pragma unroll
        for (int ks = 0; ks < 2; ++ks) {
            const int cs = (ks * 64 + g * 16) ^ swx;
            bf16x8 a0 = ld_bf8((const bf16*)((const char*)Al + (w * 32 + lr) * 128 + cs));
            bf16x8 a1 = ld_bf8((const bf16*)((const char*)Al + (w * 32 + 16 + lr) * 128 + cs));
            #pragma unroll
            for (int nt = 0; nt < 4; ++nt) {
                bf16x8 b = ld_bf8((const bf16*)((const char*)Bl + (nt * 16 + lr) * 128 + cs));
                acc[0][nt] = __builtin_amdgcn_mfma_f32_16x16x32_bf16(a0, b, acc[0][nt], 0, 0, 0);
                acc[1][nt] = __builtin_amdgcn_mfma_f32_16x16x32_bf16(a1, b, acc[1][nt], 0, 0, 0);
            }
        }
        __syncthreads();
    }

    if (mode == 3 && n0 >= DM) {
        // V block (spans exactly one head): LDS transpose -> coalesced V^T rows
        const int h = (n0 - DM) >> 6;
        const int b = m0 >> 11, s0 = m0 & 2047;
        bf16* T = LB;   // [64][stride 136]
        #pragma unroll
        for (int mt = 0; mt < 2; ++mt)
        #pragma unroll
        for (int nt = 0; nt < 4; ++nt)
        #pragma unroll
        for (int r = 0; r < 4; ++r) {
            int dv = nt * 16 + lr;
            int sl = w * 32 + mt * 16 + g * 4 + r;
            T[dv * 136 + sl] = __float2bfloat16(acc[mt][nt][r]);
        }
        __syncthreads();
        const int row = tid >> 2, coff = (tid & 3) * 32;
        bf16* dst = &kv_v[((size_t)(b * NH + h) * DHD + row) * SEQ + s0 + coff];
        const bf16* srcp = &T[row * 136 + coff];
        #pragma unroll
        for (int q2 = 0; q2 < 4; ++q2)
            *(uint4*)(dst + q2 * 8) = *(const uint4*)(srcp + q2 * 8);
        return;
    }

    const int f32o = (mode == 1 && flagp) ? *flagp : 0;
    #pragma unroll
    for (int mt = 0; mt < 2; ++mt)
    #pragma unroll
    for (int nt = 0; nt < 4; ++nt)
    #pragma unroll
    for (int r = 0; r < 4; ++r) {
        int gm = m0 + w * 32 + mt * 16 + g * 4 + r;
        int gn = n0 + nt * 16 + lr;
        float v = acc[mt][nt][r];
        if (mode == 0) {
            ((float*)C0)[(size_t)gm * ldc + gn] = v;
        } else if (mode == 1) {
            if (f32o) C0f[(size_t)gm * ldc + gn] = v;
            else ((bf16*)C0)[(size_t)gm * ldc + gn] = __float2bfloat16(v);
        } else if (mode == 4) {
            int b = gm >> 11, s = gm & 2047;
            if (gn < DM) {
                int h = gn >> 6, dh = gn & 63;
                ((bf16*)C0)[((size_t)(b * NH + h) * SEQ + s) * DQKPAD + dh] = __float2bfloat16(v);
            } else {
                C0f[(size_t)gm * 64 + (gn - DM)] = v;
            }
        } else { // mode 3 K block: direct scatter [bh][s][96]
            int b = gm >> 11, s = gm & 2047;
            int h = gn >> 6, dh = gn & 63;
            kv_k[((size_t)(b * NH + h) * SEQ + s) * DQKPAD + dh] = __float2bfloat16(v);
        }
    }
}

// ------- row layernorm, one wave per row (4 rows/block, shuffle-only) -------
__global__ __launch_bounds__(256) void ln_wave(
    const float* __restrict__ Y, int ldy, int N,
    const bf16* __restrict__ gam, const bf16* __restrict__ bet,
    bf16* __restrict__ O1, float* __restrict__ O1f, const int* __restrict__ flagp, int ld1,
    bf16* __restrict__ O2, int ld2, int padN)
{
    const int w = threadIdx.x >> 6, lane = threadIdx.x & 63;
    const int row = blockIdx.x * 4 + w;
    const float* y = Y + (size_t)row * ldy;
    const int f32o = flagp ? *flagp : 0;
    float s = 0.f, ss = 0.f;
    for (int i = lane; i < N; i += 64) { float v = y[i]; s += v; ss += v * v; }
    #pragma unroll
    for (int m = 1; m < 64; m <<= 1) { s += __shfl_xor(s, m); ss += __shfl_xor(ss, m); }
    float mean = s / N;
    float var = ss / N - mean * mean;
    float rstd = rsqrtf(var + 1e-5f);
    for (int i = lane; i < N; i += 64) {
        float v = (y[i] - mean) * rstd * __bfloat162float(gam[i]) + __bfloat162float(bet[i]);
        if (f32o) O1f[(size_t)row * ld1 + i] = v;
        else O1[(size_t)row * ld1 + i] = __float2bfloat16(v);
        if (O2) O2[(size_t)row * ld2 + i] = __float2bfloat16(v);
    }
    if (O2) for (int i = N + lane; i < padN; i += 64) O2[(size_t)row * ld2 + i] = __float2bfloat16(0.f);
}

// ---------------- rope + pad fill for q/k rope tails ----------------
__global__ __launch_bounds__(256) void rope_fill(
    const float* __restrict__ yqr, int ldq,
    const float* __restrict__ ykr, int ldk,
    bf16* __restrict__ qa, bf16* __restrict__ ka)
{
    int idx = blockIdx.x * 256 + threadIdx.x;
    if (idx >= MROWS * NH) return;
    int m = idx >> 3, h = idx & 7;
    int b = m >> 11, s = m & 2047;
    float q[8], k[8], qo[8], ko[8];
    #pragma unroll
    for (int j = 0; j < 8; ++j) {
        q[j] = yqr[(size_t)m * ldq + h * 8 + j];
        k[j] = ykr[(size_t)m * ldk + h * 8 + j];
    }
    #pragma unroll
    for (int i = 0; i < 4; ++i) {
        float inv = exp2f(-(float)i * 3.3219280948873623f);  // 10000^(-i/4)
        float ang = (float)s * inv;
        float sn, cs;
        sincosf(ang, &sn, &cs);
        qo[i] = q[i] * cs - q[i + 4] * sn;
        qo[i + 4] = q[i + 4] * cs + q[i] * sn;
        ko[i] = k[i] * cs - k[i + 4] * sn;
        ko[i + 4] = k[i + 4] * cs + k[i] * sn;
    }
    bf16* qp = qa + ((size_t)(b * NH + h) * SEQ + s) * DQKPAD;
    bf16* kp = ka + ((size_t)(b * NH + h) * SEQ + s) * DQKPAD;
    #pragma unroll
    for (int j = 0; j < 8; ++j) {
        qp[64 + j] = __float2bfloat16(qo[j]);
        kp[64 + j] = __float2bfloat16(ko[j]);
    }
    #pragma unroll
    for (int j = 72; j < 96; ++j) {
        qp[j] = __float2bfloat16(0.f);
        kp[j] = __float2bfloat16(0.f);
    }
}

// ---- causal flash attention: split-KV + qb-pairing + swapped QK^T softmax ----
__global__ __launch_bounds__(256) void attn_split3(
    const bf16* __restrict__ qa, const bf16* __restrict__ ka, const bf16* __restrict__ vat,
    bf16* __restrict__ po, float* __restrict__ mlm, float* __restrict__ mll)
{
    __shared__ __align__(16) bf16 Kl[64][104];
    __shared__ __align__(16) bf16 Vt[64][72];
    __shared__ __align__(16) bf16 Pl[4][16][72];
    const int sp = blockIdx.x, pr = blockIdx.y, bh = blockIdx.z;
    const int tid = threadIdx.x, w = tid >> 6, lane = tid & 63;
    const int g = lane >> 4, lr = lane & 15;
    const size_t base = (size_t)bh * SEQ;
    const float SC = 0.11785113019775793f;   // 1/sqrt(72)
    const float L2E = 1.4426950408889634f;
    const bf16* vb = vat + (size_t)bh * DHD * SEQ;

    for (int half = 0; half < 2; ++half) {
        const int qb = half ? (31 - pr) : pr;
        const int qrow0 = qb * 64 + w * 16;
        const int myq = qrow0 + lr;

        bf16x8 qf[3];
        #pragma unroll
        for (int kc = 0; kc < 3; ++kc)
            qf[kc] = ld_bf8(&qa[(base + myq) * DQKPAD + kc * 32 + g * 8]);

        float m_p = -1e30f, l_p = 0.f;
        f32x4 acc_o[4] = {};
        const int ng = qb + 1;
        const int bs = (ng * sp) >> 2, be = (ng * (sp + 1)) >> 2;

        for (int gi = bs; gi < be; ++gi) {
            const int j0 = gi * 64;
            __syncthreads();
            for (int u = tid; u < 768; u += 256) {
                int row = u / 12, cc = (u % 12) * 8;
                *(uint4*)&Kl[row][cc] = *(const uint4*)&ka[(base + j0 + row) * DQKPAD + cc];
            }
            {
                int d = tid >> 2, ko = (tid & 3) * 16;
                const bf16* vsrc = &vb[(size_t)d * SEQ + j0 + ko];
                *(uint4*)&Vt[d][ko]     = *(const uint4*)vsrc;
                *(uint4*)&Vt[d][ko + 8] = *(const uint4*)(vsrc + 8);
            }
            __syncthreads();

            f32x4 accs[4] = {};
            #pragma unroll
            for (int kc = 0; kc < 3; ++kc) {
                #pragma unroll
                for (int nt = 0; nt < 4; ++nt) {
                    bf16x8 kf = ld_bf8(&Kl[nt * 16 + lr][kc * 32 + g * 8]);
                    accs[nt] = __builtin_amdgcn_mfma_f32_16x16x32_bf16(kf, qf[kc], accs[nt], 0, 0, 0);
                }
            }
            float s[4][4];
            float mloc = -1e30f;
            #pragma unroll
            for (int nt = 0; nt < 4; ++nt)
            #pragma unroll
            for (int r = 0; r < 4; ++r) {
                int key = j0 + nt * 16 + g * 4 + r;
                float sv = accs[nt][r] * SC;
                sv = (key <= myq) ? sv : -1e30f;
                s[nt][r] = sv;
                mloc = fmaxf(mloc, sv);
            }
            mloc = fmaxf(mloc, __shfl_xor(mloc, 16));
            mloc = fmaxf(mloc, __shfl_xor(mloc, 32));
            float mn = fmaxf(m_p, mloc);
            float alpha = exp2f((m_p - mn) * L2E);
            m_p = mn;
            float rs = 0.f;
            #pragma unroll
            for (int nt = 0; nt < 4; ++nt)
            #pragma unroll
            for (int r = 0; r < 4; ++r) {
                float p = exp2f((s[nt][r] - mn) * L2E);
                s[nt][r] = p; rs += p;
            }
            rs += __shfl_xor(rs, 16);
            rs += __shfl_xor(rs, 32);
            l_p = l_p * alpha + rs;
            float ar[4];
            #pragma unroll
            for (int r = 0; r < 4; ++r) ar[r] = __shfl(alpha, g * 4 + r);
            #pragma unroll
            for (int nv = 0; nv < 4; ++nv)
            #pragma unroll
            for (int r = 0; r < 4; ++r) acc_o[nv][r] *= ar[r];
            #pragma unroll
            for (int nt = 0; nt < 4; ++nt) {
                ushort4 pk;
                pk.x = __builtin_bit_cast(u16, __float2bfloat16(s[nt][0]));
                pk.y = __builtin_bit_cast(u16, __float2bfloat16(s[nt][1]));
                pk.z = __builtin_bit_cast(u16, __float2bfloat16(s[nt][2]));
                pk.w = __builtin_bit_cast(u16, __float2bfloat16(s[nt][3]));
                *(ushort4*)&Pl[w][lr][nt * 16 + g * 4] = pk;
            }
            bf16x8 pf0 = ld_bf8(&Pl[w][lr][g * 8]);
            bf16x8 pf1 = ld_bf8(&Pl[w][lr][32 + g * 8]);
            #pragma unroll
            for (int nv = 0; nv < 4; ++nv) {
                bf16x8 vf0 = ld_bf8(&Vt[nv * 16 + lr][g * 8]);
                acc_o[nv] = __builtin_amdgcn_mfma_f32_16x16x32_bf16(pf0, vf0, acc_o[nv], 0, 0, 0);
                bf16x8 vf1 = ld_bf8(&Vt[nv * 16 + lr][32 + g * 8]);
                acc_o[nv] = __builtin_amdgcn_mfma_f32_16x16x32_bf16(pf1, vf1, acc_o[nv], 0, 0, 0);
            }
        }

        const size_t pb = (size_t)(bh * 4 + sp) * SEQ;
        #pragma unroll
        for (int r = 0; r < 4; ++r) {
            int qrow = qrow0 + g * 4 + r;
            #pragma unroll
            for (int nv = 0; nv < 4; ++nv)
                po[(pb + qrow) * DHD + nv * 16 + lr] = __float2bfloat16(acc_o[nv][r]);
        }
        if (lane < 16) {
            mlm[pb + qrow0 + lane] = m_p;
            mll[pb + qrow0 + lane] = l_p;
        }
    }
}

// ---------------- combine split partials -> attn_o [b][s][h*64+d] ----------------
__global__ __launch_bounds__(256) void attn_combine(
    const bf16* __restrict__ po, const float* __restrict__ mlm, const float* __restrict__ mll,
    bf16* __restrict__ ao)
{
    int id = blockIdx.x * 256 + threadIdx.x;   // 16*2048*8 = 262144
    int bh = id >> 14;
    int rem = id & 16383;
    int q = rem >> 3, dc = (rem & 7) * 8;
    const float L2E = 1.4426950408889634f;
    size_t mlb = (size_t)bh * 4 * SEQ + q;
    float ms[4], ls[4];
    #pragma unroll
    for (int s = 0; s < 4; ++s) { ms[s] = mlm[mlb + (size_t)s * SEQ]; ls[s] = mll[mlb + (size_t)s * SEQ]; }
    float M = fmaxf(fmaxf(ms[0], ms[1]), fmaxf(ms[2], ms[3]));
    float wsc[4]; float L = 0.f;
    #pragma unroll
    for (int s = 0; s < 4; ++s) { wsc[s] = exp2f((ms[s] - M) * L2E); L += wsc[s] * ls[s]; }
    float o[8] = {};
    #pragma unroll
    for (int s = 0; s < 4; ++s) {
        if (ls[s] <= 0.f) continue;
        bf16x8 pv = ld_bf8(&po[((size_t)(bh * 4 + s) * SEQ + q) * DHD + dc]);
        #pragma unroll
        for (int j = 0; j < 8; ++j) o[j] += wsc[s] * (float)pv[j];
    }
    float invL = 1.f / L;
    int b = bh >> 3, h = bh & 7;
    __bf16 tmp[8];
    #pragma unroll
    for (int j = 0; j < 8; ++j) tmp[j] = (__bf16)(o[j] * invL);
    *(uint4*)&ao[((size_t)(b * SEQ) + q) * DM + h * DHD + dc] = *(uint4*)tmp;
}

extern "C" void kernel_launch(void* const* d_in, const int* in_sizes, int n_in,
                              void* d_out, int out_size, void* d_ws, size_t ws_size,
                              hipStream_t stream) {
    char* ws = (char*)d_ws;
    bf16* AR      = (bf16*)(ws + 0);              // bf16 arena (x region dead after x-gemm)
    float* ml_m   = (float*)(ws + 0);             // alias x region (written by attn)
    float* ml_l   = (float*)(ws + 524288);
    bf16* WT      = (bf16*)(ws + 6391296);        // transposed weights (1,802,240 B)
    int*  flagp   = (int*)(ws + 8193536);
    float* y      = (float*)(ws + 8194048);       // fused x-proj out [4096][704] fp32
    float* y_qr   = (float*)(ws + 19728384);      // [4096][64] fp32
    bf16* cq      = (bf16*)(ws + 20776960);       // [4096][256]
    bf16* ckvp    = (bf16*)(ws + 22874112);       // [4096][384]
    bf16* po      = (bf16*)(ws + 8194048);        // alias dead y..ckvp region (16.78MB)
    bf16* q_attn  = (bf16*)(ws + 26019840);
    bf16* k_attn  = (bf16*)(ws + 32311296);
    bf16* v_attnT = (bf16*)(ws + 38602752);
    bf16* attn_o  = (bf16*)(ws + 42797056);

    const bf16* xb  = AR + OFF_X;
    const bf16* W_o = AR + OFF_WO;
    const bf16* qg  = AR + OFF_QG;
    const bf16* qb_ = AR + OFF_QB;
    const bf16* kg  = AR + OFF_KG;
    const bf16* kb  = AR + OFF_KB;

    bf16*  out_b = (bf16*)d_out;
    float* out_f = (float*)d_out;
    bf16*  ckv_b = out_b + (size_t)MROWS * DM;
    float* ckv_f = out_f + (size_t)MROWS * DM;

    dim3 blk(256);
    detect_k<<<1, blk, 0, stream>>>((const u16*)d_in[0], flagp);
    cvt_all<<<dim3((N_ELEMS + 255) / 256), blk, 0, stream>>>(
        d_in[0], d_in[1], d_in[2], d_in[3], d_in[4], d_in[5],
        d_in[6], d_in[7], d_in[8], d_in[9], d_in[10], d_in[11],
        (u16*)AR, flagp);
    wt_all<<<dim3((T_TOT + 255) / 256), blk, 0, stream>>>(AR, WT);

    // fused low-rank projections from x: [dq(256) | dkv(384) | kr(64)] N=704
    gemm128<<<dim3(11, 32), blk, 0, stream>>>(xb, DM, WT + T_DQ, DM, 704, DM, 0, y, 704, nullptr, nullptr, nullptr, nullptr);
    // layernorms (strided reads from fused y), wave-per-row
    ln_wave<<<MROWS / 4, blk, 0, stream>>>(y, 704, QP, qg, qb_, cq, nullptr, nullptr, QP, nullptr, 0, 0);
    ln_wave<<<MROWS / 4, blk, 0, stream>>>(y + 256, 704, KVP, kg, kb, ckv_b, ckv_f, flagp, KVP, ckvp, 384, 384);
    // fused cq up-projection: [uq(512) scatter | qr(64) fp32] N=576
    gemm128<<<dim3(9, 32), blk, 0, stream>>>(cq, QP, WT + T_UQ, QP, 576, QP, 4, q_attn, 0, nullptr, nullptr, nullptr, y_qr);
    // kv up-projection (K scatter + V^T via LDS transpose), N=1024, K=384
    gemm128<<<dim3(16, 32), blk, 0, stream>>>(ckvp, 384, WT + T_UKV, 384, 1024, 384, 3, nullptr, 0, k_attn, v_attnT, nullptr, nullptr);
    // rope tails + pad zeros
    rope_fill<<<dim3(MROWS * NH / 256), blk, 0, stream>>>(y_qr, 64, y + 640, 704, q_attn, k_attn);
    // attention (split-KV, qb-paired, swapped-softmax) + combine
    attn_split3<<<dim3(4, 16, 16), blk, 0, stream>>>(q_attn, k_attn, v_attnT, po, ml_m, ml_l);
    attn_combine<<<dim3(16 * SEQ * 8 / 256), blk, 0, stream>>>(po, ml_m, ml_l, attn_o);
    // output projection (W_o natural [N][K]) -> d_out (dual dtype), N=512
    gemm128<<<dim3(8, 32), blk, 0, stream>>>(attn_o, DM, W_o, DM, DM, DM, 1, out_b, DM, nullptr, nullptr, flagp, out_f);
}

// Round 10
// 127.870 us; speedup vs baseline: 3.1223x; 1.0330x over previous
//
#include <hip/hip_runtime.h>
#include <hip/hip_bf16.h>

#define BATCH 2
#define SEQ 2048
#define DM 512
#define NH 8
#define DHD 64
#define QP 256
#define KVP 341
#define DQKPAD 96
#define MROWS 4096   // BATCH*SEQ

// bf16 arena element offsets (x, W_o, LN params only)
#define OFF_X     0
#define OFF_WO    2932224
#define OFF_QG    3194368
#define OFF_QB    3194624
#define OFF_KG    3194880
#define OFF_KB    3195221

// transposed-weight arena element offsets ([N][K])
#define T_DQ   0        // [256][512]
#define T_DKV  131072   // [384][512] (n>=341 zero)
#define T_KR   327680   // [64][512]
#define T_UQ   360448   // [512][256]
#define T_QR   491520   // [64][256]
#define T_UKV  507904   // [1024][384] (k>=341 zero)
#define T_TOT  901120

#define NW_X   2097152
#define NW_WO  262144
#define NW_PAR 1194
#define PREP_TOT (NW_X + NW_WO + NW_PAR + T_TOT)

typedef __bf16 bf16x8 __attribute__((ext_vector_type(8)));
typedef float f32x4 __attribute__((ext_vector_type(4)));
typedef __hip_bfloat16 bf16;
typedef unsigned short u16;

static __device__ __forceinline__ bf16x8 ld_bf8(const bf16* p) {
    return __builtin_bit_cast(bf16x8, *(const uint4*)p);
}

// async global->LDS, 16B per lane; LDS dest = wave-uniform base + lane*16
#define GL16(gp, lp) __builtin_amdgcn_global_load_lds( \
    (const __attribute__((address_space(1))) void*)(gp), \
    (__attribute__((address_space(3))) void*)(lp), 16, 0, 0)

// ---------- prep: dtype-flag + convert x/W_o/params + weight transposes ----------
__global__ __launch_bounds__(256) void prep(
    const void* px, const void* pwdq, const void* pwuq, const void* pwqr,
    const void* pwdkv, const void* pwukv, const void* pwkr, const void* pwo,
    const void* pqg, const void* pqb, const void* pkg, const void* pkb,
    u16* __restrict__ arena, u16* __restrict__ WT, int* __restrict__ flagp)
{
    __shared__ int cnt;
    if (threadIdx.x == 0) cnt = 0;
    __syncthreads();
    int bad = 0;
    const u16* xs = (const u16*)px;
    for (int i = threadIdx.x; i < 2048; i += 256) {
        u16 u = xs[i];
        int e = (u >> 7) & 0xFF;
        if (u != 0 && (e < 90 || e > 164)) bad++;
    }
    #pragma unroll
    for (int m2 = 1; m2 < 64; m2 <<= 1) bad += __shfl_xor(bad, m2);
    if ((threadIdx.x & 63) == 0) atomicAdd(&cnt, bad);
    __syncthreads();
    const int f = (cnt > 256) ? 1 : 0;   // 1 => inputs are fp32
    if (blockIdx.x == 0 && threadIdx.x == 0) *flagp = f;

    int gid = blockIdx.x * 256 + threadIdx.x;
    if (gid >= PREP_TOT) return;

    auto rdu = [&](const void* s, int i) -> u16 {
        if (f) return __builtin_bit_cast(u16, __float2bfloat16(((const float*)s)[i]));
        return ((const u16*)s)[i];
    };

    if (gid < NW_X) {
        arena[OFF_X + gid] = rdu(px, gid);
    } else if (gid < NW_X + NW_WO) {
        int i = gid - NW_X;
        arena[OFF_WO + i] = rdu(pwo, i);
    } else if (gid < NW_X + NW_WO + NW_PAR) {
        int i = gid - NW_X - NW_WO;
        if (i < 256)      arena[OFF_QG + i]         = rdu(pqg, i);
        else if (i < 512) arena[OFF_QB + (i - 256)] = rdu(pqb, i - 256);
        else if (i < 853) arena[OFF_KG + (i - 512)] = rdu(pkg, i - 512);
        else              arena[OFF_KB + (i - 853)] = rdu(pkb, i - 853);
    } else {
        int loc = gid - (NW_X + NW_WO + NW_PAR);
        const void* src; int srcIdx, valid;
        if (loc < T_DKV)      { int l2 = loc;          int n = l2 >> 9, k = l2 & 511; src = pwdq;  valid = 1;         srcIdx = k * 256 + n; }
        else if (loc < T_KR)  { int l2 = loc - T_DKV;  int n = l2 >> 9, k = l2 & 511; src = pwdkv; valid = (n < 341); srcIdx = k * 341 + n; }
        else if (loc < T_UQ)  { int l2 = loc - T_KR;   int n = l2 >> 9, k = l2 & 511; src = pwkr;  valid = 1;         srcIdx = k * 64 + n; }
        else if (loc < T_QR)  { int l2 = loc - T_UQ;   int n = l2 >> 8, k = l2 & 255; src = pwuq;  valid = 1;         srcIdx = k * 512 + n; }
        else if (loc < T_UKV) { int l2 = loc - T_QR;   int n = l2 >> 8, k = l2 & 255; src = pwqr;  valid = 1;         srcIdx = k * 64 + n; }
        else                  { int l2 = loc - T_UKV;  int n = l2 / 384, k = l2 % 384; src = pwukv; valid = (k < 341); srcIdx = k * 1024 + n; }
        WT[loc] = valid ? rdu(src, srcIdx) : (u16)0;
    }
}

// ---------- rope epilogue: acc holds 64 rope cols for 128 rows; partner via shfl ----------
static __device__ __forceinline__ void rope_epi(
    f32x4 (&acc)[2][4], bf16* __restrict__ dst, int m0, int w, int g, int lr, int tid, bool scaleq)
{
    const float SCv = 0.11785113019775793f;   // 1/sqrt(72)
    #pragma unroll
    for (int mt = 0; mt < 2; ++mt)
    #pragma unroll
    for (int r = 0; r < 4; ++r) {
        int gm = m0 + w * 32 + mt * 16 + g * 4 + r;
        int s = gm & 2047, b = gm >> 11;
        float ang = (float)s * exp2f(-(float)(lr & 3) * 3.3219280948873623f);
        float sn, cs;
        sincosf(ang, &sn, &cs);
        #pragma unroll
        for (int nt = 0; nt < 4; ++nt) {
            float v = acc[mt][nt][r];
            float pt = __shfl_xor(v, 4);
            float o = (lr & 4) ? fmaf(pt, sn, v * cs) : fmaf(-pt, sn, v * cs);
            if (scaleq) o *= SCv;
            int h = (nt * 16 + lr) >> 3, j = lr & 7;
            dst[((size_t)(b * NH + h) * SEQ + s) * DQKPAD + 64 + j] = __float2bfloat16(o);
        }
    }
    // zero pads [72,96) for all 8 heads of these 128 rows
    for (int u = tid; u < 128 * 96; u += 256) {
        int rw = u / 96, rem = u - rw * 96;
        int h = rem / 12, c = rem - h * 12;
        int row = m0 + rw, b2 = row >> 11, s2 = row & 2047;
        *(unsigned int*)&dst[((size_t)(b2 * NH + h) * SEQ + s2) * DQKPAD + 72 + c * 2] = 0u;
    }
}

// ------- 128x64 bf16 MFMA GEMM, BK=64, global_load_lds staging + XOR swizzle -------
// modes: 0 fp32->C0 (n0==640: kr-rope -> kv_k); 1 dual->C0/C0f;
// 3 KV-scatter (K direct, V via LDS transpose); 4 Q-scatter scaled (n0==512: q-rope).
__global__ __launch_bounds__(256) void gemm128(
    const bf16* __restrict__ A, int lda,
    const bf16* __restrict__ BT, int ldb,
    int N, int Kpad, int mode,
    void* __restrict__ C0, int ldc,
    bf16* __restrict__ kv_k, bf16* __restrict__ kv_v,
    const int* __restrict__ flagp, float* __restrict__ C0f)
{
    __shared__ __align__(16) bf16 LB[128 * 64 + 64 * 64];   // Al 16KB | Bl 8KB
    bf16* Al = LB;
    bf16* Bl = LB + 128 * 64;
    const int tid = threadIdx.x;
    const int m0 = blockIdx.y * 128, n0 = blockIdx.x * 64;
    const int lane = tid & 63, w = tid >> 6;
    const int g = lane >> 4, lr = lane & 15;
    f32x4 acc[2][4] = {};
    const int r8 = lane >> 3;
    const int xr8 = ((lane & 7) ^ r8) * 8;     // pre-swizzled source column (elems)
    const int swx = (lr & 7) << 4;             // read-side XOR (bytes)

    for (int k0 = 0; k0 < Kpad; k0 += 64) {
        #pragma unroll
        for (int i = 0; i < 4; ++i)
            GL16(&A[(size_t)(m0 + w * 32 + i * 8 + r8) * lda + k0 + xr8],
                 (char*)Al + w * 4096 + i * 1024);
        #pragma unroll
        for (int i = 0; i < 2; ++i)
            GL16(&BT[(size_t)(n0 + w * 16 + i * 8 + r8) * ldb + k0 + xr8],
                 (char*)Bl + w * 2048 + i * 1024);
        __syncthreads();
        #pragma unroll
        for (int ks = 0; ks < 2; ++ks) {
            const int cs = (ks * 64 + g * 16) ^ swx;
            bf16x8 a0 = ld_bf8((const bf16*)((const char*)Al + (w * 32 + lr) * 128 + cs));
            bf16x8 a1 = ld_bf8((const bf16*)((const char*)Al + (w * 32 + 16 + lr) * 128 + cs));
            #pragma unroll
            for (int nt = 0; nt < 4; ++nt) {
                bf16x8 b = ld_bf8((const bf16*)((const char*)Bl + (nt * 16 + lr) * 128 + cs));
                acc[0][nt] = __builtin_amdgcn_mfma_f32_16x16x32_bf16(a0, b, acc[0][nt], 0, 0, 0);
                acc[1][nt] = __builtin_amdgcn_mfma_f32_16x16x32_bf16(a1, b, acc[1][nt], 0, 0, 0);
            }
        }
        __syncthreads();
    }

    if (mode == 0 && n0 == 640) {       // kr-rope block (unscaled) -> k_attn
        rope_epi(acc, kv_k, m0, w, g, lr, tid, false);
        return;
    }
    if (mode == 4 && n0 == DM) {        // qr-rope block (scaled) -> q_attn
        rope_epi(acc, (bf16*)C0, m0, w, g, lr, tid, true);
        return;
    }
    if (mode == 3 && n0 >= DM) {
        // V block: LDS transpose -> coalesced V^T rows
        const int h = (n0 - DM) >> 6;
        const int b = m0 >> 11, s0 = m0 & 2047;
        bf16* T = LB;   // [64][stride 136]
        #pragma unroll
        for (int mt = 0; mt < 2; ++mt)
        #pragma unroll
        for (int nt = 0; nt < 4; ++nt)
        #pragma unroll
        for (int r = 0; r < 4; ++r) {
            int dv = nt * 16 + lr;
            int sl = w * 32 + mt * 16 + g * 4 + r;
            T[dv * 136 + sl] = __float2bfloat16(acc[mt][nt][r]);
        }
        __syncthreads();
        const int row = tid >> 2, coff = (tid & 3) * 32;
        bf16* dst = &kv_v[((size_t)(b * NH + h) * DHD + row) * SEQ + s0 + coff];
        const bf16* srcp = &T[row * 136 + coff];
        #pragma unroll
        for (int q2 = 0; q2 < 4; ++q2)
            *(uint4*)(dst + q2 * 8) = *(const uint4*)(srcp + q2 * 8);
        return;
    }

    const float SCv = 0.11785113019775793f;
    const int f32o = (mode == 1 && flagp) ? *flagp : 0;
    #pragma unroll
    for (int mt = 0; mt < 2; ++mt)
    #pragma unroll
    for (int nt = 0; nt < 4; ++nt)
    #pragma unroll
    for (int r = 0; r < 4; ++r) {
        int gm = m0 + w * 32 + mt * 16 + g * 4 + r;
        int gn = n0 + nt * 16 + lr;
        float v = acc[mt][nt][r];
        if (mode == 0) {
            ((float*)C0)[(size_t)gm * ldc + gn] = v;
        } else if (mode == 1) {
            if (f32o) C0f[(size_t)gm * ldc + gn] = v;
            else ((bf16*)C0)[(size_t)gm * ldc + gn] = __float2bfloat16(v);
        } else if (mode == 4) {
            int b = gm >> 11, s = gm & 2047;
            int h = gn >> 6, dh = gn & 63;
            ((bf16*)C0)[((size_t)(b * NH + h) * SEQ + s) * DQKPAD + dh] = __float2bfloat16(v * SCv);
        } else { // mode 3 K block: direct scatter [bh][s][96]
            int b = gm >> 11, s = gm & 2047;
            int h = gn >> 6, dh = gn & 63;
            kv_k[((size_t)(b * NH + h) * SEQ + s) * DQKPAD + dh] = __float2bfloat16(v);
        }
    }
}

// ------- merged layernorms, one wave per row -------
__global__ __launch_bounds__(256) void ln_both(
    const float* __restrict__ y,
    const bf16* __restrict__ qg, const bf16* __restrict__ qb,
    const bf16* __restrict__ kg, const bf16* __restrict__ kb,
    bf16* __restrict__ cq, bf16* __restrict__ ckv_b, float* __restrict__ ckv_f,
    bf16* __restrict__ ckvp, const int* __restrict__ flagp)
{
    const int w = threadIdx.x >> 6, lane = threadIdx.x & 63;
    const int blk = blockIdx.x;
    if (blk < 1024) {
        const int row = blk * 4 + w;
        const float* yr = y + (size_t)row * 704;
        float s = 0.f, ss = 0.f;
        for (int i = lane; i < 256; i += 64) { float v = yr[i]; s += v; ss += v * v; }
        #pragma unroll
        for (int m = 1; m < 64; m <<= 1) { s += __shfl_xor(s, m); ss += __shfl_xor(ss, m); }
        float mean = s * (1.f / 256.f);
        float var = ss * (1.f / 256.f) - mean * mean;
        float rstd = rsqrtf(var + 1e-5f);
        for (int i = lane; i < 256; i += 64) {
            float v = (yr[i] - mean) * rstd * __bfloat162float(qg[i]) + __bfloat162float(qb[i]);
            cq[(size_t)row * 256 + i] = __float2bfloat16(v);
        }
    } else {
        const int row = (blk - 1024) * 4 + w;
        const float* yr = y + (size_t)row * 704 + 256;
        const int f32o = *flagp;
        float s = 0.f, ss = 0.f;
        for (int i = lane; i < KVP; i += 64) { float v = yr[i]; s += v; ss += v * v; }
        #pragma unroll
        for (int m = 1; m < 64; m <<= 1) { s += __shfl_xor(s, m); ss += __shfl_xor(ss, m); }
        float mean = s * (1.f / 341.f);
        float var = ss * (1.f / 341.f) - mean * mean;
        float rstd = rsqrtf(var + 1e-5f);
        for (int i = lane; i < KVP; i += 64) {
            float v = (yr[i] - mean) * rstd * __bfloat162float(kg[i]) + __bfloat162float(kb[i]);
            if (f32o) ckv_f[(size_t)row * KVP + i] = v;
            else ckv_b[(size_t)row * KVP + i] = __float2bfloat16(v);
            ckvp[(size_t)row * 384 + i] = __float2bfloat16(v);
        }
        for (int i = KVP + lane; i < 384; i += 64) ckvp[(size_t)row * 384 + i] = __float2bfloat16(0.f);
    }
}

// ---- causal flash attention: split-KV + qb-pairing + swapped QK^T + defer-max ----
__global__ __launch_bounds__(256) void attn_split3(
    const bf16* __restrict__ qa, const bf16* __restrict__ ka, const bf16* __restrict__ vat,
    bf16* __restrict__ po, float* __restrict__ mlm, float* __restrict__ mll)
{
    __shared__ __align__(16) bf16 Kl[64][104];
    __shared__ __align__(16) bf16 Vt[64][72];
    __shared__ __align__(16) bf16 Pl[4][16][72];
    const int sp = blockIdx.x, pr = blockIdx.y, bh = blockIdx.z;
    const int tid = threadIdx.x, w = tid >> 6, lane = tid & 63;
    const int g = lane >> 4, lr = lane & 15;
    const size_t base = (size_t)bh * SEQ;
    const float L2E = 1.4426950408889634f;
    const bf16* vb = vat + (size_t)bh * DHD * SEQ;

    for (int half = 0; half < 2; ++half) {
        const int qb = half ? (31 - pr) : pr;
        const int qrow0 = qb * 64 + w * 16;
        const int myq = qrow0 + lr;

        bf16x8 qf[3];
        #pragma unroll
        for (int kc = 0; kc < 3; ++kc)
            qf[kc] = ld_bf8(&qa[(base + myq) * DQKPAD + kc * 32 + g * 8]);

        float m_p = -1e30f, l_p = 0.f;
        f32x4 acc_o[4] = {};
        const int ng = qb + 1;
        const int bs = (ng * sp) >> 2, be = (ng * (sp + 1)) >> 2;

        for (int gi = bs; gi < be; ++gi) {
            const int j0 = gi * 64;
            __syncthreads();
            for (int u = tid; u < 768; u += 256) {
                int row = u / 12, cc = (u % 12) * 8;
                *(uint4*)&Kl[row][cc] = *(const uint4*)&ka[(base + j0 + row) * DQKPAD + cc];
            }
            {
                int d = tid >> 2, ko = (tid & 3) * 16;
                const bf16* vsrc = &vb[(size_t)d * SEQ + j0 + ko];
                *(uint4*)&Vt[d][ko]     = *(const uint4*)vsrc;
                *(uint4*)&Vt[d][ko + 8] = *(const uint4*)(vsrc + 8);
            }
            __syncthreads();

            f32x4 accs[4] = {};
            #pragma unroll
            for (int kc = 0; kc < 3; ++kc) {
                #pragma unroll
                for (int nt = 0; nt < 4; ++nt) {
                    bf16x8 kf = ld_bf8(&Kl[nt * 16 + lr][kc * 32 + g * 8]);
                    accs[nt] = __builtin_amdgcn_mfma_f32_16x16x32_bf16(kf, qf[kc], accs[nt], 0, 0, 0);
                }
            }
            float s_[4][4];
            float mloc = -1e30f;
            if (j0 + 63 > qrow0) {          // diagonal granule: apply causal mask
                #pragma unroll
                for (int nt = 0; nt < 4; ++nt)
                #pragma unroll
                for (int r = 0; r < 4; ++r) {
                    int key = j0 + nt * 16 + g * 4 + r;
                    float sv = accs[nt][r];
                    sv = (key <= myq) ? sv : -1e30f;
                    s_[nt][r] = sv;
                    mloc = fmaxf(mloc, sv);
                }
            } else {                         // fully unmasked
                #pragma unroll
                for (int nt = 0; nt < 4; ++nt)
                #pragma unroll
                for (int r = 0; r < 4; ++r) {
                    float sv = accs[nt][r];
                    s_[nt][r] = sv;
                    mloc = fmaxf(mloc, sv);
                }
            }
            mloc = fmaxf(mloc, __shfl_xor(mloc, 16));
            mloc = fmaxf(mloc, __shfl_xor(mloc, 32));

            if (__all(mloc <= m_p + 8.f)) {  // defer-max: no rescale
                float rs = 0.f;
                #pragma unroll
                for (int nt = 0; nt < 4; ++nt)
                #pragma unroll
                for (int r = 0; r < 4; ++r) {
                    float p = exp2f((s_[nt][r] - m_p) * L2E);
                    s_[nt][r] = p; rs += p;
                }
                rs += __shfl_xor(rs, 16);
                rs += __shfl_xor(rs, 32);
                l_p += rs;
            } else {
                float mn = fmaxf(m_p, mloc);
                float alpha = exp2f((m_p - mn) * L2E);
                m_p = mn;
                float rs = 0.f;
                #pragma unroll
                for (int nt = 0; nt < 4; ++nt)
                #pragma unroll
                for (int r = 0; r < 4; ++r) {
                    float p = exp2f((s_[nt][r] - mn) * L2E);
                    s_[nt][r] = p; rs += p;
                }
                rs += __shfl_xor(rs, 16);
                rs += __shfl_xor(rs, 32);
                l_p = l_p * alpha + rs;
                float ar[4];
                #pragma unroll
                for (int r = 0; r < 4; ++r) ar[r] = __shfl(alpha, g * 4 + r);
                #pragma unroll
                for (int nv = 0; nv < 4; ++nv)
                #pragma unroll
                for (int r = 0; r < 4; ++r) acc_o[nv][r] *= ar[r];
            }
            #pragma unroll
            for (int nt = 0; nt < 4; ++nt) {
                ushort4 pk;
                pk.x = __builtin_bit_cast(u16, __float2bfloat16(s_[nt][0]));
                pk.y = __builtin_bit_cast(u16, __float2bfloat16(s_[nt][1]));
                pk.z = __builtin_bit_cast(u16, __float2bfloat16(s_[nt][2]));
                pk.w = __builtin_bit_cast(u16, __float2bfloat16(s_[nt][3]));
                *(ushort4*)&Pl[w][lr][nt * 16 + g * 4] = pk;
            }
            bf16x8 pf0 = ld_bf8(&Pl[w][lr][g * 8]);
            bf16x8 pf1 = ld_bf8(&Pl[w][lr][32 + g * 8]);
            #pragma unroll
            for (int nv = 0; nv < 4; ++nv) {
                bf16x8 vf0 = ld_bf8(&Vt[nv * 16 + lr][g * 8]);
                acc_o[nv] = __builtin_amdgcn_mfma_f32_16x16x32_bf16(pf0, vf0, acc_o[nv], 0, 0, 0);
                bf16x8 vf1 = ld_bf8(&Vt[nv * 16 + lr][32 + g * 8]);
                acc_o[nv] = __builtin_amdgcn_mfma_f32_16x16x32_bf16(pf1, vf1, acc_o[nv], 0, 0, 0);
            }
        }

        const size_t pb = (size_t)(bh * 4 + sp) * SEQ;
        #pragma unroll
        for (int r = 0; r < 4; ++r) {
            int qrow = qrow0 + g * 4 + r;
            #pragma unroll
            for (int nv = 0; nv < 4; ++nv)
                po[(pb + qrow) * DHD + nv * 16 + lr] = __float2bfloat16(acc_o[nv][r]);
        }
        if (lane < 16) {
            mlm[pb + qrow0 + lane] = m_p;
            mll[pb + qrow0 + lane] = l_p;
        }
    }
}

// ---------------- combine split partials -> attn_o [b][s][h*64+d] ----------------
__global__ __launch_bounds__(256) void attn_combine(
    const bf16* __restrict__ po, const float* __restrict__ mlm, const float* __restrict__ mll,
    bf16* __restrict__ ao)
{
    int id = blockIdx.x * 256 + threadIdx.x;   // 16*2048*8 = 262144
    int bh = id >> 14;
    int rem = id & 16383;
    int q = rem >> 3, dc = (rem & 7) * 8;
    const float L2E = 1.4426950408889634f;
    size_t mlb = (size_t)bh * 4 * SEQ + q;
    float ms[4], ls[4];
    #pragma unroll
    for (int s = 0; s < 4; ++s) { ms[s] = mlm[mlb + (size_t)s * SEQ]; ls[s] = mll[mlb + (size_t)s * SEQ]; }
    float M = fmaxf(fmaxf(ms[0], ms[1]), fmaxf(ms[2], ms[3]));
    float wsc[4]; float L = 0.f;
    #pragma unroll
    for (int s = 0; s < 4; ++s) { wsc[s] = exp2f((ms[s] - M) * L2E); L += wsc[s] * ls[s]; }
    float o[8] = {};
    #pragma unroll
    for (int s = 0; s < 4; ++s) {
        if (ls[s] <= 0.f) continue;
        bf16x8 pv = ld_bf8(&po[((size_t)(bh * 4 + s) * SEQ + q) * DHD + dc]);
        #pragma unroll
        for (int j = 0; j < 8; ++j) o[j] += wsc[s] * (float)pv[j];
    }
    float invL = 1.f / L;
    int b = bh >> 3, h = bh & 7;
    __bf16 tmp[8];
    #pragma unroll
    for (int j = 0; j < 8; ++j) tmp[j] = (__bf16)(o[j] * invL);
    *(uint4*)&ao[((size_t)(b * SEQ) + q) * DM + h * DHD + dc] = *(uint4*)tmp;
}

extern "C" void kernel_launch(void* const* d_in, const int* in_sizes, int n_in,
                              void* d_out, int out_size, void* d_ws, size_t ws_size,
                              hipStream_t stream) {
    char* ws = (char*)d_ws;
    bf16* AR      = (bf16*)(ws + 0);              // arena: x | W_o | params
    float* ml_m   = (float*)(ws + 0);             // alias x region (dead after x-gemm)
    float* ml_l   = (float*)(ws + 524288);
    bf16* WT      = (bf16*)(ws + 6391296);        // transposed weights (1,802,240 B)
    int*  flagp   = (int*)(ws + 8193536);
    float* y      = (float*)(ws + 8194048);       // fused x-proj out [4096][704] fp32
    bf16* cq      = (bf16*)(ws + 19728384);       // [4096][256]
    bf16* ckvp    = (bf16*)(ws + 21825536);       // [4096][384]
    bf16* po      = (bf16*)(ws + 8194048);        // alias dead y/cq/ckvp (16,777,216 B)
    bf16* q_attn  = (bf16*)(ws + 26019840);
    bf16* k_attn  = (bf16*)(ws + 32311296);
    bf16* v_attnT = (bf16*)(ws + 38602752);
    bf16* attn_o  = (bf16*)(ws + 42797056);

    const bf16* xb  = AR + OFF_X;
    const bf16* W_o = AR + OFF_WO;
    const bf16* qg  = AR + OFF_QG;
    const bf16* qb_ = AR + OFF_QB;
    const bf16* kg  = AR + OFF_KG;
    const bf16* kb  = AR + OFF_KB;

    bf16*  out_b = (bf16*)d_out;
    float* out_f = (float*)d_out;
    bf16*  ckv_b = out_b + (size_t)MROWS * DM;
    float* ckv_f = out_f + (size_t)MROWS * DM;

    dim3 blk(256);
    // 1) prep: flag + convert + weight transposes
    prep<<<dim3((PREP_TOT + 255) / 256), blk, 0, stream>>>(
        d_in[0], d_in[1], d_in[2], d_in[3], d_in[4], d_in[5],
        d_in[6], d_in[7], d_in[8], d_in[9], d_in[10], d_in[11],
        (u16*)AR, (u16*)WT, flagp);
    // 2) fused x-proj [dq|dkv|kr] N=704 (n0==640 block does kr-rope -> k_attn)
    gemm128<<<dim3(11, 32), blk, 0, stream>>>(xb, DM, WT + T_DQ, DM, 704, DM, 0, y, 704, k_attn, nullptr, nullptr, nullptr);
    // 3) merged layernorms
    ln_both<<<dim3(2048), blk, 0, stream>>>(y, qg, qb_, kg, kb, cq, ckv_b, ckv_f, ckvp, flagp);
    // 4) fused cq up-proj [uq|qr] N=576, scaled Q (n0==512 block does q-rope)
    gemm128<<<dim3(9, 32), blk, 0, stream>>>(cq, QP, WT + T_UQ, QP, 576, QP, 4, q_attn, 0, nullptr, nullptr, nullptr, nullptr);
    // 5) kv up-proj (K scatter + V^T via LDS transpose), N=1024, K=384
    gemm128<<<dim3(16, 32), blk, 0, stream>>>(ckvp, 384, WT + T_UKV, 384, 1024, 384, 3, nullptr, 0, k_attn, v_attnT, nullptr, nullptr);
    // 6) attention (split-KV, qb-paired, swapped-softmax, defer-max)
    attn_split3<<<dim3(4, 16, 16), blk, 0, stream>>>(q_attn, k_attn, v_attnT, po, ml_m, ml_l);
    // 7) combine
    attn_combine<<<dim3(1024), blk, 0, stream>>>(po, ml_m, ml_l, attn_o);
    // 8) output projection -> d_out (dual dtype)
    gemm128<<<dim3(8, 32), blk, 0, stream>>>(attn_o, DM, W_o, DM, DM, DM, 1, out_b, DM, nullptr, nullptr, flagp, out_f);
}

// Round 11
// 126.302 us; speedup vs baseline: 3.1611x; 1.0124x over previous
//
#include <hip/hip_runtime.h>
#include <hip/hip_bf16.h>

#define BATCH 2
#define SEQ 2048
#define DM 512
#define NH 8
#define DHD 64
#define QP 256
#define KVP 341
#define DQKPAD 96
#define MROWS 4096   // BATCH*SEQ

// bf16 arena element offsets (x, W_o, LN params only)
#define OFF_X     0
#define OFF_WO    2932224
#define OFF_QG    3194368
#define OFF_QB    3194624
#define OFF_KG    3194880
#define OFF_KB    3195221

// transposed-weight arena element offsets ([N][K])
#define T_DQ   0        // [256][512]
#define T_DKV  131072   // [384][512] (n>=341 zero)
#define T_KR   327680   // [64][512]
#define T_UQ   360448   // [512][256]
#define T_QR   491520   // [64][256]
#define T_UKV  507904   // [1024][384] (k>=341 zero)
#define T_TOT  901120

#define NW_X   2097152
#define NW_WO  262144
#define NW_PAR 1194

// prep work groups (8 elems each)
#define G_X   262144
#define G_WO  32768
#define G_PAR 150
#define G_WT  112640
#define G_TOT (G_X + G_WO + G_PAR + G_WT)

#define NSPLIT 8

typedef __bf16 bf16x8 __attribute__((ext_vector_type(8)));
typedef float f32x4 __attribute__((ext_vector_type(4)));
typedef __hip_bfloat16 bf16;
typedef unsigned short u16;

static __device__ __forceinline__ bf16x8 ld_bf8(const bf16* p) {
    return __builtin_bit_cast(bf16x8, *(const uint4*)p);
}

// async global->LDS, 16B per lane; LDS dest = wave-uniform base + lane*16
#define GL16(gp, lp) __builtin_amdgcn_global_load_lds( \
    (const __attribute__((address_space(1))) void*)(gp), \
    (__attribute__((address_space(3))) void*)(lp), 16, 0, 0)

// ---------- prep: dtype-flag + convert x/W_o/params + weight transposes (8-wide) ----------
__global__ __launch_bounds__(256) void prep(
    const void* px, const void* pwdq, const void* pwuq, const void* pwqr,
    const void* pwdkv, const void* pwukv, const void* pwkr, const void* pwo,
    const void* pqg, const void* pqb, const void* pkg, const void* pkb,
    u16* __restrict__ arena, u16* __restrict__ WT, int* __restrict__ flagp)
{
    __shared__ int cnt;
    if (threadIdx.x == 0) cnt = 0;
    __syncthreads();
    int bad = 0;
    const u16* xs = (const u16*)px;
    for (int i = threadIdx.x; i < 2048; i += 256) {
        u16 u = xs[i];
        int e = (u >> 7) & 0xFF;
        if (u != 0 && (e < 90 || e > 164)) bad++;
    }
    #pragma unroll
    for (int m2 = 1; m2 < 64; m2 <<= 1) bad += __shfl_xor(bad, m2);
    if ((threadIdx.x & 63) == 0) atomicAdd(&cnt, bad);
    __syncthreads();
    const int f = (cnt > 256) ? 1 : 0;   // 1 => inputs are fp32
    if (blockIdx.x == 0 && threadIdx.x == 0) *flagp = f;

    int gid = blockIdx.x * 256 + threadIdx.x;
    if (gid >= G_TOT) return;

    auto rdu = [&](const void* s, int i) -> u16 {
        if (f) return __builtin_bit_cast(u16, __float2bfloat16(((const float*)s)[i]));
        return ((const u16*)s)[i];
    };

    if (gid < G_X + G_WO) {
        const void* src = (gid < G_X) ? px : pwo;
        int base = (gid < G_X) ? OFF_X : OFF_WO;
        int i = (gid < G_X) ? gid : gid - G_X;
        u16 out[8];
        if (f) {
            const float* s = (const float*)src + i * 8;
            #pragma unroll
            for (int j = 0; j < 8; ++j) out[j] = __builtin_bit_cast(u16, __float2bfloat16(s[j]));
        } else {
            *(uint4*)out = ((const uint4*)src)[i];
        }
        *(uint4*)&arena[base + i * 8] = *(uint4*)out;
    } else if (gid < G_X + G_WO + G_PAR) {
        int i0 = (gid - G_X - G_WO) * 8;
        for (int j = 0; j < 8; ++j) {
            int i = i0 + j;
            if (i >= NW_PAR) break;
            if (i < 256)      arena[OFF_QG + i]         = rdu(pqg, i);
            else if (i < 512) arena[OFF_QB + (i - 256)] = rdu(pqb, i - 256);
            else if (i < 853) arena[OFF_KG + (i - 512)] = rdu(pkg, i - 512);
            else              arena[OFF_KB + (i - 853)] = rdu(pkb, i - 853);
        }
    } else {
        int loc = (gid - (G_X + G_WO + G_PAR)) * 8;   // 8 consecutive: same n, k0..k0+7
        const void* src; int n, k0, sN, klim, nok;
        if (loc < T_DKV)      { int l = loc;          n = l >> 9; k0 = l & 511; src = pwdq;  sN = 256;  klim = 512; nok = 1; }
        else if (loc < T_KR)  { int l = loc - T_DKV;  n = l >> 9; k0 = l & 511; src = pwdkv; sN = 341;  klim = 512; nok = (n < 341); }
        else if (loc < T_UQ)  { int l = loc - T_KR;   n = l >> 9; k0 = l & 511; src = pwkr;  sN = 64;   klim = 512; nok = 1; }
        else if (loc < T_QR)  { int l = loc - T_UQ;   n = l >> 8; k0 = l & 255; src = pwuq;  sN = 512;  klim = 256; nok = 1; }
        else if (loc < T_UKV) { int l = loc - T_QR;   n = l >> 8; k0 = l & 255; src = pwqr;  sN = 64;   klim = 256; nok = 1; }
        else                  { int l = loc - T_UKV;  n = l / 384; k0 = l % 384; src = pwukv; sN = 1024; klim = 341; nok = 1; }
        u16 out[8];
        #pragma unroll
        for (int j = 0; j < 8; ++j) {
            int k = k0 + j;
            out[j] = (nok && k < klim) ? rdu(src, k * sN + n) : (u16)0;
        }
        *(uint4*)&WT[loc] = *(uint4*)out;
    }
}

// ---------- rope epilogue: acc holds 64 rope cols for 128 rows; partner via shfl ----------
static __device__ __forceinline__ void rope_epi(
    f32x4 (&acc)[2][4], bf16* __restrict__ dst, int m0, int w, int g, int lr, int tid, bool scaleq)
{
    const float SCv = 0.11785113019775793f;   // 1/sqrt(72)
    #pragma unroll
    for (int mt = 0; mt < 2; ++mt)
    #pragma unroll
    for (int r = 0; r < 4; ++r) {
        int gm = m0 + w * 32 + mt * 16 + g * 4 + r;
        int s = gm & 2047, b = gm >> 11;
        float ang = (float)s * exp2f(-(float)(lr & 3) * 3.3219280948873623f);
        float sn, cs;
        sincosf(ang, &sn, &cs);
        #pragma unroll
        for (int nt = 0; nt < 4; ++nt) {
            float v = acc[mt][nt][r];
            float pt = __shfl_xor(v, 4);
            float o = (lr & 4) ? fmaf(pt, sn, v * cs) : fmaf(-pt, sn, v * cs);
            if (scaleq) o *= SCv;
            int h = (nt * 16 + lr) >> 3, j = lr & 7;
            dst[((size_t)(b * NH + h) * SEQ + s) * DQKPAD + 64 + j] = __float2bfloat16(o);
        }
    }
    // zero pads [72,96) for all 8 heads of these 128 rows
    for (int u = tid; u < 128 * 96; u += 256) {
        int rw = u / 96, rem = u - rw * 96;
        int h = rem / 12, c = rem - h * 12;
        int row = m0 + rw, b2 = row >> 11, s2 = row & 2047;
        *(unsigned int*)&dst[((size_t)(b2 * NH + h) * SEQ + s2) * DQKPAD + 72 + c * 2] = 0u;
    }
}

// ------- 128x64 bf16 MFMA GEMM, BK=64, global_load_lds staging + XOR swizzle -------
// modes: 0 fp32->C0 (n0==640: kr-rope -> kv_k); 1 dual->C0/C0f;
// 3 KV-scatter (K direct, V via LDS transpose); 4 Q-scatter scaled (n0==512: q-rope).
__global__ __launch_bounds__(256) void gemm128(
    const bf16* __restrict__ A, int lda,
    const bf16* __restrict__ BT, int ldb,
    int N, int Kpad, int mode,
    void* __restrict__ C0, int ldc,
    bf16* __restrict__ kv_k, bf16* __restrict__ kv_v,
    const int* __restrict__ flagp, float* __restrict__ C0f)
{
    __shared__ __align__(16) bf16 LB[128 * 64 + 64 * 64];   // Al 16KB | Bl 8KB
    bf16* Al = LB;
    bf16* Bl = LB + 128 * 64;
    const int tid = threadIdx.x;
    const int m0 = blockIdx.y * 128, n0 = blockIdx.x * 64;
    const int lane = tid & 63, w = tid >> 6;
    const int g = lane >> 4, lr = lane & 15;
    f32x4 acc[2][4] = {};
    const int r8 = lane >> 3;
    const int xr8 = ((lane & 7) ^ r8) * 8;     // pre-swizzled source column (elems)
    const int swx = (lr & 7) << 4;             // read-side XOR (bytes)

    for (int k0 = 0; k0 < Kpad; k0 += 64) {
        #pragma unroll
        for (int i = 0; i < 4; ++i)
            GL16(&A[(size_t)(m0 + w * 32 + i * 8 + r8) * lda + k0 + xr8],
                 (char*)Al + w * 4096 + i * 1024);
        #pragma unroll
        for (int i = 0; i < 2; ++i)
            GL16(&BT[(size_t)(n0 + w * 16 + i * 8 + r8) * ldb + k0 + xr8],
                 (char*)Bl + w * 2048 + i * 1024);
        __syncthreads();
        #pragma unroll
        for (int ks = 0; ks < 2; ++ks) {
            const int cs = (ks * 64 + g * 16) ^ swx;
            bf16x8 a0 = ld_bf8((const bf16*)((const char*)Al + (w * 32 + lr) * 128 + cs));
            bf16x8 a1 = ld_bf8((const bf16*)((const char*)Al + (w * 32 + 16 + lr) * 128 + cs));
            #pragma unroll
            for (int nt = 0; nt < 4; ++nt) {
                bf16x8 b = ld_bf8((const bf16*)((const char*)Bl + (nt * 16 + lr) * 128 + cs));
                acc[0][nt] = __builtin_amdgcn_mfma_f32_16x16x32_bf16(a0, b, acc[0][nt], 0, 0, 0);
                acc[1][nt] = __builtin_amdgcn_mfma_f32_16x16x32_bf16(a1, b, acc[1][nt], 0, 0, 0);
            }
        }
        __syncthreads();
    }

    if (mode == 0 && n0 == 640) {       // kr-rope block (unscaled) -> k_attn
        rope_epi(acc, kv_k, m0, w, g, lr, tid, false);
        return;
    }
    if (mode == 4 && n0 == DM) {        // qr-rope block (scaled) -> q_attn
        rope_epi(acc, (bf16*)C0, m0, w, g, lr, tid, true);
        return;
    }
    if (mode == 3 && n0 >= DM) {
        // V block: LDS transpose -> coalesced V^T rows
        const int h = (n0 - DM) >> 6;
        const int b = m0 >> 11, s0 = m0 & 2047;
        bf16* T = LB;   // [64][stride 136]
        #pragma unroll
        for (int mt = 0; mt < 2; ++mt)
        #pragma unroll
        for (int nt = 0; nt < 4; ++nt)
        #pragma unroll
        for (int r = 0; r < 4; ++r) {
            int dv = nt * 16 + lr;
            int sl = w * 32 + mt * 16 + g * 4 + r;
            T[dv * 136 + sl] = __float2bfloat16(acc[mt][nt][r]);
        }
        __syncthreads();
        const int row = tid >> 2, coff = (tid & 3) * 32;
        bf16* dst = &kv_v[((size_t)(b * NH + h) * DHD + row) * SEQ + s0 + coff];
        const bf16* srcp = &T[row * 136 + coff];
        #pragma unroll
        for (int q2 = 0; q2 < 4; ++q2)
            *(uint4*)(dst + q2 * 8) = *(const uint4*)(srcp + q2 * 8);
        return;
    }

    const float SCv = 0.11785113019775793f;
    const int f32o = (mode == 1 && flagp) ? *flagp : 0;
    #pragma unroll
    for (int mt = 0; mt < 2; ++mt)
    #pragma unroll
    for (int nt = 0; nt < 4; ++nt)
    #pragma unroll
    for (int r = 0; r < 4; ++r) {
        int gm = m0 + w * 32 + mt * 16 + g * 4 + r;
        int gn = n0 + nt * 16 + lr;
        float v = acc[mt][nt][r];
        if (mode == 0) {
            ((float*)C0)[(size_t)gm * ldc + gn] = v;
        } else if (mode == 1) {
            if (f32o) C0f[(size_t)gm * ldc + gn] = v;
            else ((bf16*)C0)[(size_t)gm * ldc + gn] = __float2bfloat16(v);
        } else if (mode == 4) {
            int b = gm >> 11, s = gm & 2047;
            int h = gn >> 6, dh = gn & 63;
            ((bf16*)C0)[((size_t)(b * NH + h) * SEQ + s) * DQKPAD + dh] = __float2bfloat16(v * SCv);
        } else { // mode 3 K block: direct scatter [bh][s][96]
            int b = gm >> 11, s = gm & 2047;
            int h = gn >> 6, dh = gn & 63;
            kv_k[((size_t)(b * NH + h) * SEQ + s) * DQKPAD + dh] = __float2bfloat16(v);
        }
    }
}

// ------- merged layernorms, one wave per row -------
__global__ __launch_bounds__(256) void ln_both(
    const float* __restrict__ y,
    const bf16* __restrict__ qg, const bf16* __restrict__ qb,
    const bf16* __restrict__ kg, const bf16* __restrict__ kb,
    bf16* __restrict__ cq, bf16* __restrict__ ckv_b, float* __restrict__ ckv_f,
    bf16* __restrict__ ckvp, const int* __restrict__ flagp)
{
    const int w = threadIdx.x >> 6, lane = threadIdx.x & 63;
    const int blk = blockIdx.x;
    if (blk < 1024) {
        const int row = blk * 4 + w;
        const float* yr = y + (size_t)row * 704;
        float s = 0.f, ss = 0.f;
        for (int i = lane; i < 256; i += 64) { float v = yr[i]; s += v; ss += v * v; }
        #pragma unroll
        for (int m = 1; m < 64; m <<= 1) { s += __shfl_xor(s, m); ss += __shfl_xor(ss, m); }
        float mean = s * (1.f / 256.f);
        float var = ss * (1.f / 256.f) - mean * mean;
        float rstd = rsqrtf(var + 1e-5f);
        for (int i = lane; i < 256; i += 64) {
            float v = (yr[i] - mean) * rstd * __bfloat162float(qg[i]) + __bfloat162float(qb[i]);
            cq[(size_t)row * 256 + i] = __float2bfloat16(v);
        }
    } else {
        const int row = (blk - 1024) * 4 + w;
        const float* yr = y + (size_t)row * 704 + 256;
        const int f32o = *flagp;
        float s = 0.f, ss = 0.f;
        for (int i = lane; i < KVP; i += 64) { float v = yr[i]; s += v; ss += v * v; }
        #pragma unroll
        for (int m = 1; m < 64; m <<= 1) { s += __shfl_xor(s, m); ss += __shfl_xor(ss, m); }
        float mean = s * (1.f / 341.f);
        float var = ss * (1.f / 341.f) - mean * mean;
        float rstd = rsqrtf(var + 1e-5f);
        for (int i = lane; i < KVP; i += 64) {
            float v = (yr[i] - mean) * rstd * __bfloat162float(kg[i]) + __bfloat162float(kb[i]);
            if (f32o) ckv_f[(size_t)row * KVP + i] = v;
            else ckv_b[(size_t)row * KVP + i] = __float2bfloat16(v);
            ckvp[(size_t)row * 384 + i] = __float2bfloat16(v);
        }
        for (int i = KVP + lane; i < 384; i += 64) ckvp[(size_t)row * 384 + i] = __float2bfloat16(0.f);
    }
}

// ---- causal flash attention: 8-way split-KV + qb-pairing + swapped QK^T + defer-max ----
__global__ __launch_bounds__(256) void attn_split3(
    const bf16* __restrict__ qa, const bf16* __restrict__ ka, const bf16* __restrict__ vat,
    bf16* __restrict__ po, float* __restrict__ mlm, float* __restrict__ mll)
{
    __shared__ __align__(16) bf16 Kl[64][104];
    __shared__ __align__(16) bf16 Vt[64][72];
    __shared__ __align__(16) bf16 Pl[4][16][72];
    const int sp = blockIdx.x, pr = blockIdx.y, bh = blockIdx.z;
    const int tid = threadIdx.x, w = tid >> 6, lane = tid & 63;
    const int g = lane >> 4, lr = lane & 15;
    const size_t base = (size_t)bh * SEQ;
    const float L2E = 1.4426950408889634f;
    const bf16* vb = vat + (size_t)bh * DHD * SEQ;

    for (int half = 0; half < 2; ++half) {
        const int qb = half ? (31 - pr) : pr;
        const int qrow0 = qb * 64 + w * 16;
        const int myq = qrow0 + lr;

        bf16x8 qf[3];
        #pragma unroll
        for (int kc = 0; kc < 3; ++kc)
            qf[kc] = ld_bf8(&qa[(base + myq) * DQKPAD + kc * 32 + g * 8]);

        float m_p = -1e30f, l_p = 0.f;
        f32x4 acc_o[4] = {};
        const int ng = qb + 1;
        const int bs = (ng * sp) >> 3, be = (ng * (sp + 1)) >> 3;

        for (int gi = bs; gi < be; ++gi) {
            const int j0 = gi * 64;
            __syncthreads();
            for (int u = tid; u < 768; u += 256) {
                int row = u / 12, cc = (u % 12) * 8;
                *(uint4*)&Kl[row][cc] = *(const uint4*)&ka[(base + j0 + row) * DQKPAD + cc];
            }
            {
                int d = tid >> 2, ko = (tid & 3) * 16;
                const bf16* vsrc = &vb[(size_t)d * SEQ + j0 + ko];
                *(uint4*)&Vt[d][ko]     = *(const uint4*)vsrc;
                *(uint4*)&Vt[d][ko + 8] = *(const uint4*)(vsrc + 8);
            }
            __syncthreads();

            f32x4 accs[4] = {};
            #pragma unroll
            for (int kc = 0; kc < 3; ++kc) {
                #pragma unroll
                for (int nt = 0; nt < 4; ++nt) {
                    bf16x8 kf = ld_bf8(&Kl[nt * 16 + lr][kc * 32 + g * 8]);
                    accs[nt] = __builtin_amdgcn_mfma_f32_16x16x32_bf16(kf, qf[kc], accs[nt], 0, 0, 0);
                }
            }
            float s_[4][4];
            float mloc = -1e30f;
            if (j0 + 63 > qrow0) {          // diagonal granule: apply causal mask
                #pragma unroll
                for (int nt = 0; nt < 4; ++nt)
                #pragma unroll
                for (int r = 0; r < 4; ++r) {
                    int key = j0 + nt * 16 + g * 4 + r;
                    float sv = accs[nt][r];
                    sv = (key <= myq) ? sv : -1e30f;
                    s_[nt][r] = sv;
                    mloc = fmaxf(mloc, sv);
                }
            } else {                         // fully unmasked
                #pragma unroll
                for (int nt = 0; nt < 4; ++nt)
                #pragma unroll
                for (int r = 0; r < 4; ++r) {
                    float sv = accs[nt][r];
                    s_[nt][r] = sv;
                    mloc = fmaxf(mloc, sv);
                }
            }
            mloc = fmaxf(mloc, __shfl_xor(mloc, 16));
            mloc = fmaxf(mloc, __shfl_xor(mloc, 32));

            if (__all(mloc <= m_p + 8.f)) {  // defer-max: no rescale
                float rs = 0.f;
                #pragma unroll
                for (int nt = 0; nt < 4; ++nt)
                #pragma unroll
                for (int r = 0; r < 4; ++r) {
                    float p = exp2f((s_[nt][r] - m_p) * L2E);
                    s_[nt][r] = p; rs += p;
                }
                rs += __shfl_xor(rs, 16);
                rs += __shfl_xor(rs, 32);
                l_p += rs;
            } else {
                float mn = fmaxf(m_p, mloc);
                float alpha = exp2f((m_p - mn) * L2E);
                m_p = mn;
                float rs = 0.f;
                #pragma unroll
                for (int nt = 0; nt < 4; ++nt)
                #pragma unroll
                for (int r = 0; r < 4; ++r) {
                    float p = exp2f((s_[nt][r] - mn) * L2E);
                    s_[nt][r] = p; rs += p;
                }
                rs += __shfl_xor(rs, 16);
                rs += __shfl_xor(rs, 32);
                l_p = l_p * alpha + rs;
                float ar[4];
                #pragma unroll
                for (int r = 0; r < 4; ++r) ar[r] = __shfl(alpha, g * 4 + r);
                #pragma unroll
                for (int nv = 0; nv < 4; ++nv)
                #pragma unroll
                for (int r = 0; r < 4; ++r) acc_o[nv][r] *= ar[r];
            }
            #pragma unroll
            for (int nt = 0; nt < 4; ++nt) {
                ushort4 pk;
                pk.x = __builtin_bit_cast(u16, __float2bfloat16(s_[nt][0]));
                pk.y = __builtin_bit_cast(u16, __float2bfloat16(s_[nt][1]));
                pk.z = __builtin_bit_cast(u16, __float2bfloat16(s_[nt][2]));
                pk.w = __builtin_bit_cast(u16, __float2bfloat16(s_[nt][3]));
                *(ushort4*)&Pl[w][lr][nt * 16 + g * 4] = pk;
            }
            bf16x8 pf0 = ld_bf8(&Pl[w][lr][g * 8]);
            bf16x8 pf1 = ld_bf8(&Pl[w][lr][32 + g * 8]);
            #pragma unroll
            for (int nv = 0; nv < 4; ++nv) {
                bf16x8 vf0 = ld_bf8(&Vt[nv * 16 + lr][g * 8]);
                acc_o[nv] = __builtin_amdgcn_mfma_f32_16x16x32_bf16(pf0, vf0, acc_o[nv], 0, 0, 0);
                bf16x8 vf1 = ld_bf8(&Vt[nv * 16 + lr][32 + g * 8]);
                acc_o[nv] = __builtin_amdgcn_mfma_f32_16x16x32_bf16(pf1, vf1, acc_o[nv], 0, 0, 0);
            }
        }

        const size_t pb = (size_t)(bh * NSPLIT + sp) * SEQ;
        #pragma unroll
        for (int r = 0; r < 4; ++r) {
            int qrow = qrow0 + g * 4 + r;
            #pragma unroll
            for (int nv = 0; nv < 4; ++nv)
                po[(pb + qrow) * DHD + nv * 16 + lr] = __float2bfloat16(acc_o[nv][r]);
        }
        if (lane < 16) {
            mlm[pb + qrow0 + lane] = m_p;
            mll[pb + qrow0 + lane] = l_p;
        }
    }
}

// ---------------- combine split partials -> attn_o [b][s][h*64+d] ----------------
__global__ __launch_bounds__(256) void attn_combine(
    const bf16* __restrict__ po, const float* __restrict__ mlm, const float* __restrict__ mll,
    bf16* __restrict__ ao)
{
    int id = blockIdx.x * 256 + threadIdx.x;   // 16*2048*8 = 262144
    int bh = id >> 14;
    int rem = id & 16383;
    int q = rem >> 3, dc = (rem & 7) * 8;
    const float L2E = 1.4426950408889634f;
    size_t mlb = (size_t)bh * NSPLIT * SEQ + q;
    float ms[NSPLIT], ls[NSPLIT];
    #pragma unroll
    for (int s = 0; s < NSPLIT; ++s) { ms[s] = mlm[mlb + (size_t)s * SEQ]; ls[s] = mll[mlb + (size_t)s * SEQ]; }
    float M = -1e30f;
    #pragma unroll
    for (int s = 0; s < NSPLIT; ++s) M = fmaxf(M, ms[s]);
    float wsc[NSPLIT]; float L = 0.f;
    #pragma unroll
    for (int s = 0; s < NSPLIT; ++s) { wsc[s] = exp2f((ms[s] - M) * L2E); L += wsc[s] * ls[s]; }
    float o[8] = {};
    #pragma unroll
    for (int s = 0; s < NSPLIT; ++s) {
        if (ls[s] <= 0.f) continue;
        bf16x8 pv = ld_bf8(&po[((size_t)(bh * NSPLIT + s) * SEQ + q) * DHD + dc]);
        #pragma unroll
        for (int j = 0; j < 8; ++j) o[j] += wsc[s] * (float)pv[j];
    }
    float invL = 1.f / L;
    int b = bh >> 3, h = bh & 7;
    __bf16 tmp[8];
    #pragma unroll
    for (int j = 0; j < 8; ++j) tmp[j] = (__bf16)(o[j] * invL);
    *(uint4*)&ao[((size_t)(b * SEQ) + q) * DM + h * DHD + dc] = *(uint4*)tmp;
}

extern "C" void kernel_launch(void* const* d_in, const int* in_sizes, int n_in,
                              void* d_out, int out_size, void* d_ws, size_t ws_size,
                              hipStream_t stream) {
    char* ws = (char*)d_ws;
    bf16* AR      = (bf16*)(ws + 0);              // arena: x | W_o | params
    float* ml_m   = (float*)(ws + 0);             // alias x region (dead after x-gemm), 1MB
    float* ml_l   = (float*)(ws + 1048576);       // 1MB
    bf16* WT      = (bf16*)(ws + 6391296);        // transposed weights (1,802,240 B)
    int*  flagp   = (int*)(ws + 8193536);
    float* y      = (float*)(ws + 8194048);       // fused x-proj out [4096][704] fp32
    bf16* cq      = (bf16*)(ws + 19728384);       // [4096][256]
    bf16* ckvp    = (bf16*)(ws + 21825536);       // [4096][384]
    bf16* q_attn  = (bf16*)(ws + 26019840);
    bf16* k_attn  = (bf16*)(ws + 32311296);
    bf16* v_attnT = (bf16*)(ws + 38602752);
    bf16* attn_o  = (bf16*)(ws + 42797056);
    bf16* po      = (bf16*)(ws + 50331648);       // 8-split partials, 33,554,432 B

    const bf16* xb  = AR + OFF_X;
    const bf16* W_o = AR + OFF_WO;
    const bf16* qg  = AR + OFF_QG;
    const bf16* qb_ = AR + OFF_QB;
    const bf16* kg  = AR + OFF_KG;
    const bf16* kb  = AR + OFF_KB;

    bf16*  out_b = (bf16*)d_out;
    float* out_f = (float*)d_out;
    bf16*  ckv_b = out_b + (size_t)MROWS * DM;
    float* ckv_f = out_f + (size_t)MROWS * DM;

    dim3 blk(256);
    // 1) prep: flag + convert + weight transposes (8-wide)
    prep<<<dim3((G_TOT + 255) / 256), blk, 0, stream>>>(
        d_in[0], d_in[1], d_in[2], d_in[3], d_in[4], d_in[5],
        d_in[6], d_in[7], d_in[8], d_in[9], d_in[10], d_in[11],
        (u16*)AR, (u16*)WT, flagp);
    // 2) fused x-proj [dq|dkv|kr] N=704 (n0==640 block does kr-rope -> k_attn)
    gemm128<<<dim3(11, 32), blk, 0, stream>>>(xb, DM, WT + T_DQ, DM, 704, DM, 0, y, 704, k_attn, nullptr, nullptr, nullptr);
    // 3) merged layernorms
    ln_both<<<dim3(2048), blk, 0, stream>>>(y, qg, qb_, kg, kb, cq, ckv_b, ckv_f, ckvp, flagp);
    // 4) fused cq up-proj [uq|qr] N=576, scaled Q (n0==512 block does q-rope)
    gemm128<<<dim3(9, 32), blk, 0, stream>>>(cq, QP, WT + T_UQ, QP, 576, QP, 4, q_attn, 0, nullptr, nullptr, nullptr, nullptr);
    // 5) kv up-proj (K scatter + V^T via LDS transpose), N=1024, K=384
    gemm128<<<dim3(16, 32), blk, 0, stream>>>(ckvp, 384, WT + T_UKV, 384, 1024, 384, 3, nullptr, 0, k_attn, v_attnT, nullptr, nullptr);
    // 6) attention (8-way split-KV, qb-paired, swapped-softmax, defer-max)
    attn_split3<<<dim3(NSPLIT, 16, 16), blk, 0, stream>>>(q_attn, k_attn, v_attnT, po, ml_m, ml_l);
    // 7) combine
    attn_combine<<<dim3(1024), blk, 0, stream>>>(po, ml_m, ml_l, attn_o);
    // 8) output projection -> d_out (dual dtype)
    gemm128<<<dim3(8, 32), blk, 0, stream>>>(attn_o, DM, W_o, DM, DM, DM, 1, out_b, DM, nullptr, nullptr, flagp, out_f);
}

// Round 12
// 120.023 us; speedup vs baseline: 3.3264x; 1.0523x over previous
//
#include <hip/hip_runtime.h>
#include <hip/hip_bf16.h>

#define BATCH 2
#define SEQ 2048
#define DM 512
#define NH 8
#define DHD 64
#define QP 256
#define KVP 341
#define DQKPAD 96
#define MROWS 4096   // BATCH*SEQ

// bf16 arena element offsets (x, W_o, LN params only)
#define OFF_X     0
#define OFF_WO    2932224
#define OFF_QG    3194368
#define OFF_QB    3194624
#define OFF_KG    3194880
#define OFF_KB    3195221

// transposed-weight arena element offsets ([N][K])
#define T_DQ   0        // [256][512]
#define T_DKV  131072   // [384][512] (n>=341 zero)
#define T_KR   327680   // [64][512]
#define T_UQ   360448   // [512][256]
#define T_QR   491520   // [64][256]
#define T_UKV  507904   // [1024][384] (k>=341 zero)
#define T_TOT  901120

#define NW_X   2097152
#define NW_WO  262144
#define NW_PAR 1194

// prep work groups (8 elems each)
#define G_X   262144
#define G_WO  32768
#define G_PAR 150
#define G_WT  112640
#define G_TOT (G_X + G_WO + G_PAR + G_WT)

#define NSPLIT 4

typedef __bf16 bf16x8 __attribute__((ext_vector_type(8)));
typedef float f32x4 __attribute__((ext_vector_type(4)));
typedef __hip_bfloat16 bf16;
typedef unsigned short u16;

static __device__ __forceinline__ bf16x8 ld_bf8(const bf16* p) {
    return __builtin_bit_cast(bf16x8, *(const uint4*)p);
}

// async global->LDS, 16B per lane; LDS dest = wave-uniform base + lane*16
#define GL16(gp, lp) __builtin_amdgcn_global_load_lds( \
    (const __attribute__((address_space(1))) void*)(gp), \
    (__attribute__((address_space(3))) void*)(lp), 16, 0, 0)

// ---------- prep: dtype-flag + convert x/W_o/params + weight transposes (8-wide) ----------
__global__ __launch_bounds__(256) void prep(
    const void* px, const void* pwdq, const void* pwuq, const void* pwqr,
    const void* pwdkv, const void* pwukv, const void* pwkr, const void* pwo,
    const void* pqg, const void* pqb, const void* pkg, const void* pkb,
    u16* __restrict__ arena, u16* __restrict__ WT, int* __restrict__ flagp)
{
    __shared__ int cnt;
    if (threadIdx.x == 0) cnt = 0;
    __syncthreads();
    int bad = 0;
    const u16* xs = (const u16*)px;
    for (int i = threadIdx.x; i < 2048; i += 256) {
        u16 u = xs[i];
        int e = (u >> 7) & 0xFF;
        if (u != 0 && (e < 90 || e > 164)) bad++;
    }
    #pragma unroll
    for (int m2 = 1; m2 < 64; m2 <<= 1) bad += __shfl_xor(bad, m2);
    if ((threadIdx.x & 63) == 0) atomicAdd(&cnt, bad);
    __syncthreads();
    const int f = (cnt > 256) ? 1 : 0;   // 1 => inputs are fp32
    if (blockIdx.x == 0 && threadIdx.x == 0) *flagp = f;

    int gid = blockIdx.x * 256 + threadIdx.x;
    if (gid >= G_TOT) return;

    auto rdu = [&](const void* s, int i) -> u16 {
        if (f) return __builtin_bit_cast(u16, __float2bfloat16(((const float*)s)[i]));
        return ((const u16*)s)[i];
    };

    if (gid < G_X + G_WO) {
        const void* src = (gid < G_X) ? px : pwo;
        int base = (gid < G_X) ? OFF_X : OFF_WO;
        int i = (gid < G_X) ? gid : gid - G_X;
        u16 out[8];
        if (f) {
            const float* s = (const float*)src + i * 8;
            #pragma unroll
            for (int j = 0; j < 8; ++j) out[j] = __builtin_bit_cast(u16, __float2bfloat16(s[j]));
        } else {
            *(uint4*)out = ((const uint4*)src)[i];
        }
        *(uint4*)&arena[base + i * 8] = *(uint4*)out;
    } else if (gid < G_X + G_WO + G_PAR) {
        int i0 = (gid - G_X - G_WO) * 8;
        for (int j = 0; j < 8; ++j) {
            int i = i0 + j;
            if (i >= NW_PAR) break;
            if (i < 256)      arena[OFF_QG + i]         = rdu(pqg, i);
            else if (i < 512) arena[OFF_QB + (i - 256)] = rdu(pqb, i - 256);
            else if (i < 853) arena[OFF_KG + (i - 512)] = rdu(pkg, i - 512);
            else              arena[OFF_KB + (i - 853)] = rdu(pkb, i - 853);
        }
    } else {
        int loc = (gid - (G_X + G_WO + G_PAR)) * 8;   // 8 consecutive: same n, k0..k0+7
        const void* src; int n, k0, sN, klim, nok;
        if (loc < T_DKV)      { int l = loc;          n = l >> 9; k0 = l & 511; src = pwdq;  sN = 256;  klim = 512; nok = 1; }
        else if (loc < T_KR)  { int l = loc - T_DKV;  n = l >> 9; k0 = l & 511; src = pwdkv; sN = 341;  klim = 512; nok = (n < 341); }
        else if (loc < T_UQ)  { int l = loc - T_KR;   n = l >> 9; k0 = l & 511; src = pwkr;  sN = 64;   klim = 512; nok = 1; }
        else if (loc < T_QR)  { int l = loc - T_UQ;   n = l >> 8; k0 = l & 255; src = pwuq;  sN = 512;  klim = 256; nok = 1; }
        else if (loc < T_UKV) { int l = loc - T_QR;   n = l >> 8; k0 = l & 255; src = pwqr;  sN = 64;   klim = 256; nok = 1; }
        else                  { int l = loc - T_UKV;  n = l / 384; k0 = l % 384; src = pwukv; sN = 1024; klim = 341; nok = 1; }
        u16 out[8];
        #pragma unroll
        for (int j = 0; j < 8; ++j) {
            int k = k0 + j;
            out[j] = (nok && k < klim) ? rdu(src, k * sN + n) : (u16)0;
        }
        *(uint4*)&WT[loc] = *(uint4*)out;
    }
}

// ---------- rope epilogue: acc holds 64 rope cols for 128 rows; partner via shfl ----------
static __device__ __forceinline__ void rope_epi(
    f32x4 (&acc)[2][4], bf16* __restrict__ dst, int m0, int w, int g, int lr, int tid, bool scaleq)
{
    const float SCv = 0.11785113019775793f;   // 1/sqrt(72)
    #pragma unroll
    for (int mt = 0; mt < 2; ++mt)
    #pragma unroll
    for (int r = 0; r < 4; ++r) {
        int gm = m0 + w * 32 + mt * 16 + g * 4 + r;
        int s = gm & 2047, b = gm >> 11;
        float ang = (float)s * exp2f(-(float)(lr & 3) * 3.3219280948873623f);
        float sn, cs;
        sincosf(ang, &sn, &cs);
        #pragma unroll
        for (int nt = 0; nt < 4; ++nt) {
            float v = acc[mt][nt][r];
            float pt = __shfl_xor(v, 4);
            float o = (lr & 4) ? fmaf(pt, sn, v * cs) : fmaf(-pt, sn, v * cs);
            if (scaleq) o *= SCv;
            int h = (nt * 16 + lr) >> 3, j = lr & 7;
            dst[((size_t)(b * NH + h) * SEQ + s) * DQKPAD + 64 + j] = __float2bfloat16(o);
        }
    }
    // zero pads [72,96) for all 8 heads of these 128 rows
    for (int u = tid; u < 128 * 96; u += 256) {
        int rw = u / 96, rem = u - rw * 96;
        int h = rem / 12, c = rem - h * 12;
        int row = m0 + rw, b2 = row >> 11, s2 = row & 2047;
        *(unsigned int*)&dst[((size_t)(b2 * NH + h) * SEQ + s2) * DQKPAD + 72 + c * 2] = 0u;
    }
}

// ------- 128x64 bf16 MFMA GEMM, BK=64, global_load_lds staging + XOR swizzle -------
// modes: 0 fp32->C0 (n0==640: kr-rope -> kv_k); 1 dual->C0/C0f;
// 3 KV-scatter (K direct, V via LDS transpose); 4 Q-scatter scaled (n0==512: q-rope).
__global__ __launch_bounds__(256) void gemm128(
    const bf16* __restrict__ A, int lda,
    const bf16* __restrict__ BT, int ldb,
    int N, int Kpad, int mode,
    void* __restrict__ C0, int ldc,
    bf16* __restrict__ kv_k, bf16* __restrict__ kv_v,
    const int* __restrict__ flagp, float* __restrict__ C0f)
{
    __shared__ __align__(16) bf16 LB[128 * 64 + 64 * 64];   // Al 16KB | Bl 8KB
    bf16* Al = LB;
    bf16* Bl = LB + 128 * 64;
    const int tid = threadIdx.x;
    const int m0 = blockIdx.y * 128, n0 = blockIdx.x * 64;
    const int lane = tid & 63, w = tid >> 6;
    const int g = lane >> 4, lr = lane & 15;
    f32x4 acc[2][4] = {};
    const int r8 = lane >> 3;
    const int xr8 = ((lane & 7) ^ r8) * 8;     // pre-swizzled source column (elems)
    const int swx = (lr & 7) << 4;             // read-side XOR (bytes)

    for (int k0 = 0; k0 < Kpad; k0 += 64) {
        #pragma unroll
        for (int i = 0; i < 4; ++i)
            GL16(&A[(size_t)(m0 + w * 32 + i * 8 + r8) * lda + k0 + xr8],
                 (char*)Al + w * 4096 + i * 1024);
        #pragma unroll
        for (int i = 0; i < 2; ++i)
            GL16(&BT[(size_t)(n0 + w * 16 + i * 8 + r8) * ldb + k0 + xr8],
                 (char*)Bl + w * 2048 + i * 1024);
        __syncthreads();
        #pragma unroll
        for (int ks = 0; ks < 2; ++ks) {
            const int cs = (ks * 64 + g * 16) ^ swx;
            bf16x8 a0 = ld_bf8((const bf16*)((const char*)Al + (w * 32 + lr) * 128 + cs));
            bf16x8 a1 = ld_bf8((const bf16*)((const char*)Al + (w * 32 + 16 + lr) * 128 + cs));
            #pragma unroll
            for (int nt = 0; nt < 4; ++nt) {
                bf16x8 b = ld_bf8((const bf16*)((const char*)Bl + (nt * 16 + lr) * 128 + cs));
                acc[0][nt] = __builtin_amdgcn_mfma_f32_16x16x32_bf16(a0, b, acc[0][nt], 0, 0, 0);
                acc[1][nt] = __builtin_amdgcn_mfma_f32_16x16x32_bf16(a1, b, acc[1][nt], 0, 0, 0);
            }
        }
        __syncthreads();
    }

    if (mode == 0 && n0 == 640) {       // kr-rope block (unscaled) -> k_attn
        rope_epi(acc, kv_k, m0, w, g, lr, tid, false);
        return;
    }
    if (mode == 4 && n0 == DM) {        // qr-rope block (scaled) -> q_attn
        rope_epi(acc, (bf16*)C0, m0, w, g, lr, tid, true);
        return;
    }
    if (mode == 3 && n0 >= DM) {
        // V block: LDS transpose -> coalesced V^T rows
        const int h = (n0 - DM) >> 6;
        const int b = m0 >> 11, s0 = m0 & 2047;
        bf16* T = LB;   // [64][stride 136]
        #pragma unroll
        for (int mt = 0; mt < 2; ++mt)
        #pragma unroll
        for (int nt = 0; nt < 4; ++nt)
        #pragma unroll
        for (int r = 0; r < 4; ++r) {
            int dv = nt * 16 + lr;
            int sl = w * 32 + mt * 16 + g * 4 + r;
            T[dv * 136 + sl] = __float2bfloat16(acc[mt][nt][r]);
        }
        __syncthreads();
        const int row = tid >> 2, coff = (tid & 3) * 32;
        bf16* dst = &kv_v[((size_t)(b * NH + h) * DHD + row) * SEQ + s0 + coff];
        const bf16* srcp = &T[row * 136 + coff];
        #pragma unroll
        for (int q2 = 0; q2 < 4; ++q2)
            *(uint4*)(dst + q2 * 8) = *(const uint4*)(srcp + q2 * 8);
        return;
    }

    const float SCv = 0.11785113019775793f;
    const int f32o = (mode == 1 && flagp) ? *flagp : 0;
    #pragma unroll
    for (int mt = 0; mt < 2; ++mt)
    #pragma unroll
    for (int nt = 0; nt < 4; ++nt)
    #pragma unroll
    for (int r = 0; r < 4; ++r) {
        int gm = m0 + w * 32 + mt * 16 + g * 4 + r;
        int gn = n0 + nt * 16 + lr;
        float v = acc[mt][nt][r];
        if (mode == 0) {
            ((float*)C0)[(size_t)gm * ldc + gn] = v;
        } else if (mode == 1) {
            if (f32o) C0f[(size_t)gm * ldc + gn] = v;
            else ((bf16*)C0)[(size_t)gm * ldc + gn] = __float2bfloat16(v);
        } else if (mode == 4) {
            int b = gm >> 11, s = gm & 2047;
            int h = gn >> 6, dh = gn & 63;
            ((bf16*)C0)[((size_t)(b * NH + h) * SEQ + s) * DQKPAD + dh] = __float2bfloat16(v * SCv);
        } else { // mode 3 K block: direct scatter [bh][s][96]
            int b = gm >> 11, s = gm & 2047;
            int h = gn >> 6, dh = gn & 63;
            kv_k[((size_t)(b * NH + h) * SEQ + s) * DQKPAD + dh] = __float2bfloat16(v);
        }
    }
}

// ------- merged layernorms, one wave per row -------
__global__ __launch_bounds__(256) void ln_both(
    const float* __restrict__ y,
    const bf16* __restrict__ qg, const bf16* __restrict__ qb,
    const bf16* __restrict__ kg, const bf16* __restrict__ kb,
    bf16* __restrict__ cq, bf16* __restrict__ ckv_b, float* __restrict__ ckv_f,
    bf16* __restrict__ ckvp, const int* __restrict__ flagp)
{
    const int w = threadIdx.x >> 6, lane = threadIdx.x & 63;
    const int blk = blockIdx.x;
    if (blk < 1024) {
        const int row = blk * 4 + w;
        const float* yr = y + (size_t)row * 704;
        float s = 0.f, ss = 0.f;
        for (int i = lane; i < 256; i += 64) { float v = yr[i]; s += v; ss += v * v; }
        #pragma unroll
        for (int m = 1; m < 64; m <<= 1) { s += __shfl_xor(s, m); ss += __shfl_xor(ss, m); }
        float mean = s * (1.f / 256.f);
        float var = ss * (1.f / 256.f) - mean * mean;
        float rstd = rsqrtf(var + 1e-5f);
        for (int i = lane; i < 256; i += 64) {
            float v = (yr[i] - mean) * rstd * __bfloat162float(qg[i]) + __bfloat162float(qb[i]);
            cq[(size_t)row * 256 + i] = __float2bfloat16(v);
        }
    } else {
        const int row = (blk - 1024) * 4 + w;
        const float* yr = y + (size_t)row * 704 + 256;
        const int f32o = *flagp;
        float s = 0.f, ss = 0.f;
        for (int i = lane; i < KVP; i += 64) { float v = yr[i]; s += v; ss += v * v; }
        #pragma unroll
        for (int m = 1; m < 64; m <<= 1) { s += __shfl_xor(s, m); ss += __shfl_xor(ss, m); }
        float mean = s * (1.f / 341.f);
        float var = ss * (1.f / 341.f) - mean * mean;
        float rstd = rsqrtf(var + 1e-5f);
        for (int i = lane; i < KVP; i += 64) {
            float v = (yr[i] - mean) * rstd * __bfloat162float(kg[i]) + __bfloat162float(kb[i]);
            if (f32o) ckv_f[(size_t)row * KVP + i] = v;
            else ckv_b[(size_t)row * KVP + i] = __float2bfloat16(v);
            ckvp[(size_t)row * 384 + i] = __float2bfloat16(v);
        }
        for (int i = KVP + lane; i < 384; i += 64) ckvp[(size_t)row * 384 + i] = __float2bfloat16(0.f);
    }
}

// ---- causal flash attention: 4-way split-KV + qb-pairing + swapped QK^T
//      + defer-max + T14 async-STAGE (issue-early regs / write-late LDS) ----
__global__ __launch_bounds__(256) void attn_split3(
    const bf16* __restrict__ qa, const bf16* __restrict__ ka, const bf16* __restrict__ vat,
    bf16* __restrict__ po, float* __restrict__ mlm, float* __restrict__ mll)
{
    __shared__ __align__(16) bf16 Kl[64][104];
    __shared__ __align__(16) bf16 Vt[64][72];
    __shared__ __align__(16) bf16 Pl[4][16][72];
    const int sp = blockIdx.x, pr = blockIdx.y, bh = blockIdx.z;
    const int tid = threadIdx.x, w = tid >> 6, lane = tid & 63;
    const int g = lane >> 4, lr = lane & 15;
    const size_t base = (size_t)bh * SEQ;
    const float L2E = 1.4426950408889634f;
    const bf16* vb = vat + (size_t)bh * DHD * SEQ;

    // staging register slots (T14: issue loads early, write LDS late)
    uint4 kreg0, kreg1, kreg2, vreg0, vreg1;
    const int krow0 = tid / 12 >= 64 ? 63 : 0; (void)krow0;
    const int vd = tid >> 2, vko = (tid & 3) * 16;

    #define ISSUE_KV(j0)  do { \
        { int u0 = tid;       int row = u0 / 12, cc = (u0 % 12) * 8; kreg0 = *(const uint4*)&ka[(base + (j0) + row) * DQKPAD + cc]; } \
        { int u1 = tid + 256; int row = u1 / 12, cc = (u1 % 12) * 8; kreg1 = *(const uint4*)&ka[(base + (j0) + row) * DQKPAD + cc]; } \
        { int u2 = tid + 512; int row = u2 / 12, cc = (u2 % 12) * 8; kreg2 = *(const uint4*)&ka[(base + (j0) + row) * DQKPAD + cc]; } \
        const bf16* vsrc = &vb[(size_t)vd * SEQ + (j0) + vko]; \
        vreg0 = *(const uint4*)vsrc; vreg1 = *(const uint4*)(vsrc + 8); \
    } while (0)

    for (int half = 0; half < 2; ++half) {
        const int qb = half ? (31 - pr) : pr;
        const int qrow0 = qb * 64 + w * 16;
        const int myq = qrow0 + lr;

        bf16x8 qf[3];
        #pragma unroll
        for (int kc = 0; kc < 3; ++kc)
            qf[kc] = ld_bf8(&qa[(base + myq) * DQKPAD + kc * 32 + g * 8]);

        float m_p = -1e30f, l_p = 0.f;
        f32x4 acc_o[4] = {};
        const int ng = qb + 1;
        const int bs = (ng * sp) >> 2, be = (ng * (sp + 1)) >> 2;

        if (bs < be) ISSUE_KV(bs * 64);   // prologue: first granule's loads in flight

        for (int gi = bs; gi < be; ++gi) {
            const int j0 = gi * 64;
            __syncthreads();   // prior readers of Kl/Vt done (prev granule / prev half)
            // write-late: staged regs -> LDS
            { int u0 = tid;       int row = u0 / 12, cc = (u0 % 12) * 8; *(uint4*)&Kl[row][cc] = kreg0; }
            { int u1 = tid + 256; int row = u1 / 12, cc = (u1 % 12) * 8; *(uint4*)&Kl[row][cc] = kreg1; }
            { int u2 = tid + 512; int row = u2 / 12, cc = (u2 % 12) * 8; *(uint4*)&Kl[row][cc] = kreg2; }
            *(uint4*)&Vt[vd][vko]     = vreg0;
            *(uint4*)&Vt[vd][vko + 8] = vreg1;
            __syncthreads();
            // issue-early: next granule's loads hide under this granule's compute
            if (gi + 1 < be) ISSUE_KV(j0 + 64);

            f32x4 accs[4] = {};
            #pragma unroll
            for (int kc = 0; kc < 3; ++kc) {
                #pragma unroll
                for (int nt = 0; nt < 4; ++nt) {
                    bf16x8 kf = ld_bf8(&Kl[nt * 16 + lr][kc * 32 + g * 8]);
                    accs[nt] = __builtin_amdgcn_mfma_f32_16x16x32_bf16(kf, qf[kc], accs[nt], 0, 0, 0);
                }
            }
            float s_[4][4];
            float mloc = -1e30f;
            if (j0 + 63 > qrow0) {          // diagonal granule: apply causal mask
                #pragma unroll
                for (int nt = 0; nt < 4; ++nt)
                #pragma unroll
                for (int r = 0; r < 4; ++r) {
                    int key = j0 + nt * 16 + g * 4 + r;
                    float sv = accs[nt][r];
                    sv = (key <= myq) ? sv : -1e30f;
                    s_[nt][r] = sv;
                    mloc = fmaxf(mloc, sv);
                }
            } else {                         // fully unmasked
                #pragma unroll
                for (int nt = 0; nt < 4; ++nt)
                #pragma unroll
                for (int r = 0; r < 4; ++r) {
                    float sv = accs[nt][r];
                    s_[nt][r] = sv;
                    mloc = fmaxf(mloc, sv);
                }
            }
            mloc = fmaxf(mloc, __shfl_xor(mloc, 16));
            mloc = fmaxf(mloc, __shfl_xor(mloc, 32));

            if (__all(mloc <= m_p + 8.f)) {  // defer-max: no rescale
                float rs = 0.f;
                #pragma unroll
                for (int nt = 0; nt < 4; ++nt)
                #pragma unroll
                for (int r = 0; r < 4; ++r) {
                    float p = exp2f((s_[nt][r] - m_p) * L2E);
                    s_[nt][r] = p; rs += p;
                }
                rs += __shfl_xor(rs, 16);
                rs += __shfl_xor(rs, 32);
                l_p += rs;
            } else {
                float mn = fmaxf(m_p, mloc);
                float alpha = exp2f((m_p - mn) * L2E);
                m_p = mn;
                float rs = 0.f;
                #pragma unroll
                for (int nt = 0; nt < 4; ++nt)
                #pragma unroll
                for (int r = 0; r < 4; ++r) {
                    float p = exp2f((s_[nt][r] - mn) * L2E);
                    s_[nt][r] = p; rs += p;
                }
                rs += __shfl_xor(rs, 16);
                rs += __shfl_xor(rs, 32);
                l_p = l_p * alpha + rs;
                float ar[4];
                #pragma unroll
                for (int r = 0; r < 4; ++r) ar[r] = __shfl(alpha, g * 4 + r);
                #pragma unroll
                for (int nv = 0; nv < 4; ++nv)
                #pragma unroll
                for (int r = 0; r < 4; ++r) acc_o[nv][r] *= ar[r];
            }
            #pragma unroll
            for (int nt = 0; nt < 4; ++nt) {
                ushort4 pk;
                pk.x = __builtin_bit_cast(u16, __float2bfloat16(s_[nt][0]));
                pk.y = __builtin_bit_cast(u16, __float2bfloat16(s_[nt][1]));
                pk.z = __builtin_bit_cast(u16, __float2bfloat16(s_[nt][2]));
                pk.w = __builtin_bit_cast(u16, __float2bfloat16(s_[nt][3]));
                *(ushort4*)&Pl[w][lr][nt * 16 + g * 4] = pk;
            }
            bf16x8 pf0 = ld_bf8(&Pl[w][lr][g * 8]);
            bf16x8 pf1 = ld_bf8(&Pl[w][lr][32 + g * 8]);
            #pragma unroll
            for (int nv = 0; nv < 4; ++nv) {
                bf16x8 vf0 = ld_bf8(&Vt[nv * 16 + lr][g * 8]);
                acc_o[nv] = __builtin_amdgcn_mfma_f32_16x16x32_bf16(pf0, vf0, acc_o[nv], 0, 0, 0);
                bf16x8 vf1 = ld_bf8(&Vt[nv * 16 + lr][32 + g * 8]);
                acc_o[nv] = __builtin_amdgcn_mfma_f32_16x16x32_bf16(pf1, vf1, acc_o[nv], 0, 0, 0);
            }
        }

        const size_t pb = (size_t)(bh * NSPLIT + sp) * SEQ;
        #pragma unroll
        for (int r = 0; r < 4; ++r) {
            int qrow = qrow0 + g * 4 + r;
            #pragma unroll
            for (int nv = 0; nv < 4; ++nv)
                po[(pb + qrow) * DHD + nv * 16 + lr] = __float2bfloat16(acc_o[nv][r]);
        }
        if (lane < 16) {
            mlm[pb + qrow0 + lane] = m_p;
            mll[pb + qrow0 + lane] = l_p;
        }
    }
    #undef ISSUE_KV
}

// ---------------- combine split partials -> attn_o [b][s][h*64+d] ----------------
__global__ __launch_bounds__(256) void attn_combine(
    const bf16* __restrict__ po, const float* __restrict__ mlm, const float* __restrict__ mll,
    bf16* __restrict__ ao)
{
    int id = blockIdx.x * 256 + threadIdx.x;   // 16*2048*8 = 262144
    int bh = id >> 14;
    int rem = id & 16383;
    int q = rem >> 3, dc = (rem & 7) * 8;
    const float L2E = 1.4426950408889634f;
    size_t mlb = (size_t)bh * NSPLIT * SEQ + q;
    float ms[NSPLIT], ls[NSPLIT];
    #pragma unroll
    for (int s = 0; s < NSPLIT; ++s) { ms[s] = mlm[mlb + (size_t)s * SEQ]; ls[s] = mll[mlb + (size_t)s * SEQ]; }
    float M = -1e30f;
    #pragma unroll
    for (int s = 0; s < NSPLIT; ++s) M = fmaxf(M, ms[s]);
    float wsc[NSPLIT]; float L = 0.f;
    #pragma unroll
    for (int s = 0; s < NSPLIT; ++s) { wsc[s] = exp2f((ms[s] - M) * L2E); L += wsc[s] * ls[s]; }
    float o[8] = {};
    #pragma unroll
    for (int s = 0; s < NSPLIT; ++s) {
        if (ls[s] <= 0.f) continue;
        bf16x8 pv = ld_bf8(&po[((size_t)(bh * NSPLIT + s) * SEQ + q) * DHD + dc]);
        #pragma unroll
        for (int j = 0; j < 8; ++j) o[j] += wsc[s] * (float)pv[j];
    }
    float invL = 1.f / L;
    int b = bh >> 3, h = bh & 7;
    __bf16 tmp[8];
    #pragma unroll
    for (int j = 0; j < 8; ++j) tmp[j] = (__bf16)(o[j] * invL);
    *(uint4*)&ao[((size_t)(b * SEQ) + q) * DM + h * DHD + dc] = *(uint4*)tmp;
}

extern "C" void kernel_launch(void* const* d_in, const int* in_sizes, int n_in,
                              void* d_out, int out_size, void* d_ws, size_t ws_size,
                              hipStream_t stream) {
    char* ws = (char*)d_ws;
    bf16* AR      = (bf16*)(ws + 0);              // arena: x | W_o | params
    float* ml_m   = (float*)(ws + 0);             // alias x region (dead after x-gemm), 1MB
    float* ml_l   = (float*)(ws + 1048576);       // 1MB
    bf16* WT      = (bf16*)(ws + 6391296);        // transposed weights (1,802,240 B)
    int*  flagp   = (int*)(ws + 8193536);
    float* y      = (float*)(ws + 8194048);       // fused x-proj out [4096][704] fp32
    bf16* cq      = (bf16*)(ws + 19728384);       // [4096][256]
    bf16* ckvp    = (bf16*)(ws + 21825536);       // [4096][384]
    bf16* q_attn  = (bf16*)(ws + 26019840);
    bf16* k_attn  = (bf16*)(ws + 32311296);
    bf16* v_attnT = (bf16*)(ws + 38602752);
    bf16* attn_o  = (bf16*)(ws + 42797056);
    bf16* po      = (bf16*)(ws + 50331648);       // 4-split partials, 16,777,216 B

    const bf16* xb  = AR + OFF_X;
    const bf16* W_o = AR + OFF_WO;
    const bf16* qg  = AR + OFF_QG;
    const bf16* qb_ = AR + OFF_QB;
    const bf16* kg  = AR + OFF_KG;
    const bf16* kb  = AR + OFF_KB;

    bf16*  out_b = (bf16*)d_out;
    float* out_f = (float*)d_out;
    bf16*  ckv_b = out_b + (size_t)MROWS * DM;
    float* ckv_f = out_f + (size_t)MROWS * DM;

    dim3 blk(256);
    // 1) prep: flag + convert + weight transposes (8-wide)
    prep<<<dim3((G_TOT + 255) / 256), blk, 0, stream>>>(
        d_in[0], d_in[1], d_in[2], d_in[3], d_in[4], d_in[5],
        d_in[6], d_in[7], d_in[8], d_in[9], d_in[10], d_in[11],
        (u16*)AR, (u16*)WT, flagp);
    // 2) fused x-proj [dq|dkv|kr] N=704 (n0==640 block does kr-rope -> k_attn)
    gemm128<<<dim3(11, 32), blk, 0, stream>>>(xb, DM, WT + T_DQ, DM, 704, DM, 0, y, 704, k_attn, nullptr, nullptr, nullptr);
    // 3) merged layernorms
    ln_both<<<dim3(2048), blk, 0, stream>>>(y, qg, qb_, kg, kb, cq, ckv_b, ckv_f, ckvp, flagp);
    // 4) fused cq up-proj [uq|qr] N=576, scaled Q (n0==512 block does q-rope)
    gemm128<<<dim3(9, 32), blk, 0, stream>>>(cq, QP, WT + T_UQ, QP, 576, QP, 4, q_attn, 0, nullptr, nullptr, nullptr, nullptr);
    // 5) kv up-proj (K scatter + V^T via LDS transpose), N=1024, K=384
    gemm128<<<dim3(16, 32), blk, 0, stream>>>(ckvp, 384, WT + T_UKV, 384, 1024, 384, 3, nullptr, 0, k_attn, v_attnT, nullptr, nullptr);
    // 6) attention (4-way split-KV, qb-paired, swapped-softmax, defer-max, T14)
    attn_split3<<<dim3(NSPLIT, 16, 16), blk, 0, stream>>>(q_attn, k_attn, v_attnT, po, ml_m, ml_l);
    // 7) combine
    attn_combine<<<dim3(1024), blk, 0, stream>>>(po, ml_m, ml_l, attn_o);
    // 8) output projection -> d_out (dual dtype)
    gemm128<<<dim3(8, 32), blk, 0, stream>>>(attn_o, DM, W_o, DM, DM, DM, 1, out_b, DM, nullptr, nullptr, flagp, out_f);
}